// Round 5
// baseline (594.742 us; speedup 1.0000x reference)
//
#include <hip/hip_runtime.h>

// B=8 S=1024 D=1024 H=16 DK=64 F=4096 -- fp32 containers (bf16-valued), detected per-tensor
#define Bq 8
#define Sq 1024
#define Dq 1024
#define Hq 16
#define DKq 64
#define Fq 4096
#define TOK (Bq*Sq)   // 8192

typedef unsigned short u16;
typedef unsigned int u32;
typedef __bf16 bf16x8 __attribute__((ext_vector_type(8)));
typedef float  f32x4  __attribute__((ext_vector_type(4)));

__device__ __forceinline__ float bf2f(u16 u) {
  u32 x = ((u32)u) << 16;
  float f; __builtin_memcpy(&f, &x, 4); return f;
}
__device__ __forceinline__ u16 f2bf(float f) {
  u32 u; __builtin_memcpy(&u, &f, 4);
  u += 0x7fffu + ((u >> 16) & 1u);
  return (u16)(u >> 16);
}
// async global->LDS, 16B/lane; LDS dest = wave-uniform base + lane*16
__device__ __forceinline__ void async16(const u16* g, u16* l) {
  __builtin_amdgcn_global_load_lds(
      (__attribute__((address_space(1))) void*)(g),
      (__attribute__((address_space(3))) void*)(l), 16, 0, 0);
}
__device__ __forceinline__ u16 load_in(const void* p, long idx, u32 fp32) {
  return fp32 ? f2bf(((const float*)p)[idx]) : ((const u16*)p)[idx];
}
// XOR-swizzled byte offset within a [rows][64 bf16] tile (128B rows)
__device__ __forceinline__ int swzb(int row, int colb) {
  return row * 128 + (colb ^ ((row & 7) << 4));
}

// ---------------- dtype detection: one launch, 17 blocks ----------------
struct InTab { const void* p[17]; int n[17]; };

__global__ void detect_all(InTab tab, u32* flags) {
  __shared__ int sh[3][256];
  int bi = blockIdx.x;
  const u16* buf = (const u16*)tab.p[bi];
  long n = tab.n[bi];
  long m = n < 65536 ? n : 65536;
  int t = threadIdx.x;
  int nanpat = 0, evz = 0, oddnz = 0;
  for (long i = t; i < m; i += 256) {
    u16 v = buf[i];
    if ((v & 0x7F80u) == 0x7F80u) nanpat++;
    if ((i & 1) == 0) { if (v == 0) evz++; }
    else { if (v != 0) oddnz++; }
  }
  sh[0][t] = nanpat; sh[1][t] = evz; sh[2][t] = oddnz;
  __syncthreads();
  for (int s = 128; s > 0; s >>= 1) {
    if (t < s) { sh[0][t] += sh[0][t+s]; sh[1][t] += sh[1][t+s]; sh[2][t] += sh[2][t+s]; }
    __syncthreads();
  }
  if (t == 0) {
    long half = m / 2;
    bool fp32 = (sh[0][0] > 8) ||
                (sh[1][0] > (half * 9) / 10 && sh[2][0] > (half * 9) / 10);
    flags[bi] = fp32 ? 1u : 0u;
  }
}

__global__ void diag_ws_too_small(u16* out, float code) { out[0] = f2bf(code); }

__global__ void diag_mixed(const u32* flags, void* out) {
  u32 a = flags[0];
  if (flags[1] != a || flags[7] != a || flags[11] != a || flags[13] != a) {
    if (a) ((float*)out)[0] = 3000.0f;
    else ((u16*)out)[0] = f2bf(3000.0f);
  }
}

// ---------------- batched LDS-tiled transpose pack (single launch) ----------------
// 3072 tile-jobs of 64x64: [0,768) Wq/Wk/Wv slices, [768,1024) Wo, [1024,2048) W1, [2048,3072) W2
__global__ __launch_bounds__(256) void pack_all(const void* __restrict__ Wq,
                                                const void* __restrict__ Wk,
                                                const void* __restrict__ Wv,
                                                const void* __restrict__ Wo,
                                                const void* __restrict__ W1,
                                                const void* __restrict__ W2,
                                                u16* __restrict__ Wqkv_t,
                                                u16* __restrict__ Wo_t,
                                                u16* __restrict__ W1_t,
                                                u16* __restrict__ W2_t,
                                                const u32* __restrict__ flags) {
  int id = blockIdx.x;
  const void* in; u16* out; u32 f; int R, C; long zin; int r0, c0;
  if (id < 768) {            // Wq/Wk/Wv: [16 h][1024 d][64 dk] -> [h*64+dk][d]
    int w = id >> 8, t = id & 255;
    int z = t >> 4, xt = t & 15;
    in = (w == 0) ? Wq : ((w == 1) ? Wk : Wv);
    f = flags[(w == 0) ? 1 : ((w == 1) ? 3 : 5)];
    R = 1024; C = 64;
    zin = (long)z * 65536;
    out = Wqkv_t + (long)w * 1048576 + (long)z * 65536;
    r0 = xt * 64; c0 = 0;
  } else if (id < 1024) {    // Wo [1024][1024]
    int t = id - 768; int xt = t & 15, yt = t >> 4;
    in = Wo; f = flags[7]; R = 1024; C = 1024; zin = 0; out = Wo_t;
    r0 = xt * 64; c0 = yt * 64;
  } else if (id < 2048) {    // W1 [1024][4096]
    int t = id - 1024; int xt = t & 15, yt = t >> 4;
    in = W1; f = flags[11]; R = 1024; C = 4096; zin = 0; out = W1_t;
    r0 = xt * 64; c0 = yt * 64;
  } else {                   // W2 [4096][1024]
    int t = id - 2048; int xt = t & 63, yt = t >> 6;
    in = W2; f = flags[13]; R = 4096; C = 1024; zin = 0; out = W2_t;
    r0 = xt * 64; c0 = yt * 64;
  }
  __shared__ u16 tile[64][65];
  int tx = threadIdx.x & 63, ty = threadIdx.x >> 6;
#pragma unroll
  for (int it = 0; it < 16; it++) {
    int row = it * 4 + ty;
    tile[row][tx] = load_in(in, zin + (long)(r0 + row) * C + (c0 + tx), f);
  }
  __syncthreads();
#pragma unroll
  for (int it = 0; it < 16; it++) {
    int cc = it * 4 + ty;
    out[(long)(c0 + cc) * R + r0 + tx] = tile[tx][cc];
  }
}

// ---------------- merged small-vector cvt ----------------
struct CvtTab { const void* p[10]; int flagidx[10]; int dstoff[10]; int n[10]; };
__global__ void cvt_small(CvtTab tab, u16* __restrict__ dst, const u32* __restrict__ flags) {
  int e = blockIdx.x;
  u32 f = flags[tab.flagidx[e]];
  const void* p = tab.p[e];
  int n = tab.n[e], o = tab.dstoff[e];
  for (int i = threadIdx.x; i < n; i += 256) dst[o + i] = load_in(p, i, f);
}

// ---------------- vectorized src cvt (8 elems/thread) ----------------
__global__ __launch_bounds__(256) void cvt_src(const void* __restrict__ in,
                                               u16* __restrict__ out,
                                               const u32* __restrict__ flag) {
  u32 f = *flag;
  long i8 = ((long)blockIdx.x * 256 + threadIdx.x) * 8;
  if (f) {
    const float4* f4 = (const float4*)((const float*)in + i8);
    float4 a = f4[0], b = f4[1];
    u16 v[8] = {f2bf(a.x), f2bf(a.y), f2bf(a.z), f2bf(a.w),
                f2bf(b.x), f2bf(b.y), f2bf(b.z), f2bf(b.w)};
    *(uint4*)(out + i8) = *(const uint4*)v;
  } else {
    *(uint4*)(out + i8) = *(const uint4*)((const u16*)in + i8);
  }
}

// ---------------- GEMM: C[M,N] = A[M,K] @ Bt[N,K]^T + bias, optional ReLU --------
// 128x128 tile, BK=32, double-buffered LDS, 32KB -> 5 blocks/CU implicit overlap.
// mode 0: C[row*ldc+col]. mode 1 (QKV): col<2048 -> C (ldc=2048, Q|K);
//   col>=2048 -> V stored TRANSPOSED into Vt[b*16+h][dk][s].
__global__ __launch_bounds__(256) void gemm_bt(const u16* __restrict__ A,
                                               const u16* __restrict__ Bt,
                                               const u16* __restrict__ bias,
                                               u16* __restrict__ C,
                                               int M, int N, int K, int act,
                                               int ldc, u16* __restrict__ Vt,
                                               int mode) {
  __shared__ alignas(16) u16 sA[2][128 * 32];
  __shared__ alignas(16) u16 sB[2][128 * 32];
  const int tid = threadIdx.x;
  const int wv = tid >> 6, lane = tid & 63;
  const int m16 = lane & 15, quad = lane >> 4;
  const long bm = (long)blockIdx.x * 128;
  const long bn = (long)blockIdx.y * 128;
  const int wm = (wv >> 1) * 64, wn = (wv & 1) * 64;

  f32x4 acc[4][4];
#pragma unroll
  for (int i = 0; i < 4; i++)
#pragma unroll
    for (int j = 0; j < 4; j++) acc[i][j] = (f32x4){0.f, 0.f, 0.f, 0.f};

  const int row_s = tid >> 2;          // 0..63
  const int col_s = (tid & 3) * 8;
  const u16* gA0 = A + (bm + row_s) * (long)K + col_s;
  const u16* gA1 = gA0 + 64 * (long)K;
  const u16* gB0 = Bt + (bn + row_s) * (long)K + col_s;
  const u16* gB1 = gB0 + 64 * (long)K;

  auto stage = [&](int p, int k) {
    async16(gA0 + k, &sA[p][wv * 512]);
    async16(gA1 + k, &sA[p][2048 + wv * 512]);
    async16(gB0 + k, &sB[p][wv * 512]);
    async16(gB1 + k, &sB[p][2048 + wv * 512]);
  };
  auto compute = [&](int p) {
    bf16x8 af[4], bf_[4];
#pragma unroll
    for (int mi = 0; mi < 4; mi++)
      af[mi] = *(const bf16x8*)&sA[p][(wm + mi * 16 + m16) * 32 + quad * 8];
#pragma unroll
    for (int ni = 0; ni < 4; ni++)
      bf_[ni] = *(const bf16x8*)&sB[p][(wn + ni * 16 + m16) * 32 + quad * 8];
#pragma unroll
    for (int mi = 0; mi < 4; mi++)
#pragma unroll
      for (int ni = 0; ni < 4; ni++)
        acc[mi][ni] = __builtin_amdgcn_mfma_f32_16x16x32_bf16(af[mi], bf_[ni], acc[mi][ni], 0, 0, 0);
  };

  stage(0, 0);
  for (int k0 = 0; k0 < K; k0 += 64) {   // K is a multiple of 64 (1024/4096)
    __syncthreads();                     // drains stage(0,k0); protects buf1 from prev iter
    if (k0 + 32 < K) stage(1, k0 + 32);
    compute(0);
    __syncthreads();                     // drains stage(1); protects buf0
    if (k0 + 64 < K) stage(0, k0 + 64);
    compute(1);
  }

  float bv4[4];
#pragma unroll
  for (int ni = 0; ni < 4; ni++) bv4[ni] = bf2f(bias[bn + wn + ni * 16 + m16]);

#pragma unroll
  for (int mi = 0; mi < 4; mi++) {
#pragma unroll
    for (int ni = 0; ni < 4; ni++) {
      long col = bn + wn + ni * 16 + m16;
      long rowb = bm + wm + mi * 16 + quad * 4;
      if (mode == 1 && col >= 2048) {
        // V -> Vt[(b*16+h)][dk][s], 4 acc rows = consecutive s
        int hh = ((int)col >> 6) & 15, dk = (int)col & 63;
        int bb = (int)(rowb >> 10), ss = (int)(rowb & 1023);
        u16 t4[4];
#pragma unroll
        for (int r = 0; r < 4; r++) t4[r] = f2bf(acc[mi][ni][r] + bv4[ni]);
        *(uint2*)&Vt[(((long)bb * 16 + hh) * 64 + dk) * 1024 + ss] = *(const uint2*)t4;
      } else {
#pragma unroll
        for (int r = 0; r < 4; r++) {
          float v = acc[mi][ni][r] + bv4[ni];
          if (act) v = fmaxf(v, 0.f);
          C[(rowb + r) * (long)ldc + col] = f2bf(v);
        }
      }
    }
  }
}

#define MF16 __builtin_amdgcn_mfma_f32_16x16x32_bf16

// ---------------- GEMM 256x256, BK=64, 8-wave, 2-PHASE counted-vmcnt ----------
// v2 of the 8-phase port: all 24 fragment ds_reads in phase A (afr[8][2]+bfr[4][2]
// held in regs), pure-register 32-MFMA cluster in phase B -> 4 barriers/tile
// (was 8). stB only in the read-free phase B, so B-reads (phase A) are fenced
// from the overwrite by phase A's closing barrier. Fence: one vmcnt(4)/tile at
// phase B: outstanding = B(T+1)[4] + A(T+1)[4] + B(T+2)[4] = 12; waits 8 oldest
// = exactly A(T+1)+B(T+1) needed by next tile; B(T+2) stays in flight.
// Tail pair peeled with vmcnt(0). VGPR ~245 (acc128+afr64+bfr32+addr) -- spill
// signature would be VGPR=256 + scratch.
#define TILEW(BUF, NBUF, DOA, DOB, KA, KB, VMS)                                \
  {                                                                            \
    /* phase A: read ALL frags of tile T; stage A(T+1); MFMA ni0-1 */          \
    _Pragma("unroll") for (int mi = 0; mi < 8; mi++)                           \
      _Pragma("unroll") for (int kk = 0; kk < 2; kk++)                         \
        afr[mi][kk] = *(const bf16x8*)&sA[BUF][offA + mi * 1024 + kof[kk]];    \
    _Pragma("unroll") for (int ni = 0; ni < 4; ni++)                           \
      _Pragma("unroll") for (int kk = 0; kk < 2; kk++)                         \
        bfr[ni][kk] = *(const bf16x8*)&sB[BUF][offB + ni * 1024 + kof[kk]];    \
    if (DOA) { stA(NBUF, 0, KA); stA(NBUF, 1, KA); }                           \
    __builtin_amdgcn_s_barrier();                                              \
    __builtin_amdgcn_s_setprio(1);                                             \
    _Pragma("unroll") for (int kk = 0; kk < 2; kk++)                           \
      _Pragma("unroll") for (int mi = 0; mi < 8; mi++)                         \
        _Pragma("unroll") for (int ni = 0; ni < 2; ni++)                       \
          acc[mi][ni] = MF16(afr[mi][kk], bfr[ni][kk], acc[mi][ni], 0, 0, 0);  \
    __builtin_amdgcn_s_setprio(0);                                             \
    __builtin_amdgcn_s_barrier();                                              \
    /* phase B: stage B(T+2) into BUF; counted fence; MFMA ni2-3 (pure reg) */ \
    if (DOB) { stB(BUF, 0, KB); stB(BUF, 1, KB); }                             \
    asm volatile("s_waitcnt vmcnt(" VMS ")" ::: "memory");                     \
    __builtin_amdgcn_s_barrier();                                              \
    __builtin_amdgcn_s_setprio(1);                                             \
    _Pragma("unroll") for (int kk = 0; kk < 2; kk++)                           \
      _Pragma("unroll") for (int mi = 0; mi < 8; mi++)                         \
        _Pragma("unroll") for (int ni = 0; ni < 2; ni++)                       \
          acc[mi][2 + ni] = MF16(afr[mi][kk], bfr[2 + ni][kk], acc[mi][2 + ni], 0, 0, 0); \
    __builtin_amdgcn_s_setprio(0);                                             \
    __builtin_amdgcn_s_barrier();                                              \
  }

__global__ __launch_bounds__(512, 2) void gemm256w(const u16* __restrict__ A,
                                                   const u16* __restrict__ Bt,
                                                   const u16* __restrict__ bias,
                                                   u16* __restrict__ C,
                                                   int M, int N, int K, int act) {
  __shared__ alignas(16) u16 sA[2][16384];   // 2 x [2 halves][128 rows][64 cols] swz
  __shared__ alignas(16) u16 sB[2][16384];
  const int tid = threadIdx.x;
  const int wv = tid >> 6, lane = tid & 63;
  const int m16 = lane & 15, quad = lane >> 4;
  const int wr = wv >> 2, wc = wv & 3;

  // T1: bijective XCD-aware remap of the linear block id (tn fastest)
  const int NT = N >> 8;
  int bid = blockIdx.x;
  {
    const int nwg = gridDim.x;
    const int q = nwg >> 3, r = nwg & 7;
    const int xcd = bid & 7, lp = bid >> 3;
    bid = (xcd < r ? xcd * (q + 1) : r * (q + 1) + (xcd - r) * q) + lp;
  }
  const long bm = (long)(bid / NT) * 256;
  const long bn = (long)(bid % NT) * 256;

  // staging: linear LDS dest, inverse-swizzled global source (rule: both-sides)
  const int r0 = wv * 16 + (lane >> 3);             // row within 128-row half
  const int cstg = ((lane & 7) ^ (lane >> 3)) * 8;  // swizzled col (elements)
  const u16* gA0 = A  + (bm + r0) * (long)K + cstg;
  const u16* gA1 = A  + (bm + 128 + r0) * (long)K + cstg;
  const u16* gB0 = Bt + (bn + r0) * (long)K + cstg;
  const u16* gB1 = Bt + (bn + 128 + r0) * (long)K + cstg;
  const long k8 = 8 * (long)K;

  auto stA = [&](int nb, int h, int k0) {
    const u16* s = (h ? gA1 : gA0) + k0;
    u16* d = &sA[nb][h * 8192 + wv * 1024];
    async16(s, d);
    async16(s + k8, d + 512);
  };
  auto stB = [&](int nb, int h, int k0) {
    const u16* s = (h ? gB1 : gB0) + k0;
    u16* d = &sB[nb][h * 8192 + wv * 1024];
    async16(s, d);
    async16(s + k8, d + 512);
  };

  // fragment-read addressing (swizzled): granule(kk) = (kk*4+quad)^(m16&7)
  const int qs = quad ^ (m16 & 3);
  const int hb = (m16 >> 2) & 1;
  const int kof[2] = {hb * 32, 32 - hb * 32};
  const int offA = wr * 8192 + m16 * 64 + qs * 8;                    // + mi*1024
  const int offB = (wc >> 1) * 8192 + (wc & 1) * 4096 + m16 * 64 + qs * 8; // + ni*1024

  f32x4 acc[8][4];
#pragma unroll
  for (int i = 0; i < 8; i++)
#pragma unroll
    for (int j = 0; j < 4; j++) acc[i][j] = (f32x4){0.f, 0.f, 0.f, 0.f};
  bf16x8 afr[8][2], bfr[4][2];

  const int KT = K >> 6;   // K-tiles of 64; K multiple of 128, KT even >= 2

  // prologue: tile0 (A0,A1,B0,B1) -> buf0; B halves of tile1 -> buf1
  stA(0, 0, 0); stA(0, 1, 0); stB(0, 0, 0); stB(0, 1, 0);
  stB(1, 0, 64); stB(1, 1, 64);
  asm volatile("s_waitcnt vmcnt(4)" ::: "memory");   // tile0 landed; B(tile1) in flight
  __builtin_amdgcn_s_barrier();

  int T = 0;
  for (; T + 2 < KT; T += 2) {
    TILEW(0, 1, true, true, (T + 1) << 6, (T + 2) << 6, "4");
    TILEW(1, 0, true, true, (T + 2) << 6, (T + 3) << 6, "4");
  }
  {  // tail pair (T = KT-2): no B stages remain -> must drain fully
    TILEW(0, 1, true, false, (T + 1) << 6, 0, "0");
    TILEW(1, 0, false, false, 0, 0, "0");
  }

  float bv4[4];
#pragma unroll
  for (int ni = 0; ni < 4; ni++) bv4[ni] = bf2f(bias[bn + wc * 64 + ni * 16 + m16]);

#pragma unroll
  for (int mi = 0; mi < 8; mi++) {
#pragma unroll
    for (int ni = 0; ni < 4; ni++) {
      long col = bn + wc * 64 + ni * 16 + m16;
      long rowb = bm + wr * 128 + mi * 16 + quad * 4;
#pragma unroll
      for (int r = 0; r < 4; r++) {
        float v = acc[mi][ni][r] + bv4[ni];
        if (act) v = fmaxf(v, 0.f);
        C[(rowb + r) * (long)N + col] = f2bf(v);
      }
    }
  }
}

// ---------------- GEMM 256x128, BK=64, 8-wave, counted-vmcnt schedule ----------
// For N=1024 GEMMs (FF2, Wo): grid = (M/256)*(N/128) = 256 blocks = 1 full round.
#define TILE128(BUF, NBUF, DOA, DOB, KA, KB, VMS)                              \
  {                                                                            \
    /* p0: read A mi0-3 + B ni0-1; stage A-half0(T+1) */                       \
    _Pragma("unroll") for (int mi = 0; mi < 4; mi++)                           \
      _Pragma("unroll") for (int kk = 0; kk < 2; kk++)                         \
        afr[mi][kk] = *(const bf16x8*)&sA[BUF][offA + mi * 1024 + kof[kk]];    \
    _Pragma("unroll") for (int ni = 0; ni < 2; ni++)                           \
      _Pragma("unroll") for (int kk = 0; kk < 2; kk++)                         \
        bfr[ni][kk] = *(const bf16x8*)&sB[BUF][offB + ni * 1024 + kof[kk]];    \
    if (DOA) stA(NBUF, 0, KA);                                                 \
    __builtin_amdgcn_s_barrier();                                              \
    __builtin_amdgcn_s_setprio(1);                                             \
    _Pragma("unroll") for (int kk = 0; kk < 2; kk++)                           \
      _Pragma("unroll") for (int mi = 0; mi < 4; mi++)                         \
        _Pragma("unroll") for (int ni = 0; ni < 2; ni++)                       \
          acc[mi][ni] = MF16(afr[mi][kk], bfr[ni][kk], acc[mi][ni], 0, 0, 0);  \
    __builtin_amdgcn_s_setprio(0);                                             \
    __builtin_amdgcn_s_barrier();                                              \
    /* p1: read B ni2-3 (A held); stage A-half1(T+1) */                        \
    _Pragma("unroll") for (int ni = 0; ni < 2; ni++)                           \
      _Pragma("unroll") for (int kk = 0; kk < 2; kk++)                         \
        bfr[2 + ni][kk] = *(const bf16x8*)&sB[BUF][offB + (2 + ni) * 1024 + kof[kk]]; \
    if (DOA) stA(NBUF, 1, KA);                                                 \
    __builtin_amdgcn_s_barrier();                                              \
    __builtin_amdgcn_s_setprio(1);                                             \
    _Pragma("unroll") for (int kk = 0; kk < 2; kk++)                           \
      _Pragma("unroll") for (int mi = 0; mi < 4; mi++)                         \
        _Pragma("unroll") for (int ni = 0; ni < 2; ni++)                       \
          acc[mi][2 + ni] = MF16(afr[mi][kk], bfr[2 + ni][kk], acc[mi][2 + ni], 0, 0, 0); \
    __builtin_amdgcn_s_setprio(0);                                             \
    __builtin_amdgcn_s_barrier();                                              \
    /* p2: stage B(T+2) into BUF (same parity); counted fence */               \
    if (DOB) stB(BUF, KB);                                                     \
    asm volatile("s_waitcnt vmcnt(" VMS ")" ::: "memory");                     \
    __builtin_amdgcn_s_barrier();                                              \
  }

__global__ __launch_bounds__(512, 2) void gemm256x128(const u16* __restrict__ A,
                                                      const u16* __restrict__ Bt,
                                                      const u16* __restrict__ bias,
                                                      u16* __restrict__ C,
                                                      int M, int N, int K, int act) {
  __shared__ alignas(16) u16 sA[2][16384];   // [2 halves][128 rows][64 cols] swz
  __shared__ alignas(16) u16 sB[2][8192];    // [128 rows][64 cols] swz
  const int tid = threadIdx.x;
  const int wv = tid >> 6, lane = tid & 63;
  const int m16 = lane & 15, quad = lane >> 4;
  const int wr = wv >> 1, wc = wv & 1;       // 4M x 2N waves, 64x64 each

  const int NT = N >> 7;
  int bid = blockIdx.x;
  {
    const int nwg = gridDim.x;
    const int q = nwg >> 3, r = nwg & 7;
    const int xcd = bid & 7, lp = bid >> 3;
    bid = (xcd < r ? xcd * (q + 1) : r * (q + 1) + (xcd - r) * q) + lp;
  }
  const long bm = (long)(bid / NT) * 256;
  const long bn = (long)(bid % NT) * 128;

  const int r0 = wv * 16 + (lane >> 3);
  const int cstg = ((lane & 7) ^ (lane >> 3)) * 8;
  const u16* gA0 = A + (bm + r0) * (long)K + cstg;
  const u16* gA1 = A + (bm + 128 + r0) * (long)K + cstg;
  const u16* gB0 = Bt + (bn + r0) * (long)K + cstg;
  const long k8 = 8 * (long)K;

  auto stA = [&](int nb, int h, int k0) {
    const u16* s = (h ? gA1 : gA0) + k0;
    u16* d = &sA[nb][h * 8192 + wv * 1024];
    async16(s, d);
    async16(s + k8, d + 512);
  };
  auto stB = [&](int nb, int k0) {
    const u16* s = gB0 + k0;
    u16* d = &sB[nb][wv * 1024];
    async16(s, d);
    async16(s + k8, d + 512);
  };

  const int qs = quad ^ (m16 & 3);
  const int hb = (m16 >> 2) & 1;
  const int kof[2] = {hb * 32, 32 - hb * 32};
  const int offA = (wr >> 1) * 8192 + (wr & 1) * 4096 + m16 * 64 + qs * 8; // +mi*1024
  const int offB = wc * 4096 + m16 * 64 + qs * 8;                          // +ni*1024

  f32x4 acc[4][4];
#pragma unroll
  for (int i = 0; i < 4; i++)
#pragma unroll
    for (int j = 0; j < 4; j++) acc[i][j] = (f32x4){0.f, 0.f, 0.f, 0.f};
  bf16x8 afr[4][2], bfr[4][2];

  const int KT = K >> 6;   // even (K multiple of 128)

  // prologue: tile0 (A0,A1,B) -> buf0; B(tile1) -> buf1
  stA(0, 0, 0); stA(0, 1, 0); stB(0, 0);
  stB(1, 64);
  asm volatile("s_waitcnt vmcnt(2)" ::: "memory");   // tile0 landed; B(1) in flight
  __builtin_amdgcn_s_barrier();

  int T = 0;
  for (; T + 2 < KT; T += 2) {
    TILE128(0, 1, true, true, (T + 1) << 6, (T + 2) << 6, "2");
    TILE128(1, 0, true, true, (T + 2) << 6, (T + 3) << 6, "2");
  }
  // tail pair: tile KT-2 stages only A(KT-1); must drain fully
  TILE128(0, 1, true, false, (T + 1) << 6, 0, "0");
  TILE128(1, 0, false, false, 0, 0, "0");

  float bv4[4];
#pragma unroll
  for (int ni = 0; ni < 4; ni++) bv4[ni] = bf2f(bias[bn + wc * 64 + ni * 16 + m16]);

#pragma unroll
  for (int mi = 0; mi < 4; mi++) {
#pragma unroll
    for (int ni = 0; ni < 4; ni++) {
      long col = bn + wc * 64 + ni * 16 + m16;
      long rowb = bm + wr * 64 + mi * 16 + quad * 4;
#pragma unroll
      for (int r = 0; r < 4; r++) {
        float v = acc[mi][ni][r] + bv4[ni];
        if (act) v = fmaxf(v, 0.f);
        C[(rowb + r) * (long)N + col] = f2bf(v);
      }
    }
  }
}

// ---------------- flash attention v2: 128q blocks, 32q/wave, V^T pre-staged ----
// qk: [8192][2048] (Q|K per token), Vt: [b*16+h][64 dk][1024 s] (from QKV GEMM).
__global__ __launch_bounds__(256, 4) void attn_fwd(const u16* __restrict__ qk,
                                                   const u16* __restrict__ Vt,
                                                   u16* __restrict__ attnO) {
  __shared__ alignas(16) u16 sQP[8192];  // Q [128][64] swz; later per-wave P[32][64] @ wv*4096B
  __shared__ alignas(16) u16 sK[4096];   // [64 key][64 dk] swz
  __shared__ alignas(16) u16 sVt[4096];  // [64 dk][64 key] swz
  const int tid = threadIdx.x;
  const int bh = blockIdx.x;
  const int qt = blockIdx.y;
  const int b = bh >> 4, h = bh & 15;
  const int wv = tid >> 6, lane = tid & 63;
  const int m16 = lane & 15, quad = lane >> 4;
  const int kk = tid >> 3;               // staging row 0..31
  const int t7 = tid & 7;

  char* cQP = (char*)sQP;
  char* cK = (char*)sK;
  char* cV = (char*)sVt;

  // ---- stage Q [128 q][64 dk], scaled by 1/sqrt(DK)=0.125, swizzled ----
  {
    int row = tid >> 1, half = tid & 1;
    const u16* g = qk + (long)(b * Sq + qt * 128 + row) * 2048 + h * 64 + half * 32;
#pragma unroll
    for (int j = 0; j < 4; j++) {
      uint4 raw = *(const uint4*)(g + j * 8);
      const u16* pv = (const u16*)&raw;
      u16 t[8];
#pragma unroll
      for (int e = 0; e < 8; e++) t[e] = f2bf(bf2f(pv[e]) * 0.125f);
      *(uint4*)(cQP + swzb(row, half * 64 + j * 16)) = *(const uint4*)t;
    }
  }
  __syncthreads();
  // Q frags: qf[qt2][s] = Q[wv*32 + qt2*16 + m16][s*32 + quad*8 ..]
  bf16x8 qf[2][2];
#pragma unroll
  for (int qt2 = 0; qt2 < 2; qt2++)
#pragma unroll
    for (int s = 0; s < 2; s++)
      qf[qt2][s] = *(const bf16x8*)(cQP + swzb(wv * 32 + qt2 * 16 + m16, s * 64 + quad * 16));

  f32x4 o[4][2];
#pragma unroll
  for (int dt = 0; dt < 4; dt++)
#pragma unroll
    for (int qt2 = 0; qt2 < 2; qt2++) o[dt][qt2] = (f32x4){0.f, 0.f, 0.f, 0.f};
  float mrun[2] = {-1e30f, -1e30f}, lrun[2] = {0.f, 0.f};

  const u16* gK = qk + (long)(b * Sq + kk) * 2048 + 1024 + h * 64 + t7 * 8;
  const u16* gV = Vt + ((long)bh * 64 + kk) * 1024 + t7 * 8;
  const long stepK = (long)64 * 2048;
  const int off0 = swzb(kk, t7 * 16);        // (kk+32)&7 == kk&7 -> +4096 bytes
  const int off1 = off0 + 4096;

  uint4 rk0 = *(const uint4*)gK;
  uint4 rk1 = *(const uint4*)(gK + 32 * 2048);
  uint4 rv0 = *(const uint4*)gV;
  uint4 rv1 = *(const uint4*)(gV + 32 * 1024);

  for (int kt = 0; kt < 16; kt++) {
    __syncthreads();   // previous iteration's K/V frag reads done
    *(uint4*)(cK + off0) = rk0;
    *(uint4*)(cK + off1) = rk1;
    *(uint4*)(cV + off0) = rv0;
    *(uint4*)(cV + off1) = rv1;
    __syncthreads();   // tiles published

    // S^T[key][q]: st[kt2][qt2], col=q=qt2*16+m16, row=key=kt2*16+quad*4+r
    f32x4 st[4][2];
#pragma unroll
    for (int kt2 = 0; kt2 < 4; kt2++)
#pragma unroll
      for (int qt2 = 0; qt2 < 2; qt2++) st[kt2][qt2] = (f32x4){0.f, 0.f, 0.f, 0.f};
    __builtin_amdgcn_s_setprio(1);
#pragma unroll
    for (int s = 0; s < 2; s++) {
      bf16x8 kf[4];
#pragma unroll
      for (int kt2 = 0; kt2 < 4; kt2++)
        kf[kt2] = *(const bf16x8*)(cK + swzb(kt2 * 16 + m16, s * 64 + quad * 16));
#pragma unroll
      for (int kt2 = 0; kt2 < 4; kt2++)
#pragma unroll
        for (int qt2 = 0; qt2 < 2; qt2++)
          st[kt2][qt2] = MF16(kf[kt2], qf[qt2][s], st[kt2][qt2], 0, 0, 0);
    }
    __builtin_amdgcn_s_setprio(0);

    if (kt < 15) {     // prefetch next K/V (hidden under softmax+PV)
      rk0 = *(const uint4*)(gK + (long)(kt + 1) * stepK);
      rk1 = *(const uint4*)(gK + (long)(kt + 1) * stepK + 32 * 2048);
      rv0 = *(const uint4*)(gV + (kt + 1) * 64);
      rv1 = *(const uint4*)(gV + (kt + 1) * 64 + 32 * 1024);
    }

    // online softmax per qt2 (lane owns q = qt2*16+m16; keys split across quad)
    char* cP = cQP + wv * 4096;
#pragma unroll
    for (int qt2 = 0; qt2 < 2; qt2++) {
      float pm = st[0][qt2][0];
#pragma unroll
      for (int kt2 = 0; kt2 < 4; kt2++)
#pragma unroll
        for (int r = 0; r < 4; r++) pm = fmaxf(pm, st[kt2][qt2][r]);
      pm = fmaxf(pm, __shfl_xor(pm, 16));
      pm = fmaxf(pm, __shfl_xor(pm, 32));
      float mnew = fmaxf(mrun[qt2], pm);
      float al = __expf(mrun[qt2] - mnew);
      mrun[qt2] = mnew;
      float rs = 0.f;
#pragma unroll
      for (int kt2 = 0; kt2 < 4; kt2++) {
        u16 t4[4];
#pragma unroll
        for (int r = 0; r < 4; r++) {
          float p = __expf(st[kt2][qt2][r] - mnew);
          rs += p;
          t4[r] = f2bf(p);
        }
        *(uint2*)(cP + swzb(qt2 * 16 + m16, kt2 * 32 + quad * 8)) = *(const uint2*)t4;
      }
      rs += __shfl_xor(rs, 16);
      rs += __shfl_xor(rs, 32);
      lrun[qt2] = lrun[qt2] * al + rs;
#pragma unroll
      for (int dt = 0; dt < 4; dt++)
#pragma unroll
        for (int r = 0; r < 4; r++) o[dt][qt2][r] *= al;
    }

    // O^T[dk][q] += V^T[dk][key] * P^T : A = V^T frags, B = P frags
    bf16x8 pb[2][2];
#pragma unroll
    for (int qt2 = 0; qt2 < 2; qt2++)
#pragma unroll
      for (int ks = 0; ks < 2; ks++)
        pb[qt2][ks] = *(const bf16x8*)(cP + swzb(qt2 * 16 + m16, ks * 64 + quad * 16));
    __builtin_amdgcn_s_setprio(1);
#pragma unroll
    for (int dt = 0; dt < 4; dt++) {
      bf16x8 v0 = *(const bf16x8*)(cV + swzb(dt * 16 + m16, quad * 16));
      bf16x8 v1 = *(const bf16x8*)(cV + swzb(dt * 16 + m16, 64 + quad * 16));
#pragma unroll
      for (int qt2 = 0; qt2 < 2; qt2++) {
        o[dt][qt2] = MF16(v0, pb[qt2][0], o[dt][qt2], 0, 0, 0);
        o[dt][qt2] = MF16(v1, pb[qt2][1], o[dt][qt2], 0, 0, 0);
      }
    }
    __builtin_amdgcn_s_setprio(0);
  }

#pragma unroll
  for (int qt2 = 0; qt2 < 2; qt2++) {
    float rl = 1.f / lrun[qt2];
    long tok = (long)(b * Sq + qt * 128 + wv * 32 + qt2 * 16 + m16);
#pragma unroll
    for (int dt = 0; dt < 4; dt++) {
      u16 t4[4];
#pragma unroll
      for (int r = 0; r < 4; r++) t4[r] = f2bf(o[dt][qt2][r] * rl);
      *(uint2*)&attnO[tok * 1024 + h * 64 + dt * 16 + quad * 4] = *(const uint2*)t4;
    }
  }
}

// ---------------- add + LayerNorm (bf16 out, internal), uint2-vectorized -------
__global__ __launch_bounds__(256) void add_ln(const u16* __restrict__ X,
                                              const u16* __restrict__ Y,
                                              const u16* __restrict__ g,
                                              const u16* __restrict__ be,
                                              u16* __restrict__ out) {
  const int row = blockIdx.x;
  const int t = threadIdx.x;
  const long base = (long)row * Dq;
  const int i4 = t * 4;
  uint2 xr = *(const uint2*)&X[base + i4];
  uint2 yr = *(const uint2*)&Y[base + i4];
  const u16* xp = (const u16*)&xr;
  const u16* yp = (const u16*)&yr;
  float v[4]; float s = 0.f, ss = 0.f;
#pragma unroll
  for (int i = 0; i < 4; i++) {
    float x = bf2f(xp[i]) + bf2f(yp[i]);
    v[i] = x; s += x; ss += x * x;
  }
#pragma unroll
  for (int off = 32; off > 0; off >>= 1) { s += __shfl_down(s, off); ss += __shfl_down(ss, off); }
  __shared__ float red[8];
  int wv = t >> 6, ln = t & 63;
  if (ln == 0) { red[wv] = s; red[4 + wv] = ss; }
  __syncthreads();
  s = red[0] + red[1] + red[2] + red[3];
  ss = red[4] + red[5] + red[6] + red[7];
  float mean = s * (1.f / Dq);
  float var = ss * (1.f / Dq) - mean * mean;
  float rstd = rsqrtf(var + 1e-5f);
  uint2 gr = *(const uint2*)&g[i4];
  uint2 br = *(const uint2*)&be[i4];
  const u16* gp = (const u16*)&gr;
  const u16* bp = (const u16*)&br;
  u16 o4[4];
#pragma unroll
  for (int i = 0; i < 4; i++)
    o4[i] = f2bf((v[i] - mean) * rstd * bf2f(gp[i]) + bf2f(bp[i]));
  *(uint2*)&out[base + i4] = *(const uint2*)o4;
}

// ---------------- final add + LayerNorm, dual-dtype store, vectorized ----------
__global__ __launch_bounds__(256) void add_ln_out(const u16* __restrict__ X,
                                                  const u16* __restrict__ Y,
                                                  const u16* __restrict__ g,
                                                  const u16* __restrict__ be,
                                                  void* __restrict__ out,
                                                  const u32* __restrict__ outflag) {
  const u32 fp32 = *outflag;
  const int row = blockIdx.x;
  const int t = threadIdx.x;
  const long base = (long)row * Dq;
  const int i4 = t * 4;
  uint2 xr = *(const uint2*)&X[base + i4];
  uint2 yr = *(const uint2*)&Y[base + i4];
  const u16* xp = (const u16*)&xr;
  const u16* yp = (const u16*)&yr;
  float v[4]; float s = 0.f, ss = 0.f;
#pragma unroll
  for (int i = 0; i < 4; i++) {
    float x = bf2f(xp[i]) + bf2f(yp[i]);
    v[i] = x; s += x; ss += x * x;
  }
#pragma unroll
  for (int off = 32; off > 0; off >>= 1) { s += __shfl_down(s, off); ss += __shfl_down(ss, off); }
  __shared__ float red[8];
  int wv = t >> 6, ln = t & 63;
  if (ln == 0) { red[wv] = s; red[4 + wv] = ss; }
  __syncthreads();
  s = red[0] + red[1] + red[2] + red[3];
  ss = red[4] + red[5] + red[6] + red[7];
  float mean = s * (1.f / Dq);
  float var = ss * (1.f / Dq) - mean * mean;
  float rstd = rsqrtf(var + 1e-5f);
  uint2 gr = *(const uint2*)&g[i4];
  uint2 br = *(const uint2*)&be[i4];
  const u16* gp = (const u16*)&gr;
  const u16* bp = (const u16*)&br;
  if (fp32) {
    float4 o4;
    o4.x = (v[0] - mean) * rstd * bf2f(gp[0]) + bf2f(bp[0]);
    o4.y = (v[1] - mean) * rstd * bf2f(gp[1]) + bf2f(bp[1]);
    o4.z = (v[2] - mean) * rstd * bf2f(gp[2]) + bf2f(bp[2]);
    o4.w = (v[3] - mean) * rstd * bf2f(gp[3]) + bf2f(bp[3]);
    *(float4*)((float*)out + base + i4) = o4;
  } else {
    u16 o4[4];
#pragma unroll
    for (int i = 0; i < 4; i++)
      o4[i] = f2bf((v[i] - mean) * rstd * bf2f(gp[i]) + bf2f(bp[i]));
    *(uint2*)((u16*)out + base + i4) = *(const uint2*)o4;
  }
}

extern "C" void kernel_launch(void* const* d_in, const int* in_sizes, int n_in,
                              void* d_out, int out_size, void* d_ws, size_t ws_size,
                              hipStream_t stream) {
  char* ws = (char*)d_ws;
  size_t off = 0;
  auto alloc = [&](size_t bytes) {
    void* p = ws + off;
    off += (bytes + 255) & ~(size_t)255;
    return p;
  };
  u32* flags  = (u32*)alloc(32 * 4);
  u16* Wqkv_t = (u16*)alloc((size_t)3072 * 1024 * 2);   // 6 MB
  u16* Wo_t   = (u16*)alloc((size_t)1024 * 1024 * 2);   // 2 MB
  u16* W1_t   = (u16*)alloc((size_t)4096 * 1024 * 2);   // 8 MB
  u16* W2_t   = (u16*)alloc((size_t)1024 * 4096 * 2);   // 8 MB
  u16* svec   = (u16*)alloc((size_t)13312 * 2);         // all small vectors
  u16* src_bf = (u16*)alloc((size_t)TOK * 1024 * 2);    // 16 MB
  u16* regA   = (u16*)alloc((size_t)TOK * 4096 * 2);    // 64 MB
  size_t need_chunk2 = off;                              // h1(32MB) fits inside regA
  size_t need_full   = off + (size_t)TOK * 4096 * 2 / 2; // +32MB so h1(64MB) spans past regA

  u16* outw = (u16*)d_out;
  int CH;  // rows per FF chunk
  if (ws_size >= need_full) { CH = 8192; (void)alloc((size_t)32 << 20); }
  else if (ws_size >= need_chunk2) CH = 4096;
  else if (ws_size >= need_chunk2 - ((size_t)16 << 20)) CH = 2048;
  else {
    diag_ws_too_small<<<1, 1, 0, stream>>>(outw, 8000.0f + (float)(ws_size >> 20));
    return;
  }

  u16* qk    = regA;                          // [0,32)  Q|K per token [8192][2048]
  u16* Vt    = regA + (size_t)TOK * 2048;     // [32,48) V transposed [128][64][1024]
  u16* attnb = regA + (size_t)TOK * 3072;     // [48,64)
  u16* proj  = regA;                          // [0,16)  after qk/Vt dead
  u16* x     = regA + (size_t)TOK * 1024;     // [16,32)
  u16* h1    = regA + (size_t)TOK * 2048;     // [32,..) CH*4096*2 bytes (Vt dead by then)
  u16* f2    = src_bf;                        // src_bf dead after x computed

  u16* bqkv = svec + 0;      // 3072
  u16* bo_c = svec + 3072;
  u16* g1_c = svec + 4096;
  u16* be1_c = svec + 5120;
  u16* b1_c = svec + 6144;   // 4096
  u16* b2_c = svec + 10240;
  u16* g2_c = svec + 11264;
  u16* be2_c = svec + 12288;

  // ---- dtype detection ----
  InTab itab;
  for (int i = 0; i < 17; i++) { itab.p[i] = d_in[i]; itab.n[i] = in_sizes[i]; }
  detect_all<<<dim3(17), 256, 0, stream>>>(itab, flags);

  // ---- all weight transposes in one launch ----
  pack_all<<<dim3(3072), 256, 0, stream>>>(d_in[1], d_in[3], d_in[5], d_in[7], d_in[11], d_in[13],
                                           Wqkv_t, Wo_t, W1_t, W2_t, flags);

  // ---- small vectors ----
  CvtTab ct;
  const int srcs[10] = {2, 4, 6, 8, 9, 10, 12, 14, 15, 16};
  const int offs[10] = {0, 1024, 2048, 3072, 4096, 5120, 6144, 10240, 11264, 12288};
  const int lens[10] = {1024, 1024, 1024, 1024, 1024, 1024, 4096, 1024, 1024, 1024};
  for (int e = 0; e < 10; e++) { ct.p[e] = d_in[srcs[e]]; ct.flagidx[e] = srcs[e]; ct.dstoff[e] = offs[e]; ct.n[e] = lens[e]; }
  cvt_small<<<dim3(10), 256, 0, stream>>>(ct, svec, flags);

  // ---- src -> bf16 ----
  cvt_src<<<dim3(TOK * 1024 / (256 * 8)), 256, 0, stream>>>(d_in[0], src_bf, &flags[0]);

  // qkv = src @ Wqkv + b: Q|K -> qk [8192][2048], V -> Vt transposed (mode 1)
  // gemm_bt: 32KB LDS -> 5 blocks/CU implicit overlap; 64x24 = 1536 blocks
  gemm_bt<<<dim3(64, 24), 256, 0, stream>>>(src_bf, Wqkv_t, bqkv, qk, TOK, 3072, 1024, 0,
                                            2048, Vt, 1);
  // attention [8192,1024]; grid: bh-major keeps one (b,h)'s K/V on one XCD's L2
  attn_fwd<<<dim3(128, 8), 256, 0, stream>>>(qk, Vt, attnb);
  // proj = attn @ Wo + bo  (256x128 tile: 32x8 = 256 blocks = 1 full round)
  gemm256x128<<<dim3(256), 512, 0, stream>>>(attnb, Wo_t, bo_c, proj, TOK, 1024, 1024, 0);
  // x = LN(src + proj)
  add_ln<<<dim3(TOK), 256, 0, stream>>>(src_bf, proj, g1_c, be1_c, x);
  // FF chunked by CH rows
  for (int c = 0; c < TOK / CH; c++) {
    const u16* xc = x + (size_t)c * CH * 1024;
    u16* f2c = f2 + (size_t)c * CH * 1024;
    if (CH >= 4096) {
      gemm256w<<<dim3((CH / 256) * 16), 512, 0, stream>>>(xc, W1_t, b1_c, h1, CH, 4096, 1024, 1);
    } else {
      gemm_bt<<<dim3(CH / 128, 32), 256, 0, stream>>>(xc, W1_t, b1_c, h1, CH, 4096, 1024, 1,
                                                      4096, nullptr, 0);
    }
    if (CH == 8192) {
      gemm256x128<<<dim3((CH / 256) * 8), 512, 0, stream>>>(h1, W2_t, b2_c, f2c, CH, 1024, 4096, 0);
    } else {
      gemm_bt<<<dim3(CH / 128, 8), 256, 0, stream>>>(h1, W2_t, b2_c, f2c, CH, 1024, 4096, 0,
                                                     1024, nullptr, 0);
    }
  }
  // out = LN(x + f2), stored in src's container dtype
  add_ln_out<<<dim3(TOK), 256, 0, stream>>>(x, f2, g2_c, be2_c, d_out, &flags[0]);
  diag_mixed<<<1, 1, 0, stream>>>(flags, d_out);
}

// Round 6
// 577.576 us; speedup vs baseline: 1.0297x; 1.0297x over previous
//
#include <hip/hip_runtime.h>

// B=8 S=1024 D=1024 H=16 DK=64 F=4096 -- fp32 containers (bf16-valued), detected per-tensor
#define Bq 8
#define Sq 1024
#define Dq 1024
#define Hq 16
#define DKq 64
#define Fq 4096
#define TOK (Bq*Sq)   // 8192

typedef unsigned short u16;
typedef unsigned int u32;
typedef __bf16 bf16x8 __attribute__((ext_vector_type(8)));
typedef float  f32x4  __attribute__((ext_vector_type(4)));

__device__ __forceinline__ float bf2f(u16 u) {
  u32 x = ((u32)u) << 16;
  float f; __builtin_memcpy(&f, &x, 4); return f;
}
__device__ __forceinline__ u16 f2bf(float f) {
  u32 u; __builtin_memcpy(&u, &f, 4);
  u += 0x7fffu + ((u >> 16) & 1u);
  return (u16)(u >> 16);
}
// async global->LDS, 16B/lane; LDS dest = wave-uniform base + lane*16
__device__ __forceinline__ void async16(const u16* g, u16* l) {
  __builtin_amdgcn_global_load_lds(
      (__attribute__((address_space(1))) void*)(g),
      (__attribute__((address_space(3))) void*)(l), 16, 0, 0);
}
__device__ __forceinline__ u16 load_in(const void* p, long idx, u32 fp32) {
  return fp32 ? f2bf(((const float*)p)[idx]) : ((const u16*)p)[idx];
}
// XOR-swizzled byte offset within a [rows][64 bf16] tile (128B rows)
__device__ __forceinline__ int swzb(int row, int colb) {
  return row * 128 + (colb ^ ((row & 7) << 4));
}

// ---------------- dtype detection: one launch, 17 blocks ----------------
struct InTab { const void* p[17]; int n[17]; };

__global__ void detect_all(InTab tab, u32* flags) {
  __shared__ int sh[3][256];
  int bi = blockIdx.x;
  const u16* buf = (const u16*)tab.p[bi];
  long n = tab.n[bi];
  long m = n < 65536 ? n : 65536;
  int t = threadIdx.x;
  int nanpat = 0, evz = 0, oddnz = 0;
  for (long i = t; i < m; i += 256) {
    u16 v = buf[i];
    if ((v & 0x7F80u) == 0x7F80u) nanpat++;
    if ((i & 1) == 0) { if (v == 0) evz++; }
    else { if (v != 0) oddnz++; }
  }
  sh[0][t] = nanpat; sh[1][t] = evz; sh[2][t] = oddnz;
  __syncthreads();
  for (int s = 128; s > 0; s >>= 1) {
    if (t < s) { sh[0][t] += sh[0][t+s]; sh[1][t] += sh[1][t+s]; sh[2][t] += sh[2][t+s]; }
    __syncthreads();
  }
  if (t == 0) {
    long half = m / 2;
    bool fp32 = (sh[0][0] > 8) ||
                (sh[1][0] > (half * 9) / 10 && sh[2][0] > (half * 9) / 10);
    flags[bi] = fp32 ? 1u : 0u;
  }
}

__global__ void diag_ws_too_small(u16* out, float code) { out[0] = f2bf(code); }

__global__ void diag_mixed(const u32* flags, void* out) {
  u32 a = flags[0];
  if (flags[1] != a || flags[7] != a || flags[11] != a || flags[13] != a) {
    if (a) ((float*)out)[0] = 3000.0f;
    else ((u16*)out)[0] = f2bf(3000.0f);
  }
}

// ---------------- batched LDS-tiled transpose pack (single launch) ----------------
// 3072 tile-jobs of 64x64: [0,768) Wq/Wk/Wv slices, [768,1024) Wo, [1024,2048) W1, [2048,3072) W2
__global__ __launch_bounds__(256) void pack_all(const void* __restrict__ Wq,
                                                const void* __restrict__ Wk,
                                                const void* __restrict__ Wv,
                                                const void* __restrict__ Wo,
                                                const void* __restrict__ W1,
                                                const void* __restrict__ W2,
                                                u16* __restrict__ Wqkv_t,
                                                u16* __restrict__ Wo_t,
                                                u16* __restrict__ W1_t,
                                                u16* __restrict__ W2_t,
                                                const u32* __restrict__ flags) {
  int id = blockIdx.x;
  const void* in; u16* out; u32 f; int R, C; long zin; int r0, c0;
  if (id < 768) {            // Wq/Wk/Wv: [16 h][1024 d][64 dk] -> [h*64+dk][d]
    int w = id >> 8, t = id & 255;
    int z = t >> 4, xt = t & 15;
    in = (w == 0) ? Wq : ((w == 1) ? Wk : Wv);
    f = flags[(w == 0) ? 1 : ((w == 1) ? 3 : 5)];
    R = 1024; C = 64;
    zin = (long)z * 65536;
    out = Wqkv_t + (long)w * 1048576 + (long)z * 65536;
    r0 = xt * 64; c0 = 0;
  } else if (id < 1024) {    // Wo [1024][1024]
    int t = id - 768; int xt = t & 15, yt = t >> 4;
    in = Wo; f = flags[7]; R = 1024; C = 1024; zin = 0; out = Wo_t;
    r0 = xt * 64; c0 = yt * 64;
  } else if (id < 2048) {    // W1 [1024][4096]
    int t = id - 1024; int xt = t & 15, yt = t >> 4;
    in = W1; f = flags[11]; R = 1024; C = 4096; zin = 0; out = W1_t;
    r0 = xt * 64; c0 = yt * 64;
  } else {                   // W2 [4096][1024]
    int t = id - 2048; int xt = t & 63, yt = t >> 6;
    in = W2; f = flags[13]; R = 4096; C = 1024; zin = 0; out = W2_t;
    r0 = xt * 64; c0 = yt * 64;
  }
  __shared__ u16 tile[64][65];
  int tx = threadIdx.x & 63, ty = threadIdx.x >> 6;
#pragma unroll
  for (int it = 0; it < 16; it++) {
    int row = it * 4 + ty;
    tile[row][tx] = load_in(in, zin + (long)(r0 + row) * C + (c0 + tx), f);
  }
  __syncthreads();
#pragma unroll
  for (int it = 0; it < 16; it++) {
    int cc = it * 4 + ty;
    out[(long)(c0 + cc) * R + r0 + tx] = tile[tx][cc];
  }
}

// ---------------- merged small-vector cvt ----------------
struct CvtTab { const void* p[10]; int flagidx[10]; int dstoff[10]; int n[10]; };
__global__ void cvt_small(CvtTab tab, u16* __restrict__ dst, const u32* __restrict__ flags) {
  int e = blockIdx.x;
  u32 f = flags[tab.flagidx[e]];
  const void* p = tab.p[e];
  int n = tab.n[e], o = tab.dstoff[e];
  for (int i = threadIdx.x; i < n; i += 256) dst[o + i] = load_in(p, i, f);
}

// ---------------- vectorized src cvt (8 elems/thread) ----------------
__global__ __launch_bounds__(256) void cvt_src(const void* __restrict__ in,
                                               u16* __restrict__ out,
                                               const u32* __restrict__ flag) {
  u32 f = *flag;
  long i8 = ((long)blockIdx.x * 256 + threadIdx.x) * 8;
  if (f) {
    const float4* f4 = (const float4*)((const float*)in + i8);
    float4 a = f4[0], b = f4[1];
    u16 v[8] = {f2bf(a.x), f2bf(a.y), f2bf(a.z), f2bf(a.w),
                f2bf(b.x), f2bf(b.y), f2bf(b.z), f2bf(b.w)};
    *(uint4*)(out + i8) = *(const uint4*)v;
  } else {
    *(uint4*)(out + i8) = *(const uint4*)((const u16*)in + i8);
  }
}

// ---------------- GEMM: C[M,N] = A[M,K] @ Bt[N,K]^T + bias, optional ReLU --------
// 128x128 tile, BK=32, double-buffered LDS. Kept only for chunked fallbacks.
__global__ __launch_bounds__(256) void gemm_bt(const u16* __restrict__ A,
                                               const u16* __restrict__ Bt,
                                               const u16* __restrict__ bias,
                                               u16* __restrict__ C,
                                               int M, int N, int K, int act,
                                               int ldc) {
  __shared__ alignas(16) u16 sA[2][128 * 32];
  __shared__ alignas(16) u16 sB[2][128 * 32];
  const int tid = threadIdx.x;
  const int wv = tid >> 6, lane = tid & 63;
  const int m16 = lane & 15, quad = lane >> 4;
  const long bm = (long)blockIdx.x * 128;
  const long bn = (long)blockIdx.y * 128;
  const int wm = (wv >> 1) * 64, wn = (wv & 1) * 64;

  f32x4 acc[4][4];
#pragma unroll
  for (int i = 0; i < 4; i++)
#pragma unroll
    for (int j = 0; j < 4; j++) acc[i][j] = (f32x4){0.f, 0.f, 0.f, 0.f};

  const int row_s = tid >> 2;          // 0..63
  const int col_s = (tid & 3) * 8;
  const u16* gA0 = A + (bm + row_s) * (long)K + col_s;
  const u16* gA1 = gA0 + 64 * (long)K;
  const u16* gB0 = Bt + (bn + row_s) * (long)K + col_s;
  const u16* gB1 = gB0 + 64 * (long)K;

  auto stage = [&](int p, int k) {
    async16(gA0 + k, &sA[p][wv * 512]);
    async16(gA1 + k, &sA[p][2048 + wv * 512]);
    async16(gB0 + k, &sB[p][wv * 512]);
    async16(gB1 + k, &sB[p][2048 + wv * 512]);
  };
  auto compute = [&](int p) {
    bf16x8 af[4], bf_[4];
#pragma unroll
    for (int mi = 0; mi < 4; mi++)
      af[mi] = *(const bf16x8*)&sA[p][(wm + mi * 16 + m16) * 32 + quad * 8];
#pragma unroll
    for (int ni = 0; ni < 4; ni++)
      bf_[ni] = *(const bf16x8*)&sB[p][(wn + ni * 16 + m16) * 32 + quad * 8];
#pragma unroll
    for (int mi = 0; mi < 4; mi++)
#pragma unroll
      for (int ni = 0; ni < 4; ni++)
        acc[mi][ni] = __builtin_amdgcn_mfma_f32_16x16x32_bf16(af[mi], bf_[ni], acc[mi][ni], 0, 0, 0);
  };

  stage(0, 0);
  for (int k0 = 0; k0 < K; k0 += 64) {   // K is a multiple of 64 (1024/4096)
    __syncthreads();                     // drains stage(0,k0); protects buf1 from prev iter
    if (k0 + 32 < K) stage(1, k0 + 32);
    compute(0);
    __syncthreads();                     // drains stage(1); protects buf0
    if (k0 + 64 < K) stage(0, k0 + 64);
    compute(1);
  }

  float bv4[4];
#pragma unroll
  for (int ni = 0; ni < 4; ni++) bv4[ni] = bf2f(bias[bn + wn + ni * 16 + m16]);

#pragma unroll
  for (int mi = 0; mi < 4; mi++) {
#pragma unroll
    for (int ni = 0; ni < 4; ni++) {
      long col = bn + wn + ni * 16 + m16;
      long rowb = bm + wm + mi * 16 + quad * 4;
#pragma unroll
      for (int r = 0; r < 4; r++) {
        float v = acc[mi][ni][r] + bv4[ni];
        if (act) v = fmaxf(v, 0.f);
        C[(rowb + r) * (long)ldc + col] = f2bf(v);
      }
    }
  }
}

// ---------------- GEMM 256x256, BK=64, 8-wave, 4-phase counted-vmcnt schedule ----
// (restored R4-verified version: 87 us @ FF1/QKV, no spill -- the 2-phase variant
//  regressed to 116 us via scratch spill: 96 frag-VGPRs live > 128 cap)
// mode 0: C[row*ldc+col]. mode 1 (QKV): cols<2048 -> C (ldc=2048, Q|K),
//   cols>=2048 -> V stored TRANSPOSED into Vt[b*16+h][dk][s].
#define MF16 __builtin_amdgcn_mfma_f32_16x16x32_bf16

#define TILE256(BUF, NBUF, DOA, DOB, KA, KB, VMS)                              \
  {                                                                            \
    /* p0: read A mi0-3 + B ni0-1, stage A-half0 of next tile */               \
    _Pragma("unroll") for (int mi = 0; mi < 4; mi++)                           \
      _Pragma("unroll") for (int kk = 0; kk < 2; kk++)                         \
        afr[mi][kk] = *(const bf16x8*)&sA[BUF][offA + mi * 1024 + kof[kk]];    \
    _Pragma("unroll") for (int ni = 0; ni < 2; ni++)                           \
      _Pragma("unroll") for (int kk = 0; kk < 2; kk++)                         \
        bfr[ni][kk] = *(const bf16x8*)&sB[BUF][offB + ni * 1024 + kof[kk]];    \
    if (DOA) stA(NBUF, 0, KA);                                                 \
    __builtin_amdgcn_s_barrier();                                              \
    __builtin_amdgcn_s_setprio(1);                                             \
    _Pragma("unroll") for (int kk = 0; kk < 2; kk++)                           \
      _Pragma("unroll") for (int mi = 0; mi < 4; mi++)                         \
        _Pragma("unroll") for (int ni = 0; ni < 2; ni++)                       \
          acc[mi][ni] = MF16(afr[mi][kk], bfr[ni][kk], acc[mi][ni], 0, 0, 0);  \
    __builtin_amdgcn_s_setprio(0);                                             \
    __builtin_amdgcn_s_barrier();                                              \
    /* p1: read B ni2-3 (A held), stage A-half1 */                             \
    _Pragma("unroll") for (int ni = 0; ni < 2; ni++)                           \
      _Pragma("unroll") for (int kk = 0; kk < 2; kk++)                         \
        bfr[2 + ni][kk] = *(const bf16x8*)&sB[BUF][offB + (2 + ni) * 1024 + kof[kk]]; \
    if (DOA) stA(NBUF, 1, KA);                                                 \
    __builtin_amdgcn_s_barrier();                                              \
    __builtin_amdgcn_s_setprio(1);                                             \
    _Pragma("unroll") for (int kk = 0; kk < 2; kk++)                           \
      _Pragma("unroll") for (int mi = 0; mi < 4; mi++)                         \
        _Pragma("unroll") for (int ni = 0; ni < 2; ni++)                       \
          acc[mi][2 + ni] = MF16(afr[mi][kk], bfr[2 + ni][kk], acc[mi][2 + ni], 0, 0, 0); \
    __builtin_amdgcn_s_setprio(0);                                             \
    __builtin_amdgcn_s_barrier();                                              \
    /* p2: read A mi4-7 (B held), stage B-half0 of tile T+2 (B of T read-done @p1) */ \
    _Pragma("unroll") for (int mi = 0; mi < 4; mi++)                           \
      _Pragma("unroll") for (int kk = 0; kk < 2; kk++)                         \
        afr[mi][kk] = *(const bf16x8*)&sA[BUF][offA + (4 + mi) * 1024 + kof[kk]]; \
    if (DOB) stB(BUF, 0, KB);                                                  \
    __builtin_amdgcn_s_barrier();                                              \
    __builtin_amdgcn_s_setprio(1);                                             \
    _Pragma("unroll") for (int kk = 0; kk < 2; kk++)                           \
      _Pragma("unroll") for (int mi = 0; mi < 4; mi++)                         \
        _Pragma("unroll") for (int ni = 0; ni < 2; ni++)                       \
          acc[4 + mi][2 + ni] = MF16(afr[mi][kk], bfr[2 + ni][kk], acc[4 + mi][2 + ni], 0, 0, 0); \
    __builtin_amdgcn_s_setprio(0);                                             \
    __builtin_amdgcn_s_barrier();                                              \
    /* p3: no reads, stage B-half1, counted vmcnt fence for next tile */       \
    if (DOB) stB(BUF, 1, KB);                                                  \
    asm volatile("s_waitcnt vmcnt(" VMS ")" ::: "memory");                     \
    __builtin_amdgcn_s_barrier();                                              \
    __builtin_amdgcn_s_setprio(1);                                             \
    _Pragma("unroll") for (int kk = 0; kk < 2; kk++)                           \
      _Pragma("unroll") for (int mi = 0; mi < 4; mi++)                         \
        _Pragma("unroll") for (int ni = 0; ni < 2; ni++)                       \
          acc[4 + mi][ni] = MF16(afr[mi][kk], bfr[ni][kk], acc[4 + mi][ni], 0, 0, 0); \
    __builtin_amdgcn_s_setprio(0);                                             \
    __builtin_amdgcn_s_barrier();                                              \
  }

__global__ __launch_bounds__(512, 2) void gemm256(const u16* __restrict__ A,
                                                  const u16* __restrict__ Bt,
                                                  const u16* __restrict__ bias,
                                                  u16* __restrict__ C,
                                                  int M, int N, int K, int act,
                                                  int ldc, u16* __restrict__ Vt,
                                                  int mode) {
  __shared__ alignas(16) u16 sA[2][16384];   // 2 x [2 halves][128 rows][64 cols]
  __shared__ alignas(16) u16 sB[2][16384];
  const int tid = threadIdx.x;
  const int wv = tid >> 6, lane = tid & 63;
  const int m16 = lane & 15, quad = lane >> 4;
  const int wr = wv >> 2, wc = wv & 3;

  // T1: bijective XCD-aware remap of the linear block id (tn fastest)
  const int NT = N >> 8;
  int bid = blockIdx.x;
  {
    const int nwg = gridDim.x;
    const int q = nwg >> 3, r = nwg & 7;
    const int xcd = bid & 7, lp = bid >> 3;
    bid = (xcd < r ? xcd * (q + 1) : r * (q + 1) + (xcd - r) * q) + lp;
  }
  const long bm = (long)(bid / NT) * 256;
  const long bn = (long)(bid % NT) * 256;

  // staging: linear LDS dest, inverse-swizzled global source (rule: both-sides)
  const int r0 = wv * 16 + (lane >> 3);             // row within 128-row half
  const int cstg = ((lane & 7) ^ (lane >> 3)) * 8;  // swizzled col (elements)
  const u16* gA0 = A  + (bm + r0) * (long)K + cstg;
  const u16* gA1 = A  + (bm + 128 + r0) * (long)K + cstg;
  const u16* gB0 = Bt + (bn + r0) * (long)K + cstg;
  const u16* gB1 = Bt + (bn + 128 + r0) * (long)K + cstg;
  const long k8 = 8 * (long)K;

  auto stA = [&](int nb, int h, int k0) {
    const u16* s = (h ? gA1 : gA0) + k0;
    u16* d = &sA[nb][h * 8192 + wv * 1024];
    async16(s, d);
    async16(s + k8, d + 512);
  };
  auto stB = [&](int nb, int h, int k0) {
    const u16* s = (h ? gB1 : gB0) + k0;
    u16* d = &sB[nb][h * 8192 + wv * 1024];
    async16(s, d);
    async16(s + k8, d + 512);
  };

  // fragment-read addressing (swizzled): granule(kk) = (kk*4+quad)^(m16&7)
  const int qs = quad ^ (m16 & 3);
  const int hb = (m16 >> 2) & 1;
  const int kof[2] = {hb * 32, 32 - hb * 32};
  const int offA = wr * 8192 + m16 * 64 + qs * 8;                    // + mi*1024
  const int offB = (wc >> 1) * 8192 + (wc & 1) * 4096 + m16 * 64 + qs * 8; // + ni*1024

  f32x4 acc[8][4];
#pragma unroll
  for (int i = 0; i < 8; i++)
#pragma unroll
    for (int j = 0; j < 4; j++) acc[i][j] = (f32x4){0.f, 0.f, 0.f, 0.f};
  bf16x8 afr[4][2], bfr[4][2];

  const int KT = K >> 6;   // K-tiles of 64; K multiple of 128, KT even >= 2

  // prologue: tile0 (A0,A1,B0,B1) -> buf0; B halves of tile1 -> buf1
  stA(0, 0, 0); stA(0, 1, 0); stB(0, 0, 0); stB(0, 1, 0);
  stB(1, 0, 64); stB(1, 1, 64);
  asm volatile("s_waitcnt vmcnt(4)" ::: "memory");   // tile0 landed; B(tile1) in flight
  __builtin_amdgcn_s_barrier();

  int T = 0;
  for (; T + 2 < KT; T += 2) {
    const int kA1 = (T + 1) << 6, kB2 = (T + 2) << 6, kB3 = (T + 3) << 6;
    TILE256(0, 1, true, true, kA1, kB2, "4");
    TILE256(1, 0, true, true, kB2, kB3, "4");
  }
  {  // tail pair (T = KT-2): no B stages remain -> must drain fully
    const int kA1 = (T + 1) << 6;
    TILE256(0, 1, true, false, kA1, 0, "0");
    TILE256(1, 0, false, false, 0, 0, "0");
  }

  float bv4[4];
#pragma unroll
  for (int ni = 0; ni < 4; ni++) bv4[ni] = bf2f(bias[bn + wc * 64 + ni * 16 + m16]);

#pragma unroll
  for (int mi = 0; mi < 8; mi++) {
#pragma unroll
    for (int ni = 0; ni < 4; ni++) {
      long col = bn + wc * 64 + ni * 16 + m16;
      long rowb = bm + wr * 128 + mi * 16 + quad * 4;
      if (mode == 1 && col >= 2048) {
        // V -> Vt[(b*16+h)][dk][s], 4 acc rows = consecutive s
        int hh = ((int)col >> 6) & 15, dk = (int)col & 63;
        int bb = (int)(rowb >> 10), ss = (int)(rowb & 1023);
        u16 t4[4];
#pragma unroll
        for (int r = 0; r < 4; r++) t4[r] = f2bf(acc[mi][ni][r] + bv4[ni]);
        *(uint2*)&Vt[(((long)bb * 16 + hh) * 64 + dk) * 1024 + ss] = *(const uint2*)t4;
      } else {
#pragma unroll
        for (int r = 0; r < 4; r++) {
          float v = acc[mi][ni][r] + bv4[ni];
          if (act) v = fmaxf(v, 0.f);
          C[(rowb + r) * (long)ldc + col] = f2bf(v);
        }
      }
    }
  }
}

// ---------------- GEMM 256x128, BK=64, 8-wave, counted-vmcnt schedule ----------
// For N=1024 GEMMs (FF2, Wo): grid = (M/256)*(N/128) = 256 blocks = 1 full round.
#define TILE128(BUF, NBUF, DOA, DOB, KA, KB, VMS)                              \
  {                                                                            \
    /* p0: read A mi0-3 + B ni0-1; stage A-half0(T+1) */                       \
    _Pragma("unroll") for (int mi = 0; mi < 4; mi++)                           \
      _Pragma("unroll") for (int kk = 0; kk < 2; kk++)                         \
        afr[mi][kk] = *(const bf16x8*)&sA[BUF][offA + mi * 1024 + kof[kk]];    \
    _Pragma("unroll") for (int ni = 0; ni < 2; ni++)                           \
      _Pragma("unroll") for (int kk = 0; kk < 2; kk++)                         \
        bfr[ni][kk] = *(const bf16x8*)&sB[BUF][offB + ni * 1024 + kof[kk]];    \
    if (DOA) stA(NBUF, 0, KA);                                                 \
    __builtin_amdgcn_s_barrier();                                              \
    __builtin_amdgcn_s_setprio(1);                                             \
    _Pragma("unroll") for (int kk = 0; kk < 2; kk++)                           \
      _Pragma("unroll") for (int mi = 0; mi < 4; mi++)                         \
        _Pragma("unroll") for (int ni = 0; ni < 2; ni++)                       \
          acc[mi][ni] = MF16(afr[mi][kk], bfr[ni][kk], acc[mi][ni], 0, 0, 0);  \
    __builtin_amdgcn_s_setprio(0);                                             \
    __builtin_amdgcn_s_barrier();                                              \
    /* p1: read B ni2-3 (A held); stage A-half1(T+1) */                        \
    _Pragma("unroll") for (int ni = 0; ni < 2; ni++)                           \
      _Pragma("unroll") for (int kk = 0; kk < 2; kk++)                         \
        bfr[2 + ni][kk] = *(const bf16x8*)&sB[BUF][offB + (2 + ni) * 1024 + kof[kk]]; \
    if (DOA) stA(NBUF, 1, KA);                                                 \
    __builtin_amdgcn_s_barrier();                                              \
    __builtin_amdgcn_s_setprio(1);                                             \
    _Pragma("unroll") for (int kk = 0; kk < 2; kk++)                           \
      _Pragma("unroll") for (int mi = 0; mi < 4; mi++)                         \
        _Pragma("unroll") for (int ni = 0; ni < 2; ni++)                       \
          acc[mi][2 + ni] = MF16(afr[mi][kk], bfr[2 + ni][kk], acc[mi][2 + ni], 0, 0, 0); \
    __builtin_amdgcn_s_setprio(0);                                             \
    __builtin_amdgcn_s_barrier();                                              \
    /* p2: stage B(T+2) into BUF (same parity); counted fence */               \
    if (DOB) stB(BUF, KB);                                                     \
    asm volatile("s_waitcnt vmcnt(" VMS ")" ::: "memory");                     \
    __builtin_amdgcn_s_barrier();                                              \
  }

__global__ __launch_bounds__(512, 2) void gemm256x128(const u16* __restrict__ A,
                                                      const u16* __restrict__ Bt,
                                                      const u16* __restrict__ bias,
                                                      u16* __restrict__ C,
                                                      int M, int N, int K, int act) {
  __shared__ alignas(16) u16 sA[2][16384];   // [2 halves][128 rows][64 cols] swz
  __shared__ alignas(16) u16 sB[2][8192];    // [128 rows][64 cols] swz
  const int tid = threadIdx.x;
  const int wv = tid >> 6, lane = tid & 63;
  const int m16 = lane & 15, quad = lane >> 4;
  const int wr = wv >> 1, wc = wv & 1;       // 4M x 2N waves, 64x64 each

  const int NT = N >> 7;
  int bid = blockIdx.x;
  {
    const int nwg = gridDim.x;
    const int q = nwg >> 3, r = nwg & 7;
    const int xcd = bid & 7, lp = bid >> 3;
    bid = (xcd < r ? xcd * (q + 1) : r * (q + 1) + (xcd - r) * q) + lp;
  }
  const long bm = (long)(bid / NT) * 256;
  const long bn = (long)(bid % NT) * 128;

  const int r0 = wv * 16 + (lane >> 3);
  const int cstg = ((lane & 7) ^ (lane >> 3)) * 8;
  const u16* gA0 = A + (bm + r0) * (long)K + cstg;
  const u16* gA1 = A + (bm + 128 + r0) * (long)K + cstg;
  const u16* gB0 = Bt + (bn + r0) * (long)K + cstg;
  const long k8 = 8 * (long)K;

  auto stA = [&](int nb, int h, int k0) {
    const u16* s = (h ? gA1 : gA0) + k0;
    u16* d = &sA[nb][h * 8192 + wv * 1024];
    async16(s, d);
    async16(s + k8, d + 512);
  };
  auto stB = [&](int nb, int k0) {
    const u16* s = gB0 + k0;
    u16* d = &sB[nb][wv * 1024];
    async16(s, d);
    async16(s + k8, d + 512);
  };

  const int qs = quad ^ (m16 & 3);
  const int hb = (m16 >> 2) & 1;
  const int kof[2] = {hb * 32, 32 - hb * 32};
  const int offA = (wr >> 1) * 8192 + (wr & 1) * 4096 + m16 * 64 + qs * 8; // +mi*1024
  const int offB = wc * 4096 + m16 * 64 + qs * 8;                          // +ni*1024

  f32x4 acc[4][4];
#pragma unroll
  for (int i = 0; i < 4; i++)
#pragma unroll
    for (int j = 0; j < 4; j++) acc[i][j] = (f32x4){0.f, 0.f, 0.f, 0.f};
  bf16x8 afr[4][2], bfr[4][2];

  const int KT = K >> 6;   // even (K multiple of 128)

  // prologue: tile0 (A0,A1,B) -> buf0; B(tile1) -> buf1
  stA(0, 0, 0); stA(0, 1, 0); stB(0, 0);
  stB(1, 64);
  asm volatile("s_waitcnt vmcnt(2)" ::: "memory");   // tile0 landed; B(1) in flight
  __builtin_amdgcn_s_barrier();

  int T = 0;
  for (; T + 2 < KT; T += 2) {
    TILE128(0, 1, true, true, (T + 1) << 6, (T + 2) << 6, "2");
    TILE128(1, 0, true, true, (T + 2) << 6, (T + 3) << 6, "2");
  }
  // tail pair: tile KT-2 stages only A(KT-1); must drain fully
  TILE128(0, 1, true, false, (T + 1) << 6, 0, "0");
  TILE128(1, 0, false, false, 0, 0, "0");

  float bv4[4];
#pragma unroll
  for (int ni = 0; ni < 4; ni++) bv4[ni] = bf2f(bias[bn + wc * 64 + ni * 16 + m16]);

#pragma unroll
  for (int mi = 0; mi < 4; mi++) {
#pragma unroll
    for (int ni = 0; ni < 4; ni++) {
      long col = bn + wc * 64 + ni * 16 + m16;
      long rowb = bm + wr * 64 + mi * 16 + quad * 4;
#pragma unroll
      for (int r = 0; r < 4; r++) {
        float v = acc[mi][ni][r] + bv4[ni];
        if (act) v = fmaxf(v, 0.f);
        C[(rowb + r) * (long)N + col] = f2bf(v);
      }
    }
  }
}

// ---------------- flash attention v2: 128q blocks, 32q/wave, V^T pre-staged ----
// qk: [8192][2048] (Q|K per token), Vt: [b*16+h][64 dk][1024 s] (from QKV GEMM).
__global__ __launch_bounds__(256, 4) void attn_fwd(const u16* __restrict__ qk,
                                                   const u16* __restrict__ Vt,
                                                   u16* __restrict__ attnO) {
  __shared__ alignas(16) u16 sQP[8192];  // Q [128][64] swz; later per-wave P[32][64] @ wv*4096B
  __shared__ alignas(16) u16 sK[4096];   // [64 key][64 dk] swz
  __shared__ alignas(16) u16 sVt[4096];  // [64 dk][64 key] swz
  const int tid = threadIdx.x;
  const int bh = blockIdx.x;
  const int qt = blockIdx.y;
  const int b = bh >> 4, h = bh & 15;
  const int wv = tid >> 6, lane = tid & 63;
  const int m16 = lane & 15, quad = lane >> 4;
  const int kk = tid >> 3;               // staging row 0..31
  const int t7 = tid & 7;

  char* cQP = (char*)sQP;
  char* cK = (char*)sK;
  char* cV = (char*)sVt;

  // ---- stage Q [128 q][64 dk], scaled by 1/sqrt(DK)=0.125, swizzled ----
  {
    int row = tid >> 1, half = tid & 1;
    const u16* g = qk + (long)(b * Sq + qt * 128 + row) * 2048 + h * 64 + half * 32;
#pragma unroll
    for (int j = 0; j < 4; j++) {
      uint4 raw = *(const uint4*)(g + j * 8);
      const u16* pv = (const u16*)&raw;
      u16 t[8];
#pragma unroll
      for (int e = 0; e < 8; e++) t[e] = f2bf(bf2f(pv[e]) * 0.125f);
      *(uint4*)(cQP + swzb(row, half * 64 + j * 16)) = *(const uint4*)t;
    }
  }
  __syncthreads();
  // Q frags: qf[qt2][s] = Q[wv*32 + qt2*16 + m16][s*32 + quad*8 ..]
  bf16x8 qf[2][2];
#pragma unroll
  for (int qt2 = 0; qt2 < 2; qt2++)
#pragma unroll
    for (int s = 0; s < 2; s++)
      qf[qt2][s] = *(const bf16x8*)(cQP + swzb(wv * 32 + qt2 * 16 + m16, s * 64 + quad * 16));

  f32x4 o[4][2];
#pragma unroll
  for (int dt = 0; dt < 4; dt++)
#pragma unroll
    for (int qt2 = 0; qt2 < 2; qt2++) o[dt][qt2] = (f32x4){0.f, 0.f, 0.f, 0.f};
  float mrun[2] = {-1e30f, -1e30f}, lrun[2] = {0.f, 0.f};

  const u16* gK = qk + (long)(b * Sq + kk) * 2048 + 1024 + h * 64 + t7 * 8;
  const u16* gV = Vt + ((long)bh * 64 + kk) * 1024 + t7 * 8;
  const long stepK = (long)64 * 2048;
  const int off0 = swzb(kk, t7 * 16);        // (kk+32)&7 == kk&7 -> +4096 bytes
  const int off1 = off0 + 4096;

  uint4 rk0 = *(const uint4*)gK;
  uint4 rk1 = *(const uint4*)(gK + 32 * 2048);
  uint4 rv0 = *(const uint4*)gV;
  uint4 rv1 = *(const uint4*)(gV + 32 * 1024);

  for (int kt = 0; kt < 16; kt++) {
    __syncthreads();   // previous iteration's K/V frag reads done
    *(uint4*)(cK + off0) = rk0;
    *(uint4*)(cK + off1) = rk1;
    *(uint4*)(cV + off0) = rv0;
    *(uint4*)(cV + off1) = rv1;
    __syncthreads();   // tiles published

    // S^T[key][q]: st[kt2][qt2], col=q=qt2*16+m16, row=key=kt2*16+quad*4+r
    f32x4 st[4][2];
#pragma unroll
    for (int kt2 = 0; kt2 < 4; kt2++)
#pragma unroll
      for (int qt2 = 0; qt2 < 2; qt2++) st[kt2][qt2] = (f32x4){0.f, 0.f, 0.f, 0.f};
    __builtin_amdgcn_s_setprio(1);
#pragma unroll
    for (int s = 0; s < 2; s++) {
      bf16x8 kf[4];
#pragma unroll
      for (int kt2 = 0; kt2 < 4; kt2++)
        kf[kt2] = *(const bf16x8*)(cK + swzb(kt2 * 16 + m16, s * 64 + quad * 16));
#pragma unroll
      for (int kt2 = 0; kt2 < 4; kt2++)
#pragma unroll
        for (int qt2 = 0; qt2 < 2; qt2++)
          st[kt2][qt2] = MF16(kf[kt2], qf[qt2][s], st[kt2][qt2], 0, 0, 0);
    }
    __builtin_amdgcn_s_setprio(0);

    if (kt < 15) {     // prefetch next K/V (hidden under softmax+PV)
      rk0 = *(const uint4*)(gK + (long)(kt + 1) * stepK);
      rk1 = *(const uint4*)(gK + (long)(kt + 1) * stepK + 32 * 2048);
      rv0 = *(const uint4*)(gV + (kt + 1) * 64);
      rv1 = *(const uint4*)(gV + (kt + 1) * 64 + 32 * 1024);
    }

    // online softmax per qt2 (lane owns q = qt2*16+m16; keys split across quad)
    char* cP = cQP + wv * 4096;
#pragma unroll
    for (int qt2 = 0; qt2 < 2; qt2++) {
      float pm = st[0][qt2][0];
#pragma unroll
      for (int kt2 = 0; kt2 < 4; kt2++)
#pragma unroll
        for (int r = 0; r < 4; r++) pm = fmaxf(pm, st[kt2][qt2][r]);
      pm = fmaxf(pm, __shfl_xor(pm, 16));
      pm = fmaxf(pm, __shfl_xor(pm, 32));
      float mnew = fmaxf(mrun[qt2], pm);
      float al = __expf(mrun[qt2] - mnew);
      mrun[qt2] = mnew;
      float rs = 0.f;
#pragma unroll
      for (int kt2 = 0; kt2 < 4; kt2++) {
        u16 t4[4];
#pragma unroll
        for (int r = 0; r < 4; r++) {
          float p = __expf(st[kt2][qt2][r] - mnew);
          rs += p;
          t4[r] = f2bf(p);
        }
        *(uint2*)(cP + swzb(qt2 * 16 + m16, kt2 * 32 + quad * 8)) = *(const uint2*)t4;
      }
      rs += __shfl_xor(rs, 16);
      rs += __shfl_xor(rs, 32);
      lrun[qt2] = lrun[qt2] * al + rs;
#pragma unroll
      for (int dt = 0; dt < 4; dt++)
#pragma unroll
        for (int r = 0; r < 4; r++) o[dt][qt2][r] *= al;
    }

    // O^T[dk][q] += V^T[dk][key] * P^T : A = V^T frags, B = P frags
    bf16x8 pb[2][2];
#pragma unroll
    for (int qt2 = 0; qt2 < 2; qt2++)
#pragma unroll
      for (int ks = 0; ks < 2; ks++)
        pb[qt2][ks] = *(const bf16x8*)(cP + swzb(qt2 * 16 + m16, ks * 64 + quad * 16));
    __builtin_amdgcn_s_setprio(1);
#pragma unroll
    for (int dt = 0; dt < 4; dt++) {
      bf16x8 v0 = *(const bf16x8*)(cV + swzb(dt * 16 + m16, quad * 16));
      bf16x8 v1 = *(const bf16x8*)(cV + swzb(dt * 16 + m16, 64 + quad * 16));
#pragma unroll
      for (int qt2 = 0; qt2 < 2; qt2++) {
        o[dt][qt2] = MF16(v0, pb[qt2][0], o[dt][qt2], 0, 0, 0);
        o[dt][qt2] = MF16(v1, pb[qt2][1], o[dt][qt2], 0, 0, 0);
      }
    }
    __builtin_amdgcn_s_setprio(0);
  }

#pragma unroll
  for (int qt2 = 0; qt2 < 2; qt2++) {
    float rl = 1.f / lrun[qt2];
    long tok = (long)(b * Sq + qt * 128 + wv * 32 + qt2 * 16 + m16);
#pragma unroll
    for (int dt = 0; dt < 4; dt++) {
      u16 t4[4];
#pragma unroll
      for (int r = 0; r < 4; r++) t4[r] = f2bf(o[dt][qt2][r] * rl);
      *(uint2*)&attnO[tok * 1024 + h * 64 + dt * 16 + quad * 4] = *(const uint2*)t4;
    }
  }
}

// ---------------- add + LayerNorm (bf16 out, internal), uint2-vectorized -------
__global__ __launch_bounds__(256) void add_ln(const u16* __restrict__ X,
                                              const u16* __restrict__ Y,
                                              const u16* __restrict__ g,
                                              const u16* __restrict__ be,
                                              u16* __restrict__ out) {
  const int row = blockIdx.x;
  const int t = threadIdx.x;
  const long base = (long)row * Dq;
  const int i4 = t * 4;
  uint2 xr = *(const uint2*)&X[base + i4];
  uint2 yr = *(const uint2*)&Y[base + i4];
  const u16* xp = (const u16*)&xr;
  const u16* yp = (const u16*)&yr;
  float v[4]; float s = 0.f, ss = 0.f;
#pragma unroll
  for (int i = 0; i < 4; i++) {
    float x = bf2f(xp[i]) + bf2f(yp[i]);
    v[i] = x; s += x; ss += x * x;
  }
#pragma unroll
  for (int off = 32; off > 0; off >>= 1) { s += __shfl_down(s, off); ss += __shfl_down(ss, off); }
  __shared__ float red[8];
  int wv = t >> 6, ln = t & 63;
  if (ln == 0) { red[wv] = s; red[4 + wv] = ss; }
  __syncthreads();
  s = red[0] + red[1] + red[2] + red[3];
  ss = red[4] + red[5] + red[6] + red[7];
  float mean = s * (1.f / Dq);
  float var = ss * (1.f / Dq) - mean * mean;
  float rstd = rsqrtf(var + 1e-5f);
  uint2 gr = *(const uint2*)&g[i4];
  uint2 br = *(const uint2*)&be[i4];
  const u16* gp = (const u16*)&gr;
  const u16* bp = (const u16*)&br;
  u16 o4[4];
#pragma unroll
  for (int i = 0; i < 4; i++)
    o4[i] = f2bf((v[i] - mean) * rstd * bf2f(gp[i]) + bf2f(bp[i]));
  *(uint2*)&out[base + i4] = *(const uint2*)o4;
}

// ---------------- final add + LayerNorm, dual-dtype store, vectorized ----------
__global__ __launch_bounds__(256) void add_ln_out(const u16* __restrict__ X,
                                                  const u16* __restrict__ Y,
                                                  const u16* __restrict__ g,
                                                  const u16* __restrict__ be,
                                                  void* __restrict__ out,
                                                  const u32* __restrict__ outflag) {
  const u32 fp32 = *outflag;
  const int row = blockIdx.x;
  const int t = threadIdx.x;
  const long base = (long)row * Dq;
  const int i4 = t * 4;
  uint2 xr = *(const uint2*)&X[base + i4];
  uint2 yr = *(const uint2*)&Y[base + i4];
  const u16* xp = (const u16*)&xr;
  const u16* yp = (const u16*)&yr;
  float v[4]; float s = 0.f, ss = 0.f;
#pragma unroll
  for (int i = 0; i < 4; i++) {
    float x = bf2f(xp[i]) + bf2f(yp[i]);
    v[i] = x; s += x; ss += x * x;
  }
#pragma unroll
  for (int off = 32; off > 0; off >>= 1) { s += __shfl_down(s, off); ss += __shfl_down(ss, off); }
  __shared__ float red[8];
  int wv = t >> 6, ln = t & 63;
  if (ln == 0) { red[wv] = s; red[4 + wv] = ss; }
  __syncthreads();
  s = red[0] + red[1] + red[2] + red[3];
  ss = red[4] + red[5] + red[6] + red[7];
  float mean = s * (1.f / Dq);
  float var = ss * (1.f / Dq) - mean * mean;
  float rstd = rsqrtf(var + 1e-5f);
  uint2 gr = *(const uint2*)&g[i4];
  uint2 br = *(const uint2*)&be[i4];
  const u16* gp = (const u16*)&gr;
  const u16* bp = (const u16*)&br;
  if (fp32) {
    float4 o4;
    o4.x = (v[0] - mean) * rstd * bf2f(gp[0]) + bf2f(bp[0]);
    o4.y = (v[1] - mean) * rstd * bf2f(gp[1]) + bf2f(bp[1]);
    o4.z = (v[2] - mean) * rstd * bf2f(gp[2]) + bf2f(bp[2]);
    o4.w = (v[3] - mean) * rstd * bf2f(gp[3]) + bf2f(bp[3]);
    *(float4*)((float*)out + base + i4) = o4;
  } else {
    u16 o4[4];
#pragma unroll
    for (int i = 0; i < 4; i++)
      o4[i] = f2bf((v[i] - mean) * rstd * bf2f(gp[i]) + bf2f(bp[i]));
    *(uint2*)((u16*)out + base + i4) = *(const uint2*)o4;
  }
}

extern "C" void kernel_launch(void* const* d_in, const int* in_sizes, int n_in,
                              void* d_out, int out_size, void* d_ws, size_t ws_size,
                              hipStream_t stream) {
  char* ws = (char*)d_ws;
  size_t off = 0;
  auto alloc = [&](size_t bytes) {
    void* p = ws + off;
    off += (bytes + 255) & ~(size_t)255;
    return p;
  };
  u32* flags  = (u32*)alloc(32 * 4);
  u16* Wqkv_t = (u16*)alloc((size_t)3072 * 1024 * 2);   // 6 MB
  u16* Wo_t   = (u16*)alloc((size_t)1024 * 1024 * 2);   // 2 MB
  u16* W1_t   = (u16*)alloc((size_t)4096 * 1024 * 2);   // 8 MB
  u16* W2_t   = (u16*)alloc((size_t)1024 * 4096 * 2);   // 8 MB
  u16* svec   = (u16*)alloc((size_t)13312 * 2);         // all small vectors
  u16* src_bf = (u16*)alloc((size_t)TOK * 1024 * 2);    // 16 MB
  u16* regA   = (u16*)alloc((size_t)TOK * 4096 * 2);    // 64 MB
  size_t need_chunk2 = off;                              // h1(32MB) fits inside regA
  size_t need_full   = off + (size_t)TOK * 4096 * 2 / 2; // +32MB so h1(64MB) spans past regA

  u16* outw = (u16*)d_out;
  int CH;  // rows per FF chunk
  if (ws_size >= need_full) { CH = 8192; (void)alloc((size_t)32 << 20); }
  else if (ws_size >= need_chunk2) CH = 4096;
  else if (ws_size >= need_chunk2 - ((size_t)16 << 20)) CH = 2048;
  else {
    diag_ws_too_small<<<1, 1, 0, stream>>>(outw, 8000.0f + (float)(ws_size >> 20));
    return;
  }

  u16* qk    = regA;                          // [0,32)  Q|K per token [8192][2048]
  u16* Vt    = regA + (size_t)TOK * 2048;     // [32,48) V transposed [128][64][1024]
  u16* attnb = regA + (size_t)TOK * 3072;     // [48,64)
  u16* proj  = regA;                          // [0,16)  after qk/Vt dead
  u16* x     = regA + (size_t)TOK * 1024;     // [16,32)
  u16* h1    = regA + (size_t)TOK * 2048;     // [32,..) CH*4096*2 bytes (Vt dead by then)
  u16* f2    = src_bf;                        // src_bf dead after x computed

  u16* bqkv = svec + 0;      // 3072
  u16* bo_c = svec + 3072;
  u16* g1_c = svec + 4096;
  u16* be1_c = svec + 5120;
  u16* b1_c = svec + 6144;   // 4096
  u16* b2_c = svec + 10240;
  u16* g2_c = svec + 11264;
  u16* be2_c = svec + 12288;

  // ---- dtype detection ----
  InTab itab;
  for (int i = 0; i < 17; i++) { itab.p[i] = d_in[i]; itab.n[i] = in_sizes[i]; }
  detect_all<<<dim3(17), 256, 0, stream>>>(itab, flags);

  // ---- all weight transposes in one launch ----
  pack_all<<<dim3(3072), 256, 0, stream>>>(d_in[1], d_in[3], d_in[5], d_in[7], d_in[11], d_in[13],
                                           Wqkv_t, Wo_t, W1_t, W2_t, flags);

  // ---- small vectors ----
  CvtTab ct;
  const int srcs[10] = {2, 4, 6, 8, 9, 10, 12, 14, 15, 16};
  const int offs[10] = {0, 1024, 2048, 3072, 4096, 5120, 6144, 10240, 11264, 12288};
  const int lens[10] = {1024, 1024, 1024, 1024, 1024, 1024, 4096, 1024, 1024, 1024};
  for (int e = 0; e < 10; e++) { ct.p[e] = d_in[srcs[e]]; ct.flagidx[e] = srcs[e]; ct.dstoff[e] = offs[e]; ct.n[e] = lens[e]; }
  cvt_small<<<dim3(10), 256, 0, stream>>>(ct, svec, flags);

  // ---- src -> bf16 ----
  cvt_src<<<dim3(TOK * 1024 / (256 * 8)), 256, 0, stream>>>(d_in[0], src_bf, &flags[0]);

  // qkv = src @ Wqkv + b: Q|K -> qk [8192][2048], V -> Vt transposed (mode 1)
  gemm256<<<dim3(32 * 12), 512, 0, stream>>>(src_bf, Wqkv_t, bqkv, qk, TOK, 3072, 1024, 0,
                                             2048, Vt, 1);
  // attention [8192,1024]; grid: bh-major keeps one (b,h)'s K/V on one XCD's L2
  attn_fwd<<<dim3(128, 8), 256, 0, stream>>>(qk, Vt, attnb);
  // proj = attn @ Wo + bo  (256x128 tile: 32x8 = 256 blocks = 1 full round)
  gemm256x128<<<dim3(256), 512, 0, stream>>>(attnb, Wo_t, bo_c, proj, TOK, 1024, 1024, 0);
  // x = LN(src + proj)
  add_ln<<<dim3(TOK), 256, 0, stream>>>(src_bf, proj, g1_c, be1_c, x);
  // FF chunked by CH rows
  for (int c = 0; c < TOK / CH; c++) {
    const u16* xc = x + (size_t)c * CH * 1024;
    u16* f2c = f2 + (size_t)c * CH * 1024;
    if (CH >= 4096) {
      gemm256<<<dim3((CH / 256) * 16), 512, 0, stream>>>(xc, W1_t, b1_c, h1, CH, 4096, 1024, 1,
                                                         4096, nullptr, 0);
    } else {
      gemm_bt<<<dim3(CH / 128, 32), 256, 0, stream>>>(xc, W1_t, b1_c, h1, CH, 4096, 1024, 1, 4096);
    }
    if (CH == 8192) {
      gemm256x128<<<dim3((CH / 256) * 8), 512, 0, stream>>>(h1, W2_t, b2_c, f2c, CH, 1024, 4096, 0);
    } else {
      gemm_bt<<<dim3(CH / 128, 8), 256, 0, stream>>>(h1, W2_t, b2_c, f2c, CH, 1024, 4096, 0, 1024);
    }
  }
  // out = LN(x + f2), stored in src's container dtype
  add_ln_out<<<dim3(TOK), 256, 0, stream>>>(x, f2, g2_c, be2_c, d_out, &flags[0]);
  diag_mixed<<<1, 1, 0, stream>>>(flags, d_out);
}

// Round 7
// 573.466 us; speedup vs baseline: 1.0371x; 1.0072x over previous
//
#include <hip/hip_runtime.h>

// B=8 S=1024 D=1024 H=16 DK=64 F=4096 -- fp32 containers (bf16-valued), detected per-tensor
#define Bq 8
#define Sq 1024
#define Dq 1024
#define Hq 16
#define DKq 64
#define Fq 4096
#define TOK (Bq*Sq)   // 8192

typedef unsigned short u16;
typedef unsigned int u32;
typedef __bf16 bf16x8 __attribute__((ext_vector_type(8)));
typedef float  f32x4  __attribute__((ext_vector_type(4)));

__device__ __forceinline__ float bf2f(u16 u) {
  u32 x = ((u32)u) << 16;
  float f; __builtin_memcpy(&f, &x, 4); return f;
}
__device__ __forceinline__ u16 f2bf(float f) {
  u32 u; __builtin_memcpy(&u, &f, 4);
  u += 0x7fffu + ((u >> 16) & 1u);
  return (u16)(u >> 16);
}
// async global->LDS, 16B/lane; LDS dest = wave-uniform base + lane*16
__device__ __forceinline__ void async16(const u16* g, u16* l) {
  __builtin_amdgcn_global_load_lds(
      (__attribute__((address_space(1))) void*)(g),
      (__attribute__((address_space(3))) void*)(l), 16, 0, 0);
}
__device__ __forceinline__ u16 load_in(const void* p, long idx, u32 fp32) {
  return fp32 ? f2bf(((const float*)p)[idx]) : ((const u16*)p)[idx];
}
// XOR-swizzled byte offset within a [rows][64 bf16] tile (128B rows)
__device__ __forceinline__ int swzb(int row, int colb) {
  return row * 128 + (colb ^ ((row & 7) << 4));
}

// ---------------- dtype detection: one launch, 17 blocks ----------------
struct InTab { const void* p[17]; int n[17]; };

__global__ void detect_all(InTab tab, u32* flags) {
  __shared__ int sh[3][256];
  int bi = blockIdx.x;
  const u16* buf = (const u16*)tab.p[bi];
  long n = tab.n[bi];
  long m = n < 65536 ? n : 65536;
  int t = threadIdx.x;
  int nanpat = 0, evz = 0, oddnz = 0;
  for (long i = t; i < m; i += 256) {
    u16 v = buf[i];
    if ((v & 0x7F80u) == 0x7F80u) nanpat++;
    if ((i & 1) == 0) { if (v == 0) evz++; }
    else { if (v != 0) oddnz++; }
  }
  sh[0][t] = nanpat; sh[1][t] = evz; sh[2][t] = oddnz;
  __syncthreads();
  for (int s = 128; s > 0; s >>= 1) {
    if (t < s) { sh[0][t] += sh[0][t+s]; sh[1][t] += sh[1][t+s]; sh[2][t] += sh[2][t+s]; }
    __syncthreads();
  }
  if (t == 0) {
    long half = m / 2;
    bool fp32 = (sh[0][0] > 8) ||
                (sh[1][0] > (half * 9) / 10 && sh[2][0] > (half * 9) / 10);
    flags[bi] = fp32 ? 1u : 0u;
  }
}

__global__ void diag_ws_too_small(u16* out, float code) { out[0] = f2bf(code); }

__global__ void diag_mixed(const u32* flags, void* out) {
  u32 a = flags[0];
  if (flags[1] != a || flags[7] != a || flags[11] != a || flags[13] != a) {
    if (a) ((float*)out)[0] = 3000.0f;
    else ((u16*)out)[0] = f2bf(3000.0f);
  }
}

// ---------------- batched LDS-tiled transpose pack (single launch) ----------------
// 3072 tile-jobs of 64x64: [0,768) Wq/Wk/Wv slices, [768,1024) Wo, [1024,2048) W1, [2048,3072) W2
__global__ __launch_bounds__(256) void pack_all(const void* __restrict__ Wq,
                                                const void* __restrict__ Wk,
                                                const void* __restrict__ Wv,
                                                const void* __restrict__ Wo,
                                                const void* __restrict__ W1,
                                                const void* __restrict__ W2,
                                                u16* __restrict__ Wqkv_t,
                                                u16* __restrict__ Wo_t,
                                                u16* __restrict__ W1_t,
                                                u16* __restrict__ W2_t,
                                                const u32* __restrict__ flags) {
  int id = blockIdx.x;
  const void* in; u16* out; u32 f; int R, C; long zin; int r0, c0;
  if (id < 768) {            // Wq/Wk/Wv: [16 h][1024 d][64 dk] -> [h*64+dk][d]
    int w = id >> 8, t = id & 255;
    int z = t >> 4, xt = t & 15;
    in = (w == 0) ? Wq : ((w == 1) ? Wk : Wv);
    f = flags[(w == 0) ? 1 : ((w == 1) ? 3 : 5)];
    R = 1024; C = 64;
    zin = (long)z * 65536;
    out = Wqkv_t + (long)w * 1048576 + (long)z * 65536;
    r0 = xt * 64; c0 = 0;
  } else if (id < 1024) {    // Wo [1024][1024]
    int t = id - 768; int xt = t & 15, yt = t >> 4;
    in = Wo; f = flags[7]; R = 1024; C = 1024; zin = 0; out = Wo_t;
    r0 = xt * 64; c0 = yt * 64;
  } else if (id < 2048) {    // W1 [1024][4096]
    int t = id - 1024; int xt = t & 15, yt = t >> 4;
    in = W1; f = flags[11]; R = 1024; C = 4096; zin = 0; out = W1_t;
    r0 = xt * 64; c0 = yt * 64;
  } else {                   // W2 [4096][1024]
    int t = id - 2048; int xt = t & 63, yt = t >> 6;
    in = W2; f = flags[13]; R = 4096; C = 1024; zin = 0; out = W2_t;
    r0 = xt * 64; c0 = yt * 64;
  }
  __shared__ u16 tile[64][65];
  int tx = threadIdx.x & 63, ty = threadIdx.x >> 6;
#pragma unroll
  for (int it = 0; it < 16; it++) {
    int row = it * 4 + ty;
    tile[row][tx] = load_in(in, zin + (long)(r0 + row) * C + (c0 + tx), f);
  }
  __syncthreads();
#pragma unroll
  for (int it = 0; it < 16; it++) {
    int cc = it * 4 + ty;
    out[(long)(c0 + cc) * R + r0 + tx] = tile[tx][cc];
  }
}

// ---------------- merged small-vector cvt ----------------
struct CvtTab { const void* p[10]; int flagidx[10]; int dstoff[10]; int n[10]; };
__global__ void cvt_small(CvtTab tab, u16* __restrict__ dst, const u32* __restrict__ flags) {
  int e = blockIdx.x;
  u32 f = flags[tab.flagidx[e]];
  const void* p = tab.p[e];
  int n = tab.n[e], o = tab.dstoff[e];
  for (int i = threadIdx.x; i < n; i += 256) dst[o + i] = load_in(p, i, f);
}

// ---------------- vectorized src cvt (8 elems/thread) ----------------
__global__ __launch_bounds__(256) void cvt_src(const void* __restrict__ in,
                                               u16* __restrict__ out,
                                               const u32* __restrict__ flag) {
  u32 f = *flag;
  long i8 = ((long)blockIdx.x * 256 + threadIdx.x) * 8;
  if (f) {
    const float4* f4 = (const float4*)((const float*)in + i8);
    float4 a = f4[0], b = f4[1];
    u16 v[8] = {f2bf(a.x), f2bf(a.y), f2bf(a.z), f2bf(a.w),
                f2bf(b.x), f2bf(b.y), f2bf(b.z), f2bf(b.w)};
    *(uint4*)(out + i8) = *(const uint4*)v;
  } else {
    *(uint4*)(out + i8) = *(const uint4*)((const u16*)in + i8);
  }
}

// ---------------- GEMM: C[M,N] = A[M,K] @ Bt[N,K]^T + bias, optional ReLU --------
// 128x128 tile, BK=32, double-buffered LDS. Kept only for chunked fallbacks.
__global__ __launch_bounds__(256) void gemm_bt(const u16* __restrict__ A,
                                               const u16* __restrict__ Bt,
                                               const u16* __restrict__ bias,
                                               u16* __restrict__ C,
                                               int M, int N, int K, int act,
                                               int ldc) {
  __shared__ alignas(16) u16 sA[2][128 * 32];
  __shared__ alignas(16) u16 sB[2][128 * 32];
  const int tid = threadIdx.x;
  const int wv = tid >> 6, lane = tid & 63;
  const int m16 = lane & 15, quad = lane >> 4;
  const long bm = (long)blockIdx.x * 128;
  const long bn = (long)blockIdx.y * 128;
  const int wm = (wv >> 1) * 64, wn = (wv & 1) * 64;

  f32x4 acc[4][4];
#pragma unroll
  for (int i = 0; i < 4; i++)
#pragma unroll
    for (int j = 0; j < 4; j++) acc[i][j] = (f32x4){0.f, 0.f, 0.f, 0.f};

  const int row_s = tid >> 2;          // 0..63
  const int col_s = (tid & 3) * 8;
  const u16* gA0 = A + (bm + row_s) * (long)K + col_s;
  const u16* gA1 = gA0 + 64 * (long)K;
  const u16* gB0 = Bt + (bn + row_s) * (long)K + col_s;
  const u16* gB1 = gB0 + 64 * (long)K;

  auto stage = [&](int p, int k) {
    async16(gA0 + k, &sA[p][wv * 512]);
    async16(gA1 + k, &sA[p][2048 + wv * 512]);
    async16(gB0 + k, &sB[p][wv * 512]);
    async16(gB1 + k, &sB[p][2048 + wv * 512]);
  };
  auto compute = [&](int p) {
    bf16x8 af[4], bf_[4];
#pragma unroll
    for (int mi = 0; mi < 4; mi++)
      af[mi] = *(const bf16x8*)&sA[p][(wm + mi * 16 + m16) * 32 + quad * 8];
#pragma unroll
    for (int ni = 0; ni < 4; ni++)
      bf_[ni] = *(const bf16x8*)&sB[p][(wn + ni * 16 + m16) * 32 + quad * 8];
#pragma unroll
    for (int mi = 0; mi < 4; mi++)
#pragma unroll
      for (int ni = 0; ni < 4; ni++)
        acc[mi][ni] = __builtin_amdgcn_mfma_f32_16x16x32_bf16(af[mi], bf_[ni], acc[mi][ni], 0, 0, 0);
  };

  stage(0, 0);
  for (int k0 = 0; k0 < K; k0 += 64) {   // K is a multiple of 64 (1024/4096)
    __syncthreads();                     // drains stage(0,k0); protects buf1 from prev iter
    if (k0 + 32 < K) stage(1, k0 + 32);
    compute(0);
    __syncthreads();                     // drains stage(1); protects buf0
    if (k0 + 64 < K) stage(0, k0 + 64);
    compute(1);
  }

  float bv4[4];
#pragma unroll
  for (int ni = 0; ni < 4; ni++) bv4[ni] = bf2f(bias[bn + wn + ni * 16 + m16]);

#pragma unroll
  for (int mi = 0; mi < 4; mi++) {
#pragma unroll
    for (int ni = 0; ni < 4; ni++) {
      long col = bn + wn + ni * 16 + m16;
      long rowb = bm + wm + mi * 16 + quad * 4;
#pragma unroll
      for (int r = 0; r < 4; r++) {
        float v = acc[mi][ni][r] + bv4[ni];
        if (act) v = fmaxf(v, 0.f);
        C[(rowb + r) * (long)ldc + col] = f2bf(v);
      }
    }
  }
}

// ---------------- GEMM 256x256, BK=64, 8-wave, 4-phase counted-vmcnt schedule ----
// R7 change (single variable): explicit `s_waitcnt lgkmcnt(0)` after each opening
// barrier, before setprio+MFMA cluster -- the m201 template's exact discipline.
// Coarse drain lets the 16-MFMA cluster fire back-to-back under setprio(1) instead
// of the compiler's fine-grained lgkmcnt(N) interleaved between MFMAs.
// mode 0: C[row*ldc+col]. mode 1 (QKV): cols<2048 -> C (ldc=2048, Q|K),
//   cols>=2048 -> V stored TRANSPOSED into Vt[b*16+h][dk][s].
#define MF16 __builtin_amdgcn_mfma_f32_16x16x32_bf16

#define TILE256(BUF, NBUF, DOA, DOB, KA, KB, VMS)                              \
  {                                                                            \
    /* p0: read A mi0-3 + B ni0-1, stage A-half0 of next tile */               \
    _Pragma("unroll") for (int mi = 0; mi < 4; mi++)                           \
      _Pragma("unroll") for (int kk = 0; kk < 2; kk++)                         \
        afr[mi][kk] = *(const bf16x8*)&sA[BUF][offA + mi * 1024 + kof[kk]];    \
    _Pragma("unroll") for (int ni = 0; ni < 2; ni++)                           \
      _Pragma("unroll") for (int kk = 0; kk < 2; kk++)                         \
        bfr[ni][kk] = *(const bf16x8*)&sB[BUF][offB + ni * 1024 + kof[kk]];    \
    if (DOA) stA(NBUF, 0, KA);                                                 \
    __builtin_amdgcn_s_barrier();                                              \
    asm volatile("s_waitcnt lgkmcnt(0)");                                      \
    __builtin_amdgcn_s_setprio(1);                                             \
    _Pragma("unroll") for (int kk = 0; kk < 2; kk++)                           \
      _Pragma("unroll") for (int mi = 0; mi < 4; mi++)                         \
        _Pragma("unroll") for (int ni = 0; ni < 2; ni++)                       \
          acc[mi][ni] = MF16(afr[mi][kk], bfr[ni][kk], acc[mi][ni], 0, 0, 0);  \
    __builtin_amdgcn_s_setprio(0);                                             \
    __builtin_amdgcn_s_barrier();                                              \
    /* p1: read B ni2-3 (A held), stage A-half1 */                             \
    _Pragma("unroll") for (int ni = 0; ni < 2; ni++)                           \
      _Pragma("unroll") for (int kk = 0; kk < 2; kk++)                         \
        bfr[2 + ni][kk] = *(const bf16x8*)&sB[BUF][offB + (2 + ni) * 1024 + kof[kk]]; \
    if (DOA) stA(NBUF, 1, KA);                                                 \
    __builtin_amdgcn_s_barrier();                                              \
    asm volatile("s_waitcnt lgkmcnt(0)");                                      \
    __builtin_amdgcn_s_setprio(1);                                             \
    _Pragma("unroll") for (int kk = 0; kk < 2; kk++)                           \
      _Pragma("unroll") for (int mi = 0; mi < 4; mi++)                         \
        _Pragma("unroll") for (int ni = 0; ni < 2; ni++)                       \
          acc[mi][2 + ni] = MF16(afr[mi][kk], bfr[2 + ni][kk], acc[mi][2 + ni], 0, 0, 0); \
    __builtin_amdgcn_s_setprio(0);                                             \
    __builtin_amdgcn_s_barrier();                                              \
    /* p2: read A mi4-7 (B held), stage B-half0 of tile T+2 (B of T read-done @p1) */ \
    _Pragma("unroll") for (int mi = 0; mi < 4; mi++)                           \
      _Pragma("unroll") for (int kk = 0; kk < 2; kk++)                         \
        afr[mi][kk] = *(const bf16x8*)&sA[BUF][offA + (4 + mi) * 1024 + kof[kk]]; \
    if (DOB) stB(BUF, 0, KB);                                                  \
    __builtin_amdgcn_s_barrier();                                              \
    asm volatile("s_waitcnt lgkmcnt(0)");                                      \
    __builtin_amdgcn_s_setprio(1);                                             \
    _Pragma("unroll") for (int kk = 0; kk < 2; kk++)                           \
      _Pragma("unroll") for (int mi = 0; mi < 4; mi++)                         \
        _Pragma("unroll") for (int ni = 0; ni < 2; ni++)                       \
          acc[4 + mi][2 + ni] = MF16(afr[mi][kk], bfr[2 + ni][kk], acc[4 + mi][2 + ni], 0, 0, 0); \
    __builtin_amdgcn_s_setprio(0);                                             \
    __builtin_amdgcn_s_barrier();                                              \
    /* p3: no reads, stage B-half1, counted vmcnt fence for next tile */       \
    if (DOB) stB(BUF, 1, KB);                                                  \
    asm volatile("s_waitcnt vmcnt(" VMS ")" ::: "memory");                     \
    __builtin_amdgcn_s_barrier();                                              \
    asm volatile("s_waitcnt lgkmcnt(0)");                                      \
    __builtin_amdgcn_s_setprio(1);                                             \
    _Pragma("unroll") for (int kk = 0; kk < 2; kk++)                           \
      _Pragma("unroll") for (int mi = 0; mi < 4; mi++)                         \
        _Pragma("unroll") for (int ni = 0; ni < 2; ni++)                       \
          acc[4 + mi][ni] = MF16(afr[mi][kk], bfr[ni][kk], acc[4 + mi][ni], 0, 0, 0); \
    __builtin_amdgcn_s_setprio(0);                                             \
    __builtin_amdgcn_s_barrier();                                              \
  }

__global__ __launch_bounds__(512, 2) void gemm256(const u16* __restrict__ A,
                                                  const u16* __restrict__ Bt,
                                                  const u16* __restrict__ bias,
                                                  u16* __restrict__ C,
                                                  int M, int N, int K, int act,
                                                  int ldc, u16* __restrict__ Vt,
                                                  int mode) {
  __shared__ alignas(16) u16 sA[2][16384];   // 2 x [2 halves][128 rows][64 cols]
  __shared__ alignas(16) u16 sB[2][16384];
  const int tid = threadIdx.x;
  const int wv = tid >> 6, lane = tid & 63;
  const int m16 = lane & 15, quad = lane >> 4;
  const int wr = wv >> 2, wc = wv & 3;

  // T1: bijective XCD-aware remap of the linear block id (tn fastest)
  const int NT = N >> 8;
  int bid = blockIdx.x;
  {
    const int nwg = gridDim.x;
    const int q = nwg >> 3, r = nwg & 7;
    const int xcd = bid & 7, lp = bid >> 3;
    bid = (xcd < r ? xcd * (q + 1) : r * (q + 1) + (xcd - r) * q) + lp;
  }
  const long bm = (long)(bid / NT) * 256;
  const long bn = (long)(bid % NT) * 256;

  // staging: linear LDS dest, inverse-swizzled global source (rule: both-sides)
  const int r0 = wv * 16 + (lane >> 3);             // row within 128-row half
  const int cstg = ((lane & 7) ^ (lane >> 3)) * 8;  // swizzled col (elements)
  const u16* gA0 = A  + (bm + r0) * (long)K + cstg;
  const u16* gA1 = A  + (bm + 128 + r0) * (long)K + cstg;
  const u16* gB0 = Bt + (bn + r0) * (long)K + cstg;
  const u16* gB1 = Bt + (bn + 128 + r0) * (long)K + cstg;
  const long k8 = 8 * (long)K;

  auto stA = [&](int nb, int h, int k0) {
    const u16* s = (h ? gA1 : gA0) + k0;
    u16* d = &sA[nb][h * 8192 + wv * 1024];
    async16(s, d);
    async16(s + k8, d + 512);
  };
  auto stB = [&](int nb, int h, int k0) {
    const u16* s = (h ? gB1 : gB0) + k0;
    u16* d = &sB[nb][h * 8192 + wv * 1024];
    async16(s, d);
    async16(s + k8, d + 512);
  };

  // fragment-read addressing (swizzled): granule(kk) = (kk*4+quad)^(m16&7)
  const int qs = quad ^ (m16 & 3);
  const int hb = (m16 >> 2) & 1;
  const int kof[2] = {hb * 32, 32 - hb * 32};
  const int offA = wr * 8192 + m16 * 64 + qs * 8;                    // + mi*1024
  const int offB = (wc >> 1) * 8192 + (wc & 1) * 4096 + m16 * 64 + qs * 8; // + ni*1024

  f32x4 acc[8][4];
#pragma unroll
  for (int i = 0; i < 8; i++)
#pragma unroll
    for (int j = 0; j < 4; j++) acc[i][j] = (f32x4){0.f, 0.f, 0.f, 0.f};
  bf16x8 afr[4][2], bfr[4][2];

  const int KT = K >> 6;   // K-tiles of 64; K multiple of 128, KT even >= 2

  // prologue: tile0 (A0,A1,B0,B1) -> buf0; B halves of tile1 -> buf1
  stA(0, 0, 0); stA(0, 1, 0); stB(0, 0, 0); stB(0, 1, 0);
  stB(1, 0, 64); stB(1, 1, 64);
  asm volatile("s_waitcnt vmcnt(4)" ::: "memory");   // tile0 landed; B(tile1) in flight
  __builtin_amdgcn_s_barrier();

  int T = 0;
  for (; T + 2 < KT; T += 2) {
    const int kA1 = (T + 1) << 6, kB2 = (T + 2) << 6, kB3 = (T + 3) << 6;
    TILE256(0, 1, true, true, kA1, kB2, "4");
    TILE256(1, 0, true, true, kB2, kB3, "4");
  }
  {  // tail pair (T = KT-2): no B stages remain -> must drain fully
    const int kA1 = (T + 1) << 6;
    TILE256(0, 1, true, false, kA1, 0, "0");
    TILE256(1, 0, false, false, 0, 0, "0");
  }

  float bv4[4];
#pragma unroll
  for (int ni = 0; ni < 4; ni++) bv4[ni] = bf2f(bias[bn + wc * 64 + ni * 16 + m16]);

#pragma unroll
  for (int mi = 0; mi < 8; mi++) {
#pragma unroll
    for (int ni = 0; ni < 4; ni++) {
      long col = bn + wc * 64 + ni * 16 + m16;
      long rowb = bm + wr * 128 + mi * 16 + quad * 4;
      if (mode == 1 && col >= 2048) {
        // V -> Vt[(b*16+h)][dk][s], 4 acc rows = consecutive s
        int hh = ((int)col >> 6) & 15, dk = (int)col & 63;
        int bb = (int)(rowb >> 10), ss = (int)(rowb & 1023);
        u16 t4[4];
#pragma unroll
        for (int r = 0; r < 4; r++) t4[r] = f2bf(acc[mi][ni][r] + bv4[ni]);
        *(uint2*)&Vt[(((long)bb * 16 + hh) * 64 + dk) * 1024 + ss] = *(const uint2*)t4;
      } else {
#pragma unroll
        for (int r = 0; r < 4; r++) {
          float v = acc[mi][ni][r] + bv4[ni];
          if (act) v = fmaxf(v, 0.f);
          C[(rowb + r) * (long)ldc + col] = f2bf(v);
        }
      }
    }
  }
}

// ---------------- GEMM 256x128, BK=64, 8-wave, counted-vmcnt schedule ----------
// For N=1024 GEMMs (FF2, Wo): grid = (M/256)*(N/128) = 256 blocks = 1 full round.
// R7: same lgkmcnt(0) discipline as TILE256.
#define TILE128(BUF, NBUF, DOA, DOB, KA, KB, VMS)                              \
  {                                                                            \
    /* p0: read A mi0-3 + B ni0-1; stage A-half0(T+1) */                       \
    _Pragma("unroll") for (int mi = 0; mi < 4; mi++)                           \
      _Pragma("unroll") for (int kk = 0; kk < 2; kk++)                         \
        afr[mi][kk] = *(const bf16x8*)&sA[BUF][offA + mi * 1024 + kof[kk]];    \
    _Pragma("unroll") for (int ni = 0; ni < 2; ni++)                           \
      _Pragma("unroll") for (int kk = 0; kk < 2; kk++)                         \
        bfr[ni][kk] = *(const bf16x8*)&sB[BUF][offB + ni * 1024 + kof[kk]];    \
    if (DOA) stA(NBUF, 0, KA);                                                 \
    __builtin_amdgcn_s_barrier();                                              \
    asm volatile("s_waitcnt lgkmcnt(0)");                                      \
    __builtin_amdgcn_s_setprio(1);                                             \
    _Pragma("unroll") for (int kk = 0; kk < 2; kk++)                           \
      _Pragma("unroll") for (int mi = 0; mi < 4; mi++)                         \
        _Pragma("unroll") for (int ni = 0; ni < 2; ni++)                       \
          acc[mi][ni] = MF16(afr[mi][kk], bfr[ni][kk], acc[mi][ni], 0, 0, 0);  \
    __builtin_amdgcn_s_setprio(0);                                             \
    __builtin_amdgcn_s_barrier();                                              \
    /* p1: read B ni2-3 (A held); stage A-half1(T+1) */                        \
    _Pragma("unroll") for (int ni = 0; ni < 2; ni++)                           \
      _Pragma("unroll") for (int kk = 0; kk < 2; kk++)                         \
        bfr[2 + ni][kk] = *(const bf16x8*)&sB[BUF][offB + (2 + ni) * 1024 + kof[kk]]; \
    if (DOA) stA(NBUF, 1, KA);                                                 \
    __builtin_amdgcn_s_barrier();                                              \
    asm volatile("s_waitcnt lgkmcnt(0)");                                      \
    __builtin_amdgcn_s_setprio(1);                                             \
    _Pragma("unroll") for (int kk = 0; kk < 2; kk++)                           \
      _Pragma("unroll") for (int mi = 0; mi < 4; mi++)                         \
        _Pragma("unroll") for (int ni = 0; ni < 2; ni++)                       \
          acc[mi][2 + ni] = MF16(afr[mi][kk], bfr[2 + ni][kk], acc[mi][2 + ni], 0, 0, 0); \
    __builtin_amdgcn_s_setprio(0);                                             \
    __builtin_amdgcn_s_barrier();                                              \
    /* p2: stage B(T+2) into BUF (same parity); counted fence */               \
    if (DOB) stB(BUF, KB);                                                     \
    asm volatile("s_waitcnt vmcnt(" VMS ")" ::: "memory");                     \
    __builtin_amdgcn_s_barrier();                                              \
  }

__global__ __launch_bounds__(512, 2) void gemm256x128(const u16* __restrict__ A,
                                                      const u16* __restrict__ Bt,
                                                      const u16* __restrict__ bias,
                                                      u16* __restrict__ C,
                                                      int M, int N, int K, int act) {
  __shared__ alignas(16) u16 sA[2][16384];   // [2 halves][128 rows][64 cols] swz
  __shared__ alignas(16) u16 sB[2][8192];    // [128 rows][64 cols] swz
  const int tid = threadIdx.x;
  const int wv = tid >> 6, lane = tid & 63;
  const int m16 = lane & 15, quad = lane >> 4;
  const int wr = wv >> 1, wc = wv & 1;       // 4M x 2N waves, 64x64 each

  const int NT = N >> 7;
  int bid = blockIdx.x;
  {
    const int nwg = gridDim.x;
    const int q = nwg >> 3, r = nwg & 7;
    const int xcd = bid & 7, lp = bid >> 3;
    bid = (xcd < r ? xcd * (q + 1) : r * (q + 1) + (xcd - r) * q) + lp;
  }
  const long bm = (long)(bid / NT) * 256;
  const long bn = (long)(bid % NT) * 128;

  const int r0 = wv * 16 + (lane >> 3);
  const int cstg = ((lane & 7) ^ (lane >> 3)) * 8;
  const u16* gA0 = A + (bm + r0) * (long)K + cstg;
  const u16* gA1 = A + (bm + 128 + r0) * (long)K + cstg;
  const u16* gB0 = Bt + (bn + r0) * (long)K + cstg;
  const long k8 = 8 * (long)K;

  auto stA = [&](int nb, int h, int k0) {
    const u16* s = (h ? gA1 : gA0) + k0;
    u16* d = &sA[nb][h * 8192 + wv * 1024];
    async16(s, d);
    async16(s + k8, d + 512);
  };
  auto stB = [&](int nb, int k0) {
    const u16* s = gB0 + k0;
    u16* d = &sB[nb][wv * 1024];
    async16(s, d);
    async16(s + k8, d + 512);
  };

  const int qs = quad ^ (m16 & 3);
  const int hb = (m16 >> 2) & 1;
  const int kof[2] = {hb * 32, 32 - hb * 32};
  const int offA = (wr >> 1) * 8192 + (wr & 1) * 4096 + m16 * 64 + qs * 8; // +mi*1024
  const int offB = wc * 4096 + m16 * 64 + qs * 8;                          // +ni*1024

  f32x4 acc[4][4];
#pragma unroll
  for (int i = 0; i < 4; i++)
#pragma unroll
    for (int j = 0; j < 4; j++) acc[i][j] = (f32x4){0.f, 0.f, 0.f, 0.f};
  bf16x8 afr[4][2], bfr[4][2];

  const int KT = K >> 6;   // even (K multiple of 128)

  // prologue: tile0 (A0,A1,B) -> buf0; B(tile1) -> buf1
  stA(0, 0, 0); stA(0, 1, 0); stB(0, 0);
  stB(1, 64);
  asm volatile("s_waitcnt vmcnt(2)" ::: "memory");   // tile0 landed; B(1) in flight
  __builtin_amdgcn_s_barrier();

  int T = 0;
  for (; T + 2 < KT; T += 2) {
    TILE128(0, 1, true, true, (T + 1) << 6, (T + 2) << 6, "2");
    TILE128(1, 0, true, true, (T + 2) << 6, (T + 3) << 6, "2");
  }
  // tail pair: tile KT-2 stages only A(KT-1); must drain fully
  TILE128(0, 1, true, false, (T + 1) << 6, 0, "0");
  TILE128(1, 0, false, false, 0, 0, "0");

  float bv4[4];
#pragma unroll
  for (int ni = 0; ni < 4; ni++) bv4[ni] = bf2f(bias[bn + wc * 64 + ni * 16 + m16]);

#pragma unroll
  for (int mi = 0; mi < 4; mi++) {
#pragma unroll
    for (int ni = 0; ni < 4; ni++) {
      long col = bn + wc * 64 + ni * 16 + m16;
      long rowb = bm + wr * 64 + mi * 16 + quad * 4;
#pragma unroll
      for (int r = 0; r < 4; r++) {
        float v = acc[mi][ni][r] + bv4[ni];
        if (act) v = fmaxf(v, 0.f);
        C[(rowb + r) * (long)N + col] = f2bf(v);
      }
    }
  }
}

// ---------------- flash attention v2: 128q blocks, 32q/wave, V^T pre-staged ----
// qk: [8192][2048] (Q|K per token), Vt: [b*16+h][64 dk][1024 s] (from QKV GEMM).
__global__ __launch_bounds__(256, 4) void attn_fwd(const u16* __restrict__ qk,
                                                   const u16* __restrict__ Vt,
                                                   u16* __restrict__ attnO) {
  __shared__ alignas(16) u16 sQP[8192];  // Q [128][64] swz; later per-wave P[32][64] @ wv*4096B
  __shared__ alignas(16) u16 sK[4096];   // [64 key][64 dk] swz
  __shared__ alignas(16) u16 sVt[4096];  // [64 dk][64 key] swz
  const int tid = threadIdx.x;
  const int bh = blockIdx.x;
  const int qt = blockIdx.y;
  const int b = bh >> 4, h = bh & 15;
  const int wv = tid >> 6, lane = tid & 63;
  const int m16 = lane & 15, quad = lane >> 4;
  const int kk = tid >> 3;               // staging row 0..31
  const int t7 = tid & 7;

  char* cQP = (char*)sQP;
  char* cK = (char*)sK;
  char* cV = (char*)sVt;

  // ---- stage Q [128 q][64 dk], scaled by 1/sqrt(DK)=0.125, swizzled ----
  {
    int row = tid >> 1, half = tid & 1;
    const u16* g = qk + (long)(b * Sq + qt * 128 + row) * 2048 + h * 64 + half * 32;
#pragma unroll
    for (int j = 0; j < 4; j++) {
      uint4 raw = *(const uint4*)(g + j * 8);
      const u16* pv = (const u16*)&raw;
      u16 t[8];
#pragma unroll
      for (int e = 0; e < 8; e++) t[e] = f2bf(bf2f(pv[e]) * 0.125f);
      *(uint4*)(cQP + swzb(row, half * 64 + j * 16)) = *(const uint4*)t;
    }
  }
  __syncthreads();
  // Q frags: qf[qt2][s] = Q[wv*32 + qt2*16 + m16][s*32 + quad*8 ..]
  bf16x8 qf[2][2];
#pragma unroll
  for (int qt2 = 0; qt2 < 2; qt2++)
#pragma unroll
    for (int s = 0; s < 2; s++)
      qf[qt2][s] = *(const bf16x8*)(cQP + swzb(wv * 32 + qt2 * 16 + m16, s * 64 + quad * 16));

  f32x4 o[4][2];
#pragma unroll
  for (int dt = 0; dt < 4; dt++)
#pragma unroll
    for (int qt2 = 0; qt2 < 2; qt2++) o[dt][qt2] = (f32x4){0.f, 0.f, 0.f, 0.f};
  float mrun[2] = {-1e30f, -1e30f}, lrun[2] = {0.f, 0.f};

  const u16* gK = qk + (long)(b * Sq + kk) * 2048 + 1024 + h * 64 + t7 * 8;
  const u16* gV = Vt + ((long)bh * 64 + kk) * 1024 + t7 * 8;
  const long stepK = (long)64 * 2048;
  const int off0 = swzb(kk, t7 * 16);        // (kk+32)&7 == kk&7 -> +4096 bytes
  const int off1 = off0 + 4096;

  uint4 rk0 = *(const uint4*)gK;
  uint4 rk1 = *(const uint4*)(gK + 32 * 2048);
  uint4 rv0 = *(const uint4*)gV;
  uint4 rv1 = *(const uint4*)(gV + 32 * 1024);

  for (int kt = 0; kt < 16; kt++) {
    __syncthreads();   // previous iteration's K/V frag reads done
    *(uint4*)(cK + off0) = rk0;
    *(uint4*)(cK + off1) = rk1;
    *(uint4*)(cV + off0) = rv0;
    *(uint4*)(cV + off1) = rv1;
    __syncthreads();   // tiles published

    // S^T[key][q]: st[kt2][qt2], col=q=qt2*16+m16, row=key=kt2*16+quad*4+r
    f32x4 st[4][2];
#pragma unroll
    for (int kt2 = 0; kt2 < 4; kt2++)
#pragma unroll
      for (int qt2 = 0; qt2 < 2; qt2++) st[kt2][qt2] = (f32x4){0.f, 0.f, 0.f, 0.f};
    __builtin_amdgcn_s_setprio(1);
#pragma unroll
    for (int s = 0; s < 2; s++) {
      bf16x8 kf[4];
#pragma unroll
      for (int kt2 = 0; kt2 < 4; kt2++)
        kf[kt2] = *(const bf16x8*)(cK + swzb(kt2 * 16 + m16, s * 64 + quad * 16));
#pragma unroll
      for (int kt2 = 0; kt2 < 4; kt2++)
#pragma unroll
        for (int qt2 = 0; qt2 < 2; qt2++)
          st[kt2][qt2] = MF16(kf[kt2], qf[qt2][s], st[kt2][qt2], 0, 0, 0);
    }
    __builtin_amdgcn_s_setprio(0);

    if (kt < 15) {     // prefetch next K/V (hidden under softmax+PV)
      rk0 = *(const uint4*)(gK + (long)(kt + 1) * stepK);
      rk1 = *(const uint4*)(gK + (long)(kt + 1) * stepK + 32 * 2048);
      rv0 = *(const uint4*)(gV + (kt + 1) * 64);
      rv1 = *(const uint4*)(gV + (kt + 1) * 64 + 32 * 1024);
    }

    // online softmax per qt2 (lane owns q = qt2*16+m16; keys split across quad)
    char* cP = cQP + wv * 4096;
#pragma unroll
    for (int qt2 = 0; qt2 < 2; qt2++) {
      float pm = st[0][qt2][0];
#pragma unroll
      for (int kt2 = 0; kt2 < 4; kt2++)
#pragma unroll
        for (int r = 0; r < 4; r++) pm = fmaxf(pm, st[kt2][qt2][r]);
      pm = fmaxf(pm, __shfl_xor(pm, 16));
      pm = fmaxf(pm, __shfl_xor(pm, 32));
      float mnew = fmaxf(mrun[qt2], pm);
      float al = __expf(mrun[qt2] - mnew);
      mrun[qt2] = mnew;
      float rs = 0.f;
#pragma unroll
      for (int kt2 = 0; kt2 < 4; kt2++) {
        u16 t4[4];
#pragma unroll
        for (int r = 0; r < 4; r++) {
          float p = __expf(st[kt2][qt2][r] - mnew);
          rs += p;
          t4[r] = f2bf(p);
        }
        *(uint2*)(cP + swzb(qt2 * 16 + m16, kt2 * 32 + quad * 8)) = *(const uint2*)t4;
      }
      rs += __shfl_xor(rs, 16);
      rs += __shfl_xor(rs, 32);
      lrun[qt2] = lrun[qt2] * al + rs;
#pragma unroll
      for (int dt = 0; dt < 4; dt++)
#pragma unroll
        for (int r = 0; r < 4; r++) o[dt][qt2][r] *= al;
    }

    // O^T[dk][q] += V^T[dk][key] * P^T : A = V^T frags, B = P frags
    bf16x8 pb[2][2];
#pragma unroll
    for (int qt2 = 0; qt2 < 2; qt2++)
#pragma unroll
      for (int ks = 0; ks < 2; ks++)
        pb[qt2][ks] = *(const bf16x8*)(cP + swzb(qt2 * 16 + m16, ks * 64 + quad * 16));
    __builtin_amdgcn_s_setprio(1);
#pragma unroll
    for (int dt = 0; dt < 4; dt++) {
      bf16x8 v0 = *(const bf16x8*)(cV + swzb(dt * 16 + m16, quad * 16));
      bf16x8 v1 = *(const bf16x8*)(cV + swzb(dt * 16 + m16, 64 + quad * 16));
#pragma unroll
      for (int qt2 = 0; qt2 < 2; qt2++) {
        o[dt][qt2] = MF16(v0, pb[qt2][0], o[dt][qt2], 0, 0, 0);
        o[dt][qt2] = MF16(v1, pb[qt2][1], o[dt][qt2], 0, 0, 0);
      }
    }
    __builtin_amdgcn_s_setprio(0);
  }

#pragma unroll
  for (int qt2 = 0; qt2 < 2; qt2++) {
    float rl = 1.f / lrun[qt2];
    long tok = (long)(b * Sq + qt * 128 + wv * 32 + qt2 * 16 + m16);
#pragma unroll
    for (int dt = 0; dt < 4; dt++) {
      u16 t4[4];
#pragma unroll
      for (int r = 0; r < 4; r++) t4[r] = f2bf(o[dt][qt2][r] * rl);
      *(uint2*)&attnO[tok * 1024 + h * 64 + dt * 16 + quad * 4] = *(const uint2*)t4;
    }
  }
}

// ---------------- add + LayerNorm (bf16 out, internal), uint2-vectorized -------
__global__ __launch_bounds__(256) void add_ln(const u16* __restrict__ X,
                                              const u16* __restrict__ Y,
                                              const u16* __restrict__ g,
                                              const u16* __restrict__ be,
                                              u16* __restrict__ out) {
  const int row = blockIdx.x;
  const int t = threadIdx.x;
  const long base = (long)row * Dq;
  const int i4 = t * 4;
  uint2 xr = *(const uint2*)&X[base + i4];
  uint2 yr = *(const uint2*)&Y[base + i4];
  const u16* xp = (const u16*)&xr;
  const u16* yp = (const u16*)&yr;
  float v[4]; float s = 0.f, ss = 0.f;
#pragma unroll
  for (int i = 0; i < 4; i++) {
    float x = bf2f(xp[i]) + bf2f(yp[i]);
    v[i] = x; s += x; ss += x * x;
  }
#pragma unroll
  for (int off = 32; off > 0; off >>= 1) { s += __shfl_down(s, off); ss += __shfl_down(ss, off); }
  __shared__ float red[8];
  int wv = t >> 6, ln = t & 63;
  if (ln == 0) { red[wv] = s; red[4 + wv] = ss; }
  __syncthreads();
  s = red[0] + red[1] + red[2] + red[3];
  ss = red[4] + red[5] + red[6] + red[7];
  float mean = s * (1.f / Dq);
  float var = ss * (1.f / Dq) - mean * mean;
  float rstd = rsqrtf(var + 1e-5f);
  uint2 gr = *(const uint2*)&g[i4];
  uint2 br = *(const uint2*)&be[i4];
  const u16* gp = (const u16*)&gr;
  const u16* bp = (const u16*)&br;
  u16 o4[4];
#pragma unroll
  for (int i = 0; i < 4; i++)
    o4[i] = f2bf((v[i] - mean) * rstd * bf2f(gp[i]) + bf2f(bp[i]));
  *(uint2*)&out[base + i4] = *(const uint2*)o4;
}

// ---------------- final add + LayerNorm, dual-dtype store, vectorized ----------
__global__ __launch_bounds__(256) void add_ln_out(const u16* __restrict__ X,
                                                  const u16* __restrict__ Y,
                                                  const u16* __restrict__ g,
                                                  const u16* __restrict__ be,
                                                  void* __restrict__ out,
                                                  const u32* __restrict__ outflag) {
  const u32 fp32 = *outflag;
  const int row = blockIdx.x;
  const int t = threadIdx.x;
  const long base = (long)row * Dq;
  const int i4 = t * 4;
  uint2 xr = *(const uint2*)&X[base + i4];
  uint2 yr = *(const uint2*)&Y[base + i4];
  const u16* xp = (const u16*)&xr;
  const u16* yp = (const u16*)&yr;
  float v[4]; float s = 0.f, ss = 0.f;
#pragma unroll
  for (int i = 0; i < 4; i++) {
    float x = bf2f(xp[i]) + bf2f(yp[i]);
    v[i] = x; s += x; ss += x * x;
  }
#pragma unroll
  for (int off = 32; off > 0; off >>= 1) { s += __shfl_down(s, off); ss += __shfl_down(ss, off); }
  __shared__ float red[8];
  int wv = t >> 6, ln = t & 63;
  if (ln == 0) { red[wv] = s; red[4 + wv] = ss; }
  __syncthreads();
  s = red[0] + red[1] + red[2] + red[3];
  ss = red[4] + red[5] + red[6] + red[7];
  float mean = s * (1.f / Dq);
  float var = ss * (1.f / Dq) - mean * mean;
  float rstd = rsqrtf(var + 1e-5f);
  uint2 gr = *(const uint2*)&g[i4];
  uint2 br = *(const uint2*)&be[i4];
  const u16* gp = (const u16*)&gr;
  const u16* bp = (const u16*)&br;
  if (fp32) {
    float4 o4;
    o4.x = (v[0] - mean) * rstd * bf2f(gp[0]) + bf2f(bp[0]);
    o4.y = (v[1] - mean) * rstd * bf2f(gp[1]) + bf2f(bp[1]);
    o4.z = (v[2] - mean) * rstd * bf2f(gp[2]) + bf2f(bp[2]);
    o4.w = (v[3] - mean) * rstd * bf2f(gp[3]) + bf2f(bp[3]);
    *(float4*)((float*)out + base + i4) = o4;
  } else {
    u16 o4[4];
#pragma unroll
    for (int i = 0; i < 4; i++)
      o4[i] = f2bf((v[i] - mean) * rstd * bf2f(gp[i]) + bf2f(bp[i]));
    *(uint2*)((u16*)out + base + i4) = *(const uint2*)o4;
  }
}

extern "C" void kernel_launch(void* const* d_in, const int* in_sizes, int n_in,
                              void* d_out, int out_size, void* d_ws, size_t ws_size,
                              hipStream_t stream) {
  char* ws = (char*)d_ws;
  size_t off = 0;
  auto alloc = [&](size_t bytes) {
    void* p = ws + off;
    off += (bytes + 255) & ~(size_t)255;
    return p;
  };
  u32* flags  = (u32*)alloc(32 * 4);
  u16* Wqkv_t = (u16*)alloc((size_t)3072 * 1024 * 2);   // 6 MB
  u16* Wo_t   = (u16*)alloc((size_t)1024 * 1024 * 2);   // 2 MB
  u16* W1_t   = (u16*)alloc((size_t)4096 * 1024 * 2);   // 8 MB
  u16* W2_t   = (u16*)alloc((size_t)1024 * 4096 * 2);   // 8 MB
  u16* svec   = (u16*)alloc((size_t)13312 * 2);         // all small vectors
  u16* src_bf = (u16*)alloc((size_t)TOK * 1024 * 2);    // 16 MB
  u16* regA   = (u16*)alloc((size_t)TOK * 4096 * 2);    // 64 MB
  size_t need_chunk2 = off;                              // h1(32MB) fits inside regA
  size_t need_full   = off + (size_t)TOK * 4096 * 2 / 2; // +32MB so h1(64MB) spans past regA

  u16* outw = (u16*)d_out;
  int CH;  // rows per FF chunk
  if (ws_size >= need_full) { CH = 8192; (void)alloc((size_t)32 << 20); }
  else if (ws_size >= need_chunk2) CH = 4096;
  else if (ws_size >= need_chunk2 - ((size_t)16 << 20)) CH = 2048;
  else {
    diag_ws_too_small<<<1, 1, 0, stream>>>(outw, 8000.0f + (float)(ws_size >> 20));
    return;
  }

  u16* qk    = regA;                          // [0,32)  Q|K per token [8192][2048]
  u16* Vt    = regA + (size_t)TOK * 2048;     // [32,48) V transposed [128][64][1024]
  u16* attnb = regA + (size_t)TOK * 3072;     // [48,64)
  u16* proj  = regA;                          // [0,16)  after qk/Vt dead
  u16* x     = regA + (size_t)TOK * 1024;     // [16,32)
  u16* h1    = regA + (size_t)TOK * 2048;     // [32,..) CH*4096*2 bytes (Vt dead by then)
  u16* f2    = src_bf;                        // src_bf dead after x computed

  u16* bqkv = svec + 0;      // 3072
  u16* bo_c = svec + 3072;
  u16* g1_c = svec + 4096;
  u16* be1_c = svec + 5120;
  u16* b1_c = svec + 6144;   // 4096
  u16* b2_c = svec + 10240;
  u16* g2_c = svec + 11264;
  u16* be2_c = svec + 12288;

  // ---- dtype detection ----
  InTab itab;
  for (int i = 0; i < 17; i++) { itab.p[i] = d_in[i]; itab.n[i] = in_sizes[i]; }
  detect_all<<<dim3(17), 256, 0, stream>>>(itab, flags);

  // ---- all weight transposes in one launch ----
  pack_all<<<dim3(3072), 256, 0, stream>>>(d_in[1], d_in[3], d_in[5], d_in[7], d_in[11], d_in[13],
                                           Wqkv_t, Wo_t, W1_t, W2_t, flags);

  // ---- small vectors ----
  CvtTab ct;
  const int srcs[10] = {2, 4, 6, 8, 9, 10, 12, 14, 15, 16};
  const int offs[10] = {0, 1024, 2048, 3072, 4096, 5120, 6144, 10240, 11264, 12288};
  const int lens[10] = {1024, 1024, 1024, 1024, 1024, 1024, 4096, 1024, 1024, 1024};
  for (int e = 0; e < 10; e++) { ct.p[e] = d_in[srcs[e]]; ct.flagidx[e] = srcs[e]; ct.dstoff[e] = offs[e]; ct.n[e] = lens[e]; }
  cvt_small<<<dim3(10), 256, 0, stream>>>(ct, svec, flags);

  // ---- src -> bf16 ----
  cvt_src<<<dim3(TOK * 1024 / (256 * 8)), 256, 0, stream>>>(d_in[0], src_bf, &flags[0]);

  // qkv = src @ Wqkv + b: Q|K -> qk [8192][2048], V -> Vt transposed (mode 1)
  gemm256<<<dim3(32 * 12), 512, 0, stream>>>(src_bf, Wqkv_t, bqkv, qk, TOK, 3072, 1024, 0,
                                             2048, Vt, 1);
  // attention [8192,1024]; grid: bh-major keeps one (b,h)'s K/V on one XCD's L2
  attn_fwd<<<dim3(128, 8), 256, 0, stream>>>(qk, Vt, attnb);
  // proj = attn @ Wo + bo  (256x128 tile: 32x8 = 256 blocks = 1 full round)
  gemm256x128<<<dim3(256), 512, 0, stream>>>(attnb, Wo_t, bo_c, proj, TOK, 1024, 1024, 0);
  // x = LN(src + proj)
  add_ln<<<dim3(TOK), 256, 0, stream>>>(src_bf, proj, g1_c, be1_c, x);
  // FF chunked by CH rows
  for (int c = 0; c < TOK / CH; c++) {
    const u16* xc = x + (size_t)c * CH * 1024;
    u16* f2c = f2 + (size_t)c * CH * 1024;
    if (CH >= 4096) {
      gemm256<<<dim3((CH / 256) * 16), 512, 0, stream>>>(xc, W1_t, b1_c, h1, CH, 4096, 1024, 1,
                                                         4096, nullptr, 0);
    } else {
      gemm_bt<<<dim3(CH / 128, 32), 256, 0, stream>>>(xc, W1_t, b1_c, h1, CH, 4096, 1024, 1, 4096);
    }
    if (CH == 8192) {
      gemm256x128<<<dim3((CH / 256) * 8), 512, 0, stream>>>(h1, W2_t, b2_c, f2c, CH, 1024, 4096, 0);
    } else {
      gemm_bt<<<dim3(CH / 128, 8), 256, 0, stream>>>(h1, W2_t, b2_c, f2c, CH, 1024, 4096, 0, 1024);
    }
  }
  // out = LN(x + f2), stored in src's container dtype
  add_ln_out<<<dim3(TOK), 256, 0, stream>>>(x, f2, g2_c, be2_c, d_out, &flags[0]);
  diag_mixed<<<1, 1, 0, stream>>>(flags, d_out);
}

// Round 8
// 568.069 us; speedup vs baseline: 1.0470x; 1.0095x over previous
//
#include <hip/hip_runtime.h>

// B=8 S=1024 D=1024 H=16 DK=64 F=4096 -- fp32 containers (bf16-valued), detected per-tensor
#define Bq 8
#define Sq 1024
#define Dq 1024
#define Hq 16
#define DKq 64
#define Fq 4096
#define TOK (Bq*Sq)   // 8192

typedef unsigned short u16;
typedef unsigned int u32;
typedef __bf16 bf16x8 __attribute__((ext_vector_type(8)));
typedef float  f32x4  __attribute__((ext_vector_type(4)));

__device__ __forceinline__ float bf2f(u16 u) {
  u32 x = ((u32)u) << 16;
  float f; __builtin_memcpy(&f, &x, 4); return f;
}
__device__ __forceinline__ u16 f2bf(float f) {
  u32 u; __builtin_memcpy(&u, &f, 4);
  u += 0x7fffu + ((u >> 16) & 1u);
  return (u16)(u >> 16);
}
// async global->LDS, 16B/lane; LDS dest = wave-uniform base + lane*16
__device__ __forceinline__ void async16(const u16* g, u16* l) {
  __builtin_amdgcn_global_load_lds(
      (__attribute__((address_space(1))) void*)(g),
      (__attribute__((address_space(3))) void*)(l), 16, 0, 0);
}
__device__ __forceinline__ u16 load_in(const void* p, long idx, u32 fp32) {
  return fp32 ? f2bf(((const float*)p)[idx]) : ((const u16*)p)[idx];
}
// XOR-swizzled byte offset within a [rows][64 bf16] tile (128B rows)
__device__ __forceinline__ int swzb(int row, int colb) {
  return row * 128 + (colb ^ ((row & 7) << 4));
}

// ---------------- dtype detection: one launch, 17 blocks ----------------
struct InTab { const void* p[17]; int n[17]; };

__global__ void detect_all(InTab tab, u32* flags) {
  __shared__ int sh[3][256];
  int bi = blockIdx.x;
  const u16* buf = (const u16*)tab.p[bi];
  long n = tab.n[bi];
  long m = n < 65536 ? n : 65536;
  int t = threadIdx.x;
  int nanpat = 0, evz = 0, oddnz = 0;
  for (long i = t; i < m; i += 256) {
    u16 v = buf[i];
    if ((v & 0x7F80u) == 0x7F80u) nanpat++;
    if ((i & 1) == 0) { if (v == 0) evz++; }
    else { if (v != 0) oddnz++; }
  }
  sh[0][t] = nanpat; sh[1][t] = evz; sh[2][t] = oddnz;
  __syncthreads();
  for (int s = 128; s > 0; s >>= 1) {
    if (t < s) { sh[0][t] += sh[0][t+s]; sh[1][t] += sh[1][t+s]; sh[2][t] += sh[2][t+s]; }
    __syncthreads();
  }
  if (t == 0) {
    long half = m / 2;
    bool fp32 = (sh[0][0] > 8) ||
                (sh[1][0] > (half * 9) / 10 && sh[2][0] > (half * 9) / 10);
    flags[bi] = fp32 ? 1u : 0u;
  }
}

__global__ void diag_ws_too_small(u16* out, float code) { out[0] = f2bf(code); }

__global__ void diag_mixed(const u32* flags, void* out) {
  u32 a = flags[0];
  if (flags[1] != a || flags[7] != a || flags[11] != a || flags[13] != a) {
    if (a) ((float*)out)[0] = 3000.0f;
    else ((u16*)out)[0] = f2bf(3000.0f);
  }
}

// ---------------- batched LDS-tiled transpose pack (single launch) ----------------
// 3072 tile-jobs of 64x64: [0,768) Wq/Wk/Wv slices, [768,1024) Wo, [1024,2048) W1, [2048,3072) W2
// R8: vectorized input loads (4x float4 fp32 / 2x uint4 bf16 per thread) --
// scalar loads were Common-mistake #2 over 50MB of weights.
__global__ __launch_bounds__(256) void pack_all(const void* __restrict__ Wq,
                                                const void* __restrict__ Wk,
                                                const void* __restrict__ Wv,
                                                const void* __restrict__ Wo,
                                                const void* __restrict__ W1,
                                                const void* __restrict__ W2,
                                                u16* __restrict__ Wqkv_t,
                                                u16* __restrict__ Wo_t,
                                                u16* __restrict__ W1_t,
                                                u16* __restrict__ W2_t,
                                                const u32* __restrict__ flags) {
  int id = blockIdx.x;
  const void* in; u16* out; u32 f; int R, C; long zin; int r0, c0;
  if (id < 768) {            // Wq/Wk/Wv: [16 h][1024 d][64 dk] -> [h*64+dk][d]
    int w = id >> 8, t = id & 255;
    int z = t >> 4, xt = t & 15;
    in = (w == 0) ? Wq : ((w == 1) ? Wk : Wv);
    f = flags[(w == 0) ? 1 : ((w == 1) ? 3 : 5)];
    R = 1024; C = 64;
    zin = (long)z * 65536;
    out = Wqkv_t + (long)w * 1048576 + (long)z * 65536;
    r0 = xt * 64; c0 = 0;
  } else if (id < 1024) {    // Wo [1024][1024]
    int t = id - 768; int xt = t & 15, yt = t >> 4;
    in = Wo; f = flags[7]; R = 1024; C = 1024; zin = 0; out = Wo_t;
    r0 = xt * 64; c0 = yt * 64;
  } else if (id < 2048) {    // W1 [1024][4096]
    int t = id - 1024; int xt = t & 15, yt = t >> 4;
    in = W1; f = flags[11]; R = 1024; C = 4096; zin = 0; out = W1_t;
    r0 = xt * 64; c0 = yt * 64;
  } else {                   // W2 [4096][1024]
    int t = id - 2048; int xt = t & 63, yt = t >> 6;
    in = W2; f = flags[13]; R = 4096; C = 1024; zin = 0; out = W2_t;
    r0 = xt * 64; c0 = yt * 64;
  }
  __shared__ u16 tile[64][65];
  {
    int row = threadIdx.x >> 2;        // 0..63
    int cg  = (threadIdx.x & 3) << 4;  // 0,16,32,48
    long srcidx = zin + (long)(r0 + row) * C + (c0 + cg);  // multiple of 16 elems
    u16 tv[16];
    if (f) {
      const float4* p4 = (const float4*)((const float*)in + srcidx);
#pragma unroll
      for (int j = 0; j < 4; j++) {
        float4 v = p4[j];
        tv[j * 4 + 0] = f2bf(v.x); tv[j * 4 + 1] = f2bf(v.y);
        tv[j * 4 + 2] = f2bf(v.z); tv[j * 4 + 3] = f2bf(v.w);
      }
    } else {
      const uint4* p8 = (const uint4*)((const u16*)in + srcidx);
      *(uint4*)&tv[0] = p8[0];
      *(uint4*)&tv[8] = p8[1];
    }
#pragma unroll
    for (int j = 0; j < 16; j++) tile[row][cg + j] = tv[j];
  }
  __syncthreads();
  int tx = threadIdx.x & 63, ty = threadIdx.x >> 6;
#pragma unroll
  for (int it = 0; it < 16; it++) {
    int cc = it * 4 + ty;
    out[(long)(c0 + cc) * R + r0 + tx] = tile[tx][cc];
  }
}

// ---------------- merged small-vector cvt ----------------
struct CvtTab { const void* p[10]; int flagidx[10]; int dstoff[10]; int n[10]; };
__global__ void cvt_small(CvtTab tab, u16* __restrict__ dst, const u32* __restrict__ flags) {
  int e = blockIdx.x;
  u32 f = flags[tab.flagidx[e]];
  const void* p = tab.p[e];
  int n = tab.n[e], o = tab.dstoff[e];
  for (int i = threadIdx.x; i < n; i += 256) dst[o + i] = load_in(p, i, f);
}

// ---------------- vectorized src cvt (8 elems/thread) ----------------
__global__ __launch_bounds__(256) void cvt_src(const void* __restrict__ in,
                                               u16* __restrict__ out,
                                               const u32* __restrict__ flag) {
  u32 f = *flag;
  long i8 = ((long)blockIdx.x * 256 + threadIdx.x) * 8;
  if (f) {
    const float4* f4 = (const float4*)((const float*)in + i8);
    float4 a = f4[0], b = f4[1];
    u16 v[8] = {f2bf(a.x), f2bf(a.y), f2bf(a.z), f2bf(a.w),
                f2bf(b.x), f2bf(b.y), f2bf(b.z), f2bf(b.w)};
    *(uint4*)(out + i8) = *(const uint4*)v;
  } else {
    *(uint4*)(out + i8) = *(const uint4*)((const u16*)in + i8);
  }
}

// ---------------- GEMM: C[M,N] = A[M,K] @ Bt[N,K]^T + bias, optional ReLU --------
// 128x128 tile, BK=32, double-buffered LDS. Kept only for chunked fallbacks.
__global__ __launch_bounds__(256) void gemm_bt(const u16* __restrict__ A,
                                               const u16* __restrict__ Bt,
                                               const u16* __restrict__ bias,
                                               u16* __restrict__ C,
                                               int M, int N, int K, int act,
                                               int ldc) {
  __shared__ alignas(16) u16 sA[2][128 * 32];
  __shared__ alignas(16) u16 sB[2][128 * 32];
  const int tid = threadIdx.x;
  const int wv = tid >> 6, lane = tid & 63;
  const int m16 = lane & 15, quad = lane >> 4;
  const long bm = (long)blockIdx.x * 128;
  const long bn = (long)blockIdx.y * 128;
  const int wm = (wv >> 1) * 64, wn = (wv & 1) * 64;

  f32x4 acc[4][4];
#pragma unroll
  for (int i = 0; i < 4; i++)
#pragma unroll
    for (int j = 0; j < 4; j++) acc[i][j] = (f32x4){0.f, 0.f, 0.f, 0.f};

  const int row_s = tid >> 2;          // 0..63
  const int col_s = (tid & 3) * 8;
  const u16* gA0 = A + (bm + row_s) * (long)K + col_s;
  const u16* gA1 = gA0 + 64 * (long)K;
  const u16* gB0 = Bt + (bn + row_s) * (long)K + col_s;
  const u16* gB1 = gB0 + 64 * (long)K;

  auto stage = [&](int p, int k) {
    async16(gA0 + k, &sA[p][wv * 512]);
    async16(gA1 + k, &sA[p][2048 + wv * 512]);
    async16(gB0 + k, &sB[p][wv * 512]);
    async16(gB1 + k, &sB[p][2048 + wv * 512]);
  };
  auto compute = [&](int p) {
    bf16x8 af[4], bf_[4];
#pragma unroll
    for (int mi = 0; mi < 4; mi++)
      af[mi] = *(const bf16x8*)&sA[p][(wm + mi * 16 + m16) * 32 + quad * 8];
#pragma unroll
    for (int ni = 0; ni < 4; ni++)
      bf_[ni] = *(const bf16x8*)&sB[p][(wn + ni * 16 + m16) * 32 + quad * 8];
#pragma unroll
    for (int mi = 0; mi < 4; mi++)
#pragma unroll
      for (int ni = 0; ni < 4; ni++)
        acc[mi][ni] = __builtin_amdgcn_mfma_f32_16x16x32_bf16(af[mi], bf_[ni], acc[mi][ni], 0, 0, 0);
  };

  stage(0, 0);
  for (int k0 = 0; k0 < K; k0 += 64) {   // K is a multiple of 64 (1024/4096)
    __syncthreads();                     // drains stage(0,k0); protects buf1 from prev iter
    if (k0 + 32 < K) stage(1, k0 + 32);
    compute(0);
    __syncthreads();                     // drains stage(1); protects buf0
    if (k0 + 64 < K) stage(0, k0 + 64);
    compute(1);
  }

  float bv4[4];
#pragma unroll
  for (int ni = 0; ni < 4; ni++) bv4[ni] = bf2f(bias[bn + wn + ni * 16 + m16]);

#pragma unroll
  for (int mi = 0; mi < 4; mi++) {
#pragma unroll
    for (int ni = 0; ni < 4; ni++) {
      long col = bn + wn + ni * 16 + m16;
      long rowb = bm + wm + mi * 16 + quad * 4;
#pragma unroll
      for (int r = 0; r < 4; r++) {
        float v = acc[mi][ni][r] + bv4[ni];
        if (act) v = fmaxf(v, 0.f);
        C[(rowb + r) * (long)ldc + col] = f2bf(v);
      }
    }
  }
}

// ---------------- GEMM 256x256, BK=64, 8-wave, 4-phase counted-vmcnt schedule ----
// Frozen at R7 state (in-session ceiling ~760 TF for K=1024 shapes).
// mode 0: C[row*ldc+col]. mode 1 (QKV): cols<2048 -> C (ldc=2048, Q|K),
//   cols>=2048 -> V stored TRANSPOSED into Vt[b*16+h][dk][s].
#define MF16 __builtin_amdgcn_mfma_f32_16x16x32_bf16

#define TILE256(BUF, NBUF, DOA, DOB, KA, KB, VMS)                              \
  {                                                                            \
    /* p0: read A mi0-3 + B ni0-1, stage A-half0 of next tile */               \
    _Pragma("unroll") for (int mi = 0; mi < 4; mi++)                           \
      _Pragma("unroll") for (int kk = 0; kk < 2; kk++)                         \
        afr[mi][kk] = *(const bf16x8*)&sA[BUF][offA + mi * 1024 + kof[kk]];    \
    _Pragma("unroll") for (int ni = 0; ni < 2; ni++)                           \
      _Pragma("unroll") for (int kk = 0; kk < 2; kk++)                         \
        bfr[ni][kk] = *(const bf16x8*)&sB[BUF][offB + ni * 1024 + kof[kk]];    \
    if (DOA) stA(NBUF, 0, KA);                                                 \
    __builtin_amdgcn_s_barrier();                                              \
    asm volatile("s_waitcnt lgkmcnt(0)");                                      \
    __builtin_amdgcn_s_setprio(1);                                             \
    _Pragma("unroll") for (int kk = 0; kk < 2; kk++)                           \
      _Pragma("unroll") for (int mi = 0; mi < 4; mi++)                         \
        _Pragma("unroll") for (int ni = 0; ni < 2; ni++)                       \
          acc[mi][ni] = MF16(afr[mi][kk], bfr[ni][kk], acc[mi][ni], 0, 0, 0);  \
    __builtin_amdgcn_s_setprio(0);                                             \
    __builtin_amdgcn_s_barrier();                                              \
    /* p1: read B ni2-3 (A held), stage A-half1 */                             \
    _Pragma("unroll") for (int ni = 0; ni < 2; ni++)                           \
      _Pragma("unroll") for (int kk = 0; kk < 2; kk++)                         \
        bfr[2 + ni][kk] = *(const bf16x8*)&sB[BUF][offB + (2 + ni) * 1024 + kof[kk]]; \
    if (DOA) stA(NBUF, 1, KA);                                                 \
    __builtin_amdgcn_s_barrier();                                              \
    asm volatile("s_waitcnt lgkmcnt(0)");                                      \
    __builtin_amdgcn_s_setprio(1);                                             \
    _Pragma("unroll") for (int kk = 0; kk < 2; kk++)                           \
      _Pragma("unroll") for (int mi = 0; mi < 4; mi++)                         \
        _Pragma("unroll") for (int ni = 0; ni < 2; ni++)                       \
          acc[mi][2 + ni] = MF16(afr[mi][kk], bfr[2 + ni][kk], acc[mi][2 + ni], 0, 0, 0); \
    __builtin_amdgcn_s_setprio(0);                                             \
    __builtin_amdgcn_s_barrier();                                              \
    /* p2: read A mi4-7 (B held), stage B-half0 of tile T+2 (B of T read-done @p1) */ \
    _Pragma("unroll") for (int mi = 0; mi < 4; mi++)                           \
      _Pragma("unroll") for (int kk = 0; kk < 2; kk++)                         \
        afr[mi][kk] = *(const bf16x8*)&sA[BUF][offA + (4 + mi) * 1024 + kof[kk]]; \
    if (DOB) stB(BUF, 0, KB);                                                  \
    __builtin_amdgcn_s_barrier();                                              \
    asm volatile("s_waitcnt lgkmcnt(0)");                                      \
    __builtin_amdgcn_s_setprio(1);                                             \
    _Pragma("unroll") for (int kk = 0; kk < 2; kk++)                           \
      _Pragma("unroll") for (int mi = 0; mi < 4; mi++)                         \
        _Pragma("unroll") for (int ni = 0; ni < 2; ni++)                       \
          acc[4 + mi][2 + ni] = MF16(afr[mi][kk], bfr[2 + ni][kk], acc[4 + mi][2 + ni], 0, 0, 0); \
    __builtin_amdgcn_s_setprio(0);                                             \
    __builtin_amdgcn_s_barrier();                                              \
    /* p3: no reads, stage B-half1, counted vmcnt fence for next tile */       \
    if (DOB) stB(BUF, 1, KB);                                                  \
    asm volatile("s_waitcnt vmcnt(" VMS ")" ::: "memory");                     \
    __builtin_amdgcn_s_barrier();                                              \
    asm volatile("s_waitcnt lgkmcnt(0)");                                      \
    __builtin_amdgcn_s_setprio(1);                                             \
    _Pragma("unroll") for (int kk = 0; kk < 2; kk++)                           \
      _Pragma("unroll") for (int mi = 0; mi < 4; mi++)                         \
        _Pragma("unroll") for (int ni = 0; ni < 2; ni++)                       \
          acc[4 + mi][ni] = MF16(afr[mi][kk], bfr[ni][kk], acc[4 + mi][ni], 0, 0, 0); \
    __builtin_amdgcn_s_setprio(0);                                             \
    __builtin_amdgcn_s_barrier();                                              \
  }

__global__ __launch_bounds__(512, 2) void gemm256(const u16* __restrict__ A,
                                                  const u16* __restrict__ Bt,
                                                  const u16* __restrict__ bias,
                                                  u16* __restrict__ C,
                                                  int M, int N, int K, int act,
                                                  int ldc, u16* __restrict__ Vt,
                                                  int mode) {
  __shared__ alignas(16) u16 sA[2][16384];   // 2 x [2 halves][128 rows][64 cols]
  __shared__ alignas(16) u16 sB[2][16384];
  const int tid = threadIdx.x;
  const int wv = tid >> 6, lane = tid & 63;
  const int m16 = lane & 15, quad = lane >> 4;
  const int wr = wv >> 2, wc = wv & 3;

  // T1: bijective XCD-aware remap of the linear block id (tn fastest)
  const int NT = N >> 8;
  int bid = blockIdx.x;
  {
    const int nwg = gridDim.x;
    const int q = nwg >> 3, r = nwg & 7;
    const int xcd = bid & 7, lp = bid >> 3;
    bid = (xcd < r ? xcd * (q + 1) : r * (q + 1) + (xcd - r) * q) + lp;
  }
  const long bm = (long)(bid / NT) * 256;
  const long bn = (long)(bid % NT) * 256;

  // staging: linear LDS dest, inverse-swizzled global source (rule: both-sides)
  const int r0 = wv * 16 + (lane >> 3);             // row within 128-row half
  const int cstg = ((lane & 7) ^ (lane >> 3)) * 8;  // swizzled col (elements)
  const u16* gA0 = A  + (bm + r0) * (long)K + cstg;
  const u16* gA1 = A  + (bm + 128 + r0) * (long)K + cstg;
  const u16* gB0 = Bt + (bn + r0) * (long)K + cstg;
  const u16* gB1 = Bt + (bn + 128 + r0) * (long)K + cstg;
  const long k8 = 8 * (long)K;

  auto stA = [&](int nb, int h, int k0) {
    const u16* s = (h ? gA1 : gA0) + k0;
    u16* d = &sA[nb][h * 8192 + wv * 1024];
    async16(s, d);
    async16(s + k8, d + 512);
  };
  auto stB = [&](int nb, int h, int k0) {
    const u16* s = (h ? gB1 : gB0) + k0;
    u16* d = &sB[nb][h * 8192 + wv * 1024];
    async16(s, d);
    async16(s + k8, d + 512);
  };

  // fragment-read addressing (swizzled): granule(kk) = (kk*4+quad)^(m16&7)
  const int qs = quad ^ (m16 & 3);
  const int hb = (m16 >> 2) & 1;
  const int kof[2] = {hb * 32, 32 - hb * 32};
  const int offA = wr * 8192 + m16 * 64 + qs * 8;                    // + mi*1024
  const int offB = (wc >> 1) * 8192 + (wc & 1) * 4096 + m16 * 64 + qs * 8; // + ni*1024

  f32x4 acc[8][4];
#pragma unroll
  for (int i = 0; i < 8; i++)
#pragma unroll
    for (int j = 0; j < 4; j++) acc[i][j] = (f32x4){0.f, 0.f, 0.f, 0.f};
  bf16x8 afr[4][2], bfr[4][2];

  const int KT = K >> 6;   // K-tiles of 64; K multiple of 128, KT even >= 2

  // prologue: tile0 (A0,A1,B0,B1) -> buf0; B halves of tile1 -> buf1
  stA(0, 0, 0); stA(0, 1, 0); stB(0, 0, 0); stB(0, 1, 0);
  stB(1, 0, 64); stB(1, 1, 64);
  asm volatile("s_waitcnt vmcnt(4)" ::: "memory");   // tile0 landed; B(tile1) in flight
  __builtin_amdgcn_s_barrier();

  int T = 0;
  for (; T + 2 < KT; T += 2) {
    const int kA1 = (T + 1) << 6, kB2 = (T + 2) << 6, kB3 = (T + 3) << 6;
    TILE256(0, 1, true, true, kA1, kB2, "4");
    TILE256(1, 0, true, true, kB2, kB3, "4");
  }
  {  // tail pair (T = KT-2): no B stages remain -> must drain fully
    const int kA1 = (T + 1) << 6;
    TILE256(0, 1, true, false, kA1, 0, "0");
    TILE256(1, 0, false, false, 0, 0, "0");
  }

  float bv4[4];
#pragma unroll
  for (int ni = 0; ni < 4; ni++) bv4[ni] = bf2f(bias[bn + wc * 64 + ni * 16 + m16]);

#pragma unroll
  for (int mi = 0; mi < 8; mi++) {
#pragma unroll
    for (int ni = 0; ni < 4; ni++) {
      long col = bn + wc * 64 + ni * 16 + m16;
      long rowb = bm + wr * 128 + mi * 16 + quad * 4;
      if (mode == 1 && col >= 2048) {
        // V -> Vt[(b*16+h)][dk][s], 4 acc rows = consecutive s
        int hh = ((int)col >> 6) & 15, dk = (int)col & 63;
        int bb = (int)(rowb >> 10), ss = (int)(rowb & 1023);
        u16 t4[4];
#pragma unroll
        for (int r = 0; r < 4; r++) t4[r] = f2bf(acc[mi][ni][r] + bv4[ni]);
        *(uint2*)&Vt[(((long)bb * 16 + hh) * 64 + dk) * 1024 + ss] = *(const uint2*)t4;
      } else {
#pragma unroll
        for (int r = 0; r < 4; r++) {
          float v = acc[mi][ni][r] + bv4[ni];
          if (act) v = fmaxf(v, 0.f);
          C[(rowb + r) * (long)ldc + col] = f2bf(v);
        }
      }
    }
  }
}

// ---------------- GEMM 256x128, BK=64, 8-wave, counted-vmcnt schedule ----------
// For N=1024 GEMMs (FF2, Wo): grid = (M/256)*(N/128) = 256 blocks = 1 full round.
#define TILE128(BUF, NBUF, DOA, DOB, KA, KB, VMS)                              \
  {                                                                            \
    /* p0: read A mi0-3 + B ni0-1; stage A-half0(T+1) */                       \
    _Pragma("unroll") for (int mi = 0; mi < 4; mi++)                           \
      _Pragma("unroll") for (int kk = 0; kk < 2; kk++)                         \
        afr[mi][kk] = *(const bf16x8*)&sA[BUF][offA + mi * 1024 + kof[kk]];    \
    _Pragma("unroll") for (int ni = 0; ni < 2; ni++)                           \
      _Pragma("unroll") for (int kk = 0; kk < 2; kk++)                         \
        bfr[ni][kk] = *(const bf16x8*)&sB[BUF][offB + ni * 1024 + kof[kk]];    \
    if (DOA) stA(NBUF, 0, KA);                                                 \
    __builtin_amdgcn_s_barrier();                                              \
    asm volatile("s_waitcnt lgkmcnt(0)");                                      \
    __builtin_amdgcn_s_setprio(1);                                             \
    _Pragma("unroll") for (int kk = 0; kk < 2; kk++)                           \
      _Pragma("unroll") for (int mi = 0; mi < 4; mi++)                         \
        _Pragma("unroll") for (int ni = 0; ni < 2; ni++)                       \
          acc[mi][ni] = MF16(afr[mi][kk], bfr[ni][kk], acc[mi][ni], 0, 0, 0);  \
    __builtin_amdgcn_s_setprio(0);                                             \
    __builtin_amdgcn_s_barrier();                                              \
    /* p1: read B ni2-3 (A held); stage A-half1(T+1) */                        \
    _Pragma("unroll") for (int ni = 0; ni < 2; ni++)                           \
      _Pragma("unroll") for (int kk = 0; kk < 2; kk++)                         \
        bfr[2 + ni][kk] = *(const bf16x8*)&sB[BUF][offB + (2 + ni) * 1024 + kof[kk]]; \
    if (DOA) stA(NBUF, 1, KA);                                                 \
    __builtin_amdgcn_s_barrier();                                              \
    asm volatile("s_waitcnt lgkmcnt(0)");                                      \
    __builtin_amdgcn_s_setprio(1);                                             \
    _Pragma("unroll") for (int kk = 0; kk < 2; kk++)                           \
      _Pragma("unroll") for (int mi = 0; mi < 4; mi++)                         \
        _Pragma("unroll") for (int ni = 0; ni < 2; ni++)                       \
          acc[mi][2 + ni] = MF16(afr[mi][kk], bfr[2 + ni][kk], acc[mi][2 + ni], 0, 0, 0); \
    __builtin_amdgcn_s_setprio(0);                                             \
    __builtin_amdgcn_s_barrier();                                              \
    /* p2: stage B(T+2) into BUF (same parity); counted fence */               \
    if (DOB) stB(BUF, KB);                                                     \
    asm volatile("s_waitcnt vmcnt(" VMS ")" ::: "memory");                     \
    __builtin_amdgcn_s_barrier();                                              \
  }

__global__ __launch_bounds__(512, 2) void gemm256x128(const u16* __restrict__ A,
                                                      const u16* __restrict__ Bt,
                                                      const u16* __restrict__ bias,
                                                      u16* __restrict__ C,
                                                      int M, int N, int K, int act) {
  __shared__ alignas(16) u16 sA[2][16384];   // [2 halves][128 rows][64 cols] swz
  __shared__ alignas(16) u16 sB[2][8192];    // [128 rows][64 cols] swz
  const int tid = threadIdx.x;
  const int wv = tid >> 6, lane = tid & 63;
  const int m16 = lane & 15, quad = lane >> 4;
  const int wr = wv >> 1, wc = wv & 1;       // 4M x 2N waves, 64x64 each

  const int NT = N >> 7;
  int bid = blockIdx.x;
  {
    const int nwg = gridDim.x;
    const int q = nwg >> 3, r = nwg & 7;
    const int xcd = bid & 7, lp = bid >> 3;
    bid = (xcd < r ? xcd * (q + 1) : r * (q + 1) + (xcd - r) * q) + lp;
  }
  const long bm = (long)(bid / NT) * 256;
  const long bn = (long)(bid % NT) * 128;

  const int r0 = wv * 16 + (lane >> 3);
  const int cstg = ((lane & 7) ^ (lane >> 3)) * 8;
  const u16* gA0 = A + (bm + r0) * (long)K + cstg;
  const u16* gA1 = A + (bm + 128 + r0) * (long)K + cstg;
  const u16* gB0 = Bt + (bn + r0) * (long)K + cstg;
  const long k8 = 8 * (long)K;

  auto stA = [&](int nb, int h, int k0) {
    const u16* s = (h ? gA1 : gA0) + k0;
    u16* d = &sA[nb][h * 8192 + wv * 1024];
    async16(s, d);
    async16(s + k8, d + 512);
  };
  auto stB = [&](int nb, int k0) {
    const u16* s = gB0 + k0;
    u16* d = &sB[nb][wv * 1024];
    async16(s, d);
    async16(s + k8, d + 512);
  };

  const int qs = quad ^ (m16 & 3);
  const int hb = (m16 >> 2) & 1;
  const int kof[2] = {hb * 32, 32 - hb * 32};
  const int offA = (wr >> 1) * 8192 + (wr & 1) * 4096 + m16 * 64 + qs * 8; // +mi*1024
  const int offB = wc * 4096 + m16 * 64 + qs * 8;                          // +ni*1024

  f32x4 acc[4][4];
#pragma unroll
  for (int i = 0; i < 4; i++)
#pragma unroll
    for (int j = 0; j < 4; j++) acc[i][j] = (f32x4){0.f, 0.f, 0.f, 0.f};
  bf16x8 afr[4][2], bfr[4][2];

  const int KT = K >> 6;   // even (K multiple of 128)

  // prologue: tile0 (A0,A1,B) -> buf0; B(tile1) -> buf1
  stA(0, 0, 0); stA(0, 1, 0); stB(0, 0);
  stB(1, 64);
  asm volatile("s_waitcnt vmcnt(2)" ::: "memory");   // tile0 landed; B(1) in flight
  __builtin_amdgcn_s_barrier();

  int T = 0;
  for (; T + 2 < KT; T += 2) {
    TILE128(0, 1, true, true, (T + 1) << 6, (T + 2) << 6, "2");
    TILE128(1, 0, true, true, (T + 2) << 6, (T + 3) << 6, "2");
  }
  // tail pair: tile KT-2 stages only A(KT-1); must drain fully
  TILE128(0, 1, true, false, (T + 1) << 6, 0, "0");
  TILE128(1, 0, false, false, 0, 0, "0");

  float bv4[4];
#pragma unroll
  for (int ni = 0; ni < 4; ni++) bv4[ni] = bf2f(bias[bn + wc * 64 + ni * 16 + m16]);

#pragma unroll
  for (int mi = 0; mi < 4; mi++) {
#pragma unroll
    for (int ni = 0; ni < 4; ni++) {
      long col = bn + wc * 64 + ni * 16 + m16;
      long rowb = bm + wr * 64 + mi * 16 + quad * 4;
#pragma unroll
      for (int r = 0; r < 4; r++) {
        float v = acc[mi][ni][r] + bv4[ni];
        if (act) v = fmaxf(v, 0.f);
        C[(rowb + r) * (long)N + col] = f2bf(v);
      }
    }
  }
}

// ---------------- flash attention v3: exp2-domain softmax + defer-max ----------
// qk: [8192][2048] (Q|K per token), Vt: [b*16+h][64 dk][1024 s] (from QKV GEMM).
// R8: (1) log2(e) folded into Q pre-scale -> bare exp2f (v_exp_f32), saves the
// implicit x1.4427 mul per exp; (2) T13 defer-max: skip O/l rescale when
// __all(pm - mrun <= 11.5) (= e-domain THR 8, HK's value). P bounded by 2^11.5,
// fine in bf16; rescale branch is wave-uniform via __all.
__global__ __launch_bounds__(256, 4) void attn_fwd(const u16* __restrict__ qk,
                                                   const u16* __restrict__ Vt,
                                                   u16* __restrict__ attnO) {
  __shared__ alignas(16) u16 sQP[8192];  // Q [128][64] swz; later per-wave P[32][64] @ wv*4096B
  __shared__ alignas(16) u16 sK[4096];   // [64 key][64 dk] swz
  __shared__ alignas(16) u16 sVt[4096];  // [64 dk][64 key] swz
  const int tid = threadIdx.x;
  const int bh = blockIdx.x;
  const int qt = blockIdx.y;
  const int b = bh >> 4, h = bh & 15;
  const int wv = tid >> 6, lane = tid & 63;
  const int m16 = lane & 15, quad = lane >> 4;
  const int kk = tid >> 3;               // staging row 0..31
  const int t7 = tid & 7;

  char* cQP = (char*)sQP;
  char* cK = (char*)sK;
  char* cV = (char*)sVt;

  // ---- stage Q [128 q][64 dk], scaled by log2(e)/sqrt(DK), swizzled ----
  {
    int row = tid >> 1, half = tid & 1;
    const u16* g = qk + (long)(b * Sq + qt * 128 + row) * 2048 + h * 64 + half * 32;
#pragma unroll
    for (int j = 0; j < 4; j++) {
      uint4 raw = *(const uint4*)(g + j * 8);
      const u16* pv = (const u16*)&raw;
      u16 t[8];
#pragma unroll
      for (int e = 0; e < 8; e++) t[e] = f2bf(bf2f(pv[e]) * 0.1803368801f);
      *(uint4*)(cQP + swzb(row, half * 64 + j * 16)) = *(const uint4*)t;
    }
  }
  __syncthreads();
  // Q frags: qf[qt2][s] = Q[wv*32 + qt2*16 + m16][s*32 + quad*8 ..]
  bf16x8 qf[2][2];
#pragma unroll
  for (int qt2 = 0; qt2 < 2; qt2++)
#pragma unroll
    for (int s = 0; s < 2; s++)
      qf[qt2][s] = *(const bf16x8*)(cQP + swzb(wv * 32 + qt2 * 16 + m16, s * 64 + quad * 16));

  f32x4 o[4][2];
#pragma unroll
  for (int dt = 0; dt < 4; dt++)
#pragma unroll
    for (int qt2 = 0; qt2 < 2; qt2++) o[dt][qt2] = (f32x4){0.f, 0.f, 0.f, 0.f};
  float mrun[2] = {-1e30f, -1e30f}, lrun[2] = {0.f, 0.f};

  const u16* gK = qk + (long)(b * Sq + kk) * 2048 + 1024 + h * 64 + t7 * 8;
  const u16* gV = Vt + ((long)bh * 64 + kk) * 1024 + t7 * 8;
  const long stepK = (long)64 * 2048;
  const int off0 = swzb(kk, t7 * 16);        // (kk+32)&7 == kk&7 -> +4096 bytes
  const int off1 = off0 + 4096;

  uint4 rk0 = *(const uint4*)gK;
  uint4 rk1 = *(const uint4*)(gK + 32 * 2048);
  uint4 rv0 = *(const uint4*)gV;
  uint4 rv1 = *(const uint4*)(gV + 32 * 1024);

  for (int kt = 0; kt < 16; kt++) {
    __syncthreads();   // previous iteration's K/V frag reads done
    *(uint4*)(cK + off0) = rk0;
    *(uint4*)(cK + off1) = rk1;
    *(uint4*)(cV + off0) = rv0;
    *(uint4*)(cV + off1) = rv1;
    __syncthreads();   // tiles published

    // S^T[key][q]: st[kt2][qt2], col=q=qt2*16+m16, row=key=kt2*16+quad*4+r
    f32x4 st[4][2];
#pragma unroll
    for (int kt2 = 0; kt2 < 4; kt2++)
#pragma unroll
      for (int qt2 = 0; qt2 < 2; qt2++) st[kt2][qt2] = (f32x4){0.f, 0.f, 0.f, 0.f};
    __builtin_amdgcn_s_setprio(1);
#pragma unroll
    for (int s = 0; s < 2; s++) {
      bf16x8 kf[4];
#pragma unroll
      for (int kt2 = 0; kt2 < 4; kt2++)
        kf[kt2] = *(const bf16x8*)(cK + swzb(kt2 * 16 + m16, s * 64 + quad * 16));
#pragma unroll
      for (int kt2 = 0; kt2 < 4; kt2++)
#pragma unroll
        for (int qt2 = 0; qt2 < 2; qt2++)
          st[kt2][qt2] = MF16(kf[kt2], qf[qt2][s], st[kt2][qt2], 0, 0, 0);
    }
    __builtin_amdgcn_s_setprio(0);

    if (kt < 15) {     // prefetch next K/V (hidden under softmax+PV)
      rk0 = *(const uint4*)(gK + (long)(kt + 1) * stepK);
      rk1 = *(const uint4*)(gK + (long)(kt + 1) * stepK + 32 * 2048);
      rv0 = *(const uint4*)(gV + (kt + 1) * 64);
      rv1 = *(const uint4*)(gV + (kt + 1) * 64 + 32 * 1024);
    }

    // online softmax per qt2 (lane owns q = qt2*16+m16; keys split across quad)
    // exp2 domain; T13 defer-max (wave-uniform skip via __all)
    char* cP = cQP + wv * 4096;
#pragma unroll
    for (int qt2 = 0; qt2 < 2; qt2++) {
      float pm = st[0][qt2][0];
#pragma unroll
      for (int kt2 = 0; kt2 < 4; kt2++)
#pragma unroll
        for (int r = 0; r < 4; r++) pm = fmaxf(pm, st[kt2][qt2][r]);
      pm = fmaxf(pm, __shfl_xor(pm, 16));
      pm = fmaxf(pm, __shfl_xor(pm, 32));
      if (!__all(pm - mrun[qt2] <= 11.5f)) {
        float mnew = fmaxf(mrun[qt2], pm);
        float al = exp2f(mrun[qt2] - mnew);
        mrun[qt2] = mnew;
        lrun[qt2] *= al;
#pragma unroll
        for (int dt = 0; dt < 4; dt++)
#pragma unroll
          for (int r = 0; r < 4; r++) o[dt][qt2][r] *= al;
      }
      float rs = 0.f;
#pragma unroll
      for (int kt2 = 0; kt2 < 4; kt2++) {
        u16 t4[4];
#pragma unroll
        for (int r = 0; r < 4; r++) {
          float p = exp2f(st[kt2][qt2][r] - mrun[qt2]);
          rs += p;
          t4[r] = f2bf(p);
        }
        *(uint2*)(cP + swzb(qt2 * 16 + m16, kt2 * 32 + quad * 8)) = *(const uint2*)t4;
      }
      rs += __shfl_xor(rs, 16);
      rs += __shfl_xor(rs, 32);
      lrun[qt2] += rs;
    }

    // O^T[dk][q] += V^T[dk][key] * P^T : A = V^T frags, B = P frags
    bf16x8 pb[2][2];
#pragma unroll
    for (int qt2 = 0; qt2 < 2; qt2++)
#pragma unroll
      for (int ks = 0; ks < 2; ks++)
        pb[qt2][ks] = *(const bf16x8*)(cP + swzb(qt2 * 16 + m16, ks * 64 + quad * 16));
    __builtin_amdgcn_s_setprio(1);
#pragma unroll
    for (int dt = 0; dt < 4; dt++) {
      bf16x8 v0 = *(const bf16x8*)(cV + swzb(dt * 16 + m16, quad * 16));
      bf16x8 v1 = *(const bf16x8*)(cV + swzb(dt * 16 + m16, 64 + quad * 16));
#pragma unroll
      for (int qt2 = 0; qt2 < 2; qt2++) {
        o[dt][qt2] = MF16(v0, pb[qt2][0], o[dt][qt2], 0, 0, 0);
        o[dt][qt2] = MF16(v1, pb[qt2][1], o[dt][qt2], 0, 0, 0);
      }
    }
    __builtin_amdgcn_s_setprio(0);
  }

#pragma unroll
  for (int qt2 = 0; qt2 < 2; qt2++) {
    float rl = 1.f / lrun[qt2];
    long tok = (long)(b * Sq + qt * 128 + wv * 32 + qt2 * 16 + m16);
#pragma unroll
    for (int dt = 0; dt < 4; dt++) {
      u16 t4[4];
#pragma unroll
      for (int r = 0; r < 4; r++) t4[r] = f2bf(o[dt][qt2][r] * rl);
      *(uint2*)&attnO[tok * 1024 + h * 64 + dt * 16 + quad * 4] = *(const uint2*)t4;
    }
  }
}

// ---------------- add + LayerNorm (bf16 out, internal), uint2-vectorized -------
__global__ __launch_bounds__(256) void add_ln(const u16* __restrict__ X,
                                              const u16* __restrict__ Y,
                                              const u16* __restrict__ g,
                                              const u16* __restrict__ be,
                                              u16* __restrict__ out) {
  const int row = blockIdx.x;
  const int t = threadIdx.x;
  const long base = (long)row * Dq;
  const int i4 = t * 4;
  uint2 xr = *(const uint2*)&X[base + i4];
  uint2 yr = *(const uint2*)&Y[base + i4];
  const u16* xp = (const u16*)&xr;
  const u16* yp = (const u16*)&yr;
  float v[4]; float s = 0.f, ss = 0.f;
#pragma unroll
  for (int i = 0; i < 4; i++) {
    float x = bf2f(xp[i]) + bf2f(yp[i]);
    v[i] = x; s += x; ss += x * x;
  }
#pragma unroll
  for (int off = 32; off > 0; off >>= 1) { s += __shfl_down(s, off); ss += __shfl_down(ss, off); }
  __shared__ float red[8];
  int wv = t >> 6, ln = t & 63;
  if (ln == 0) { red[wv] = s; red[4 + wv] = ss; }
  __syncthreads();
  s = red[0] + red[1] + red[2] + red[3];
  ss = red[4] + red[5] + red[6] + red[7];
  float mean = s * (1.f / Dq);
  float var = ss * (1.f / Dq) - mean * mean;
  float rstd = rsqrtf(var + 1e-5f);
  uint2 gr = *(const uint2*)&g[i4];
  uint2 br = *(const uint2*)&be[i4];
  const u16* gp = (const u16*)&gr;
  const u16* bp = (const u16*)&br;
  u16 o4[4];
#pragma unroll
  for (int i = 0; i < 4; i++)
    o4[i] = f2bf((v[i] - mean) * rstd * bf2f(gp[i]) + bf2f(bp[i]));
  *(uint2*)&out[base + i4] = *(const uint2*)o4;
}

// ---------------- final add + LayerNorm, dual-dtype store, vectorized ----------
__global__ __launch_bounds__(256) void add_ln_out(const u16* __restrict__ X,
                                                  const u16* __restrict__ Y,
                                                  const u16* __restrict__ g,
                                                  const u16* __restrict__ be,
                                                  void* __restrict__ out,
                                                  const u32* __restrict__ outflag) {
  const u32 fp32 = *outflag;
  const int row = blockIdx.x;
  const int t = threadIdx.x;
  const long base = (long)row * Dq;
  const int i4 = t * 4;
  uint2 xr = *(const uint2*)&X[base + i4];
  uint2 yr = *(const uint2*)&Y[base + i4];
  const u16* xp = (const u16*)&xr;
  const u16* yp = (const u16*)&yr;
  float v[4]; float s = 0.f, ss = 0.f;
#pragma unroll
  for (int i = 0; i < 4; i++) {
    float x = bf2f(xp[i]) + bf2f(yp[i]);
    v[i] = x; s += x; ss += x * x;
  }
#pragma unroll
  for (int off = 32; off > 0; off >>= 1) { s += __shfl_down(s, off); ss += __shfl_down(ss, off); }
  __shared__ float red[8];
  int wv = t >> 6, ln = t & 63;
  if (ln == 0) { red[wv] = s; red[4 + wv] = ss; }
  __syncthreads();
  s = red[0] + red[1] + red[2] + red[3];
  ss = red[4] + red[5] + red[6] + red[7];
  float mean = s * (1.f / Dq);
  float var = ss * (1.f / Dq) - mean * mean;
  float rstd = rsqrtf(var + 1e-5f);
  uint2 gr = *(const uint2*)&g[i4];
  uint2 br = *(const uint2*)&be[i4];
  const u16* gp = (const u16*)&gr;
  const u16* bp = (const u16*)&br;
  if (fp32) {
    float4 o4;
    o4.x = (v[0] - mean) * rstd * bf2f(gp[0]) + bf2f(bp[0]);
    o4.y = (v[1] - mean) * rstd * bf2f(gp[1]) + bf2f(bp[1]);
    o4.z = (v[2] - mean) * rstd * bf2f(gp[2]) + bf2f(bp[2]);
    o4.w = (v[3] - mean) * rstd * bf2f(gp[3]) + bf2f(bp[3]);
    *(float4*)((float*)out + base + i4) = o4;
  } else {
    u16 o4[4];
#pragma unroll
    for (int i = 0; i < 4; i++)
      o4[i] = f2bf((v[i] - mean) * rstd * bf2f(gp[i]) + bf2f(bp[i]));
    *(uint2*)((u16*)out + base + i4) = *(const uint2*)o4;
  }
}

extern "C" void kernel_launch(void* const* d_in, const int* in_sizes, int n_in,
                              void* d_out, int out_size, void* d_ws, size_t ws_size,
                              hipStream_t stream) {
  char* ws = (char*)d_ws;
  size_t off = 0;
  auto alloc = [&](size_t bytes) {
    void* p = ws + off;
    off += (bytes + 255) & ~(size_t)255;
    return p;
  };
  u32* flags  = (u32*)alloc(32 * 4);
  u16* Wqkv_t = (u16*)alloc((size_t)3072 * 1024 * 2);   // 6 MB
  u16* Wo_t   = (u16*)alloc((size_t)1024 * 1024 * 2);   // 2 MB
  u16* W1_t   = (u16*)alloc((size_t)4096 * 1024 * 2);   // 8 MB
  u16* W2_t   = (u16*)alloc((size_t)1024 * 4096 * 2);   // 8 MB
  u16* svec   = (u16*)alloc((size_t)13312 * 2);         // all small vectors
  u16* src_bf = (u16*)alloc((size_t)TOK * 1024 * 2);    // 16 MB
  u16* regA   = (u16*)alloc((size_t)TOK * 4096 * 2);    // 64 MB
  size_t need_chunk2 = off;                              // h1(32MB) fits inside regA
  size_t need_full   = off + (size_t)TOK * 4096 * 2 / 2; // +32MB so h1(64MB) spans past regA

  u16* outw = (u16*)d_out;
  int CH;  // rows per FF chunk
  if (ws_size >= need_full) { CH = 8192; (void)alloc((size_t)32 << 20); }
  else if (ws_size >= need_chunk2) CH = 4096;
  else if (ws_size >= need_chunk2 - ((size_t)16 << 20)) CH = 2048;
  else {
    diag_ws_too_small<<<1, 1, 0, stream>>>(outw, 8000.0f + (float)(ws_size >> 20));
    return;
  }

  u16* qk    = regA;                          // [0,32)  Q|K per token [8192][2048]
  u16* Vt    = regA + (size_t)TOK * 2048;     // [32,48) V transposed [128][64][1024]
  u16* attnb = regA + (size_t)TOK * 3072;     // [48,64)
  u16* proj  = regA;                          // [0,16)  after qk/Vt dead
  u16* x     = regA + (size_t)TOK * 1024;     // [16,32)
  u16* h1    = regA + (size_t)TOK * 2048;     // [32,..) CH*4096*2 bytes (Vt dead by then)
  u16* f2    = src_bf;                        // src_bf dead after x computed

  u16* bqkv = svec + 0;      // 3072
  u16* bo_c = svec + 3072;
  u16* g1_c = svec + 4096;
  u16* be1_c = svec + 5120;
  u16* b1_c = svec + 6144;   // 4096
  u16* b2_c = svec + 10240;
  u16* g2_c = svec + 11264;
  u16* be2_c = svec + 12288;

  // ---- dtype detection ----
  InTab itab;
  for (int i = 0; i < 17; i++) { itab.p[i] = d_in[i]; itab.n[i] = in_sizes[i]; }
  detect_all<<<dim3(17), 256, 0, stream>>>(itab, flags);

  // ---- all weight transposes in one launch ----
  pack_all<<<dim3(3072), 256, 0, stream>>>(d_in[1], d_in[3], d_in[5], d_in[7], d_in[11], d_in[13],
                                           Wqkv_t, Wo_t, W1_t, W2_t, flags);

  // ---- small vectors ----
  CvtTab ct;
  const int srcs[10] = {2, 4, 6, 8, 9, 10, 12, 14, 15, 16};
  const int offs[10] = {0, 1024, 2048, 3072, 4096, 5120, 6144, 10240, 11264, 12288};
  const int lens[10] = {1024, 1024, 1024, 1024, 1024, 1024, 4096, 1024, 1024, 1024};
  for (int e = 0; e < 10; e++) { ct.p[e] = d_in[srcs[e]]; ct.flagidx[e] = srcs[e]; ct.dstoff[e] = offs[e]; ct.n[e] = lens[e]; }
  cvt_small<<<dim3(10), 256, 0, stream>>>(ct, svec, flags);

  // ---- src -> bf16 ----
  cvt_src<<<dim3(TOK * 1024 / (256 * 8)), 256, 0, stream>>>(d_in[0], src_bf, &flags[0]);

  // qkv = src @ Wqkv + b: Q|K -> qk [8192][2048], V -> Vt transposed (mode 1)
  gemm256<<<dim3(32 * 12), 512, 0, stream>>>(src_bf, Wqkv_t, bqkv, qk, TOK, 3072, 1024, 0,
                                             2048, Vt, 1);
  // attention [8192,1024]; grid: bh-major keeps one (b,h)'s K/V on one XCD's L2
  attn_fwd<<<dim3(128, 8), 256, 0, stream>>>(qk, Vt, attnb);
  // proj = attn @ Wo + bo  (256x128 tile: 32x8 = 256 blocks = 1 full round)
  gemm256x128<<<dim3(256), 512, 0, stream>>>(attnb, Wo_t, bo_c, proj, TOK, 1024, 1024, 0);
  // x = LN(src + proj)
  add_ln<<<dim3(TOK), 256, 0, stream>>>(src_bf, proj, g1_c, be1_c, x);
  // FF chunked by CH rows
  for (int c = 0; c < TOK / CH; c++) {
    const u16* xc = x + (size_t)c * CH * 1024;
    u16* f2c = f2 + (size_t)c * CH * 1024;
    if (CH >= 4096) {
      gemm256<<<dim3((CH / 256) * 16), 512, 0, stream>>>(xc, W1_t, b1_c, h1, CH, 4096, 1024, 1,
                                                         4096, nullptr, 0);
    } else {
      gemm_bt<<<dim3(CH / 128, 32), 256, 0, stream>>>(xc, W1_t, b1_c, h1, CH, 4096, 1024, 1, 4096);
    }
    if (CH == 8192) {
      gemm256x128<<<dim3((CH / 256) * 8), 512, 0, stream>>>(h1, W2_t, b2_c, f2c, CH, 1024, 4096, 0);
    } else {
      gemm_bt<<<dim3(CH / 128, 8), 256, 0, stream>>>(h1, W2_t, b2_c, f2c, CH, 1024, 4096, 0, 1024);
    }
  }
  // out = LN(x + f2), stored in src's container dtype
  add_ln_out<<<dim3(TOK), 256, 0, stream>>>(x, f2, g2_c, be2_c, d_out, &flags[0]);
  diag_mixed<<<1, 1, 0, stream>>>(flags, d_out);
}

// Round 9
// 549.003 us; speedup vs baseline: 1.0833x; 1.0347x over previous
//
#include <hip/hip_runtime.h>

// B=8 S=1024 D=1024 H=16 DK=64 F=4096 -- fp32 containers (bf16-valued), detected per-tensor
#define Bq 8
#define Sq 1024
#define Dq 1024
#define Hq 16
#define DKq 64
#define Fq 4096
#define TOK (Bq*Sq)   // 8192

typedef unsigned short u16;
typedef unsigned int u32;
typedef __bf16 bf16x8 __attribute__((ext_vector_type(8)));
typedef float  f32x4  __attribute__((ext_vector_type(4)));

__device__ __forceinline__ float bf2f(u16 u) {
  u32 x = ((u32)u) << 16;
  float f; __builtin_memcpy(&f, &x, 4); return f;
}
__device__ __forceinline__ u16 f2bf(float f) {
  u32 u; __builtin_memcpy(&u, &f, 4);
  u += 0x7fffu + ((u >> 16) & 1u);
  return (u16)(u >> 16);
}
// async global->LDS, 16B/lane; LDS dest = wave-uniform base + lane*16
__device__ __forceinline__ void async16(const u16* g, u16* l) {
  __builtin_amdgcn_global_load_lds(
      (__attribute__((address_space(1))) void*)(g),
      (__attribute__((address_space(3))) void*)(l), 16, 0, 0);
}
__device__ __forceinline__ u16 load_in(const void* p, long idx, u32 fp32) {
  return fp32 ? f2bf(((const float*)p)[idx]) : ((const u16*)p)[idx];
}
// XOR-swizzled byte offset within a [rows][64 bf16] tile (128B rows)
__device__ __forceinline__ int swzb(int row, int colb) {
  return row * 128 + (colb ^ ((row & 7) << 4));
}

// ---------------- dtype detection: one launch, 17 blocks ----------------
struct InTab { const void* p[17]; int n[17]; };

__global__ void detect_all(InTab tab, u32* flags) {
  __shared__ int sh[3][256];
  int bi = blockIdx.x;
  const u16* buf = (const u16*)tab.p[bi];
  long n = tab.n[bi];
  long m = n < 65536 ? n : 65536;
  int t = threadIdx.x;
  int nanpat = 0, evz = 0, oddnz = 0;
  for (long i = t; i < m; i += 256) {
    u16 v = buf[i];
    if ((v & 0x7F80u) == 0x7F80u) nanpat++;
    if ((i & 1) == 0) { if (v == 0) evz++; }
    else { if (v != 0) oddnz++; }
  }
  sh[0][t] = nanpat; sh[1][t] = evz; sh[2][t] = oddnz;
  __syncthreads();
  for (int s = 128; s > 0; s >>= 1) {
    if (t < s) { sh[0][t] += sh[0][t+s]; sh[1][t] += sh[1][t+s]; sh[2][t] += sh[2][t+s]; }
    __syncthreads();
  }
  if (t == 0) {
    long half = m / 2;
    bool fp32 = (sh[0][0] > 8) ||
                (sh[1][0] > (half * 9) / 10 && sh[2][0] > (half * 9) / 10);
    flags[bi] = fp32 ? 1u : 0u;
  }
}

__global__ void diag_ws_too_small(u16* out, float code) { out[0] = f2bf(code); }

// ---------------- fused preprocessing: pack + small-vec cvt + src cvt ----------
// R9: one launch instead of three (launch overhead ~10us each).
// blocks [0,3072): weight transpose 64x64 tile-jobs (vectorized loads)
// blocks [3072,3082): small vectors
// blocks [3082,7178): src -> bf16, 8 elems/thread
struct CvtTab { const void* p[10]; int flagidx[10]; int dstoff[10]; int n[10]; };

__global__ __launch_bounds__(256) void prep_all(const void* __restrict__ Wq,
                                                const void* __restrict__ Wk,
                                                const void* __restrict__ Wv,
                                                const void* __restrict__ Wo,
                                                const void* __restrict__ W1,
                                                const void* __restrict__ W2,
                                                u16* __restrict__ Wqkv_t,
                                                u16* __restrict__ Wo_t,
                                                u16* __restrict__ W1_t,
                                                u16* __restrict__ W2_t,
                                                CvtTab ct, u16* __restrict__ svec,
                                                const void* __restrict__ src,
                                                u16* __restrict__ src_bf,
                                                const u32* __restrict__ flags) {
  int id = blockIdx.x;
  if (id >= 3082) {           // ---- src -> bf16 ----
    u32 f = flags[0];
    long i8 = ((long)(id - 3082) * 256 + threadIdx.x) * 8;
    if (f) {
      const float4* f4 = (const float4*)((const float*)src + i8);
      float4 a = f4[0], b = f4[1];
      u16 v[8] = {f2bf(a.x), f2bf(a.y), f2bf(a.z), f2bf(a.w),
                  f2bf(b.x), f2bf(b.y), f2bf(b.z), f2bf(b.w)};
      *(uint4*)(src_bf + i8) = *(const uint4*)v;
    } else {
      *(uint4*)(src_bf + i8) = *(const uint4*)((const u16*)src + i8);
    }
    return;
  }
  if (id >= 3072) {           // ---- small vectors ----
    int e = id - 3072;
    u32 f = flags[ct.flagidx[e]];
    const void* p = ct.p[e];
    int n = ct.n[e], o = ct.dstoff[e];
    for (int i = threadIdx.x; i < n; i += 256) svec[o + i] = load_in(p, i, f);
    return;
  }
  // ---- weight transpose tile-jobs ----
  const void* in; u16* out; u32 f; int R, C; long zin; int r0, c0;
  if (id < 768) {            // Wq/Wk/Wv: [16 h][1024 d][64 dk] -> [h*64+dk][d]
    int w = id >> 8, t = id & 255;
    int z = t >> 4, xt = t & 15;
    in = (w == 0) ? Wq : ((w == 1) ? Wk : Wv);
    f = flags[(w == 0) ? 1 : ((w == 1) ? 3 : 5)];
    R = 1024; C = 64;
    zin = (long)z * 65536;
    out = Wqkv_t + (long)w * 1048576 + (long)z * 65536;
    r0 = xt * 64; c0 = 0;
  } else if (id < 1024) {    // Wo [1024][1024]
    int t = id - 768; int xt = t & 15, yt = t >> 4;
    in = Wo; f = flags[7]; R = 1024; C = 1024; zin = 0; out = Wo_t;
    r0 = xt * 64; c0 = yt * 64;
  } else if (id < 2048) {    // W1 [1024][4096]
    int t = id - 1024; int xt = t & 15, yt = t >> 4;
    in = W1; f = flags[11]; R = 1024; C = 4096; zin = 0; out = W1_t;
    r0 = xt * 64; c0 = yt * 64;
  } else {                   // W2 [4096][1024]
    int t = id - 2048; int xt = t & 63, yt = t >> 6;
    in = W2; f = flags[13]; R = 4096; C = 1024; zin = 0; out = W2_t;
    r0 = xt * 64; c0 = yt * 64;
  }
  __shared__ u16 tile[64][65];
  {
    int row = threadIdx.x >> 2;        // 0..63
    int cg  = (threadIdx.x & 3) << 4;  // 0,16,32,48
    long srcidx = zin + (long)(r0 + row) * C + (c0 + cg);  // multiple of 16 elems
    u16 tv[16];
    if (f) {
      const float4* p4 = (const float4*)((const float*)in + srcidx);
#pragma unroll
      for (int j = 0; j < 4; j++) {
        float4 v = p4[j];
        tv[j * 4 + 0] = f2bf(v.x); tv[j * 4 + 1] = f2bf(v.y);
        tv[j * 4 + 2] = f2bf(v.z); tv[j * 4 + 3] = f2bf(v.w);
      }
    } else {
      const uint4* p8 = (const uint4*)((const u16*)in + srcidx);
      *(uint4*)&tv[0] = p8[0];
      *(uint4*)&tv[8] = p8[1];
    }
#pragma unroll
    for (int j = 0; j < 16; j++) tile[row][cg + j] = tv[j];
  }
  __syncthreads();
  int tx = threadIdx.x & 63, ty = threadIdx.x >> 6;
#pragma unroll
  for (int it = 0; it < 16; it++) {
    int cc = it * 4 + ty;
    out[(long)(c0 + cc) * R + r0 + tx] = tile[tx][cc];
  }
}

// ---------------- GEMM: C[M,N] = A[M,K] @ Bt[N,K]^T + bias, optional ReLU --------
// 128x128 tile, BK=32, double-buffered LDS. Kept only for chunked fallbacks.
__global__ __launch_bounds__(256) void gemm_bt(const u16* __restrict__ A,
                                               const u16* __restrict__ Bt,
                                               const u16* __restrict__ bias,
                                               u16* __restrict__ C,
                                               int M, int N, int K, int act,
                                               int ldc) {
  __shared__ alignas(16) u16 sA[2][128 * 32];
  __shared__ alignas(16) u16 sB[2][128 * 32];
  const int tid = threadIdx.x;
  const int wv = tid >> 6, lane = tid & 63;
  const int m16 = lane & 15, quad = lane >> 4;
  const long bm = (long)blockIdx.x * 128;
  const long bn = (long)blockIdx.y * 128;
  const int wm = (wv >> 1) * 64, wn = (wv & 1) * 64;

  f32x4 acc[4][4];
#pragma unroll
  for (int i = 0; i < 4; i++)
#pragma unroll
    for (int j = 0; j < 4; j++) acc[i][j] = (f32x4){0.f, 0.f, 0.f, 0.f};

  const int row_s = tid >> 2;          // 0..63
  const int col_s = (tid & 3) * 8;
  const u16* gA0 = A + (bm + row_s) * (long)K + col_s;
  const u16* gA1 = gA0 + 64 * (long)K;
  const u16* gB0 = Bt + (bn + row_s) * (long)K + col_s;
  const u16* gB1 = gB0 + 64 * (long)K;

  auto stage = [&](int p, int k) {
    async16(gA0 + k, &sA[p][wv * 512]);
    async16(gA1 + k, &sA[p][2048 + wv * 512]);
    async16(gB0 + k, &sB[p][wv * 512]);
    async16(gB1 + k, &sB[p][2048 + wv * 512]);
  };
  auto compute = [&](int p) {
    bf16x8 af[4], bf_[4];
#pragma unroll
    for (int mi = 0; mi < 4; mi++)
      af[mi] = *(const bf16x8*)&sA[p][(wm + mi * 16 + m16) * 32 + quad * 8];
#pragma unroll
    for (int ni = 0; ni < 4; ni++)
      bf_[ni] = *(const bf16x8*)&sB[p][(wn + ni * 16 + m16) * 32 + quad * 8];
#pragma unroll
    for (int mi = 0; mi < 4; mi++)
#pragma unroll
      for (int ni = 0; ni < 4; ni++)
        acc[mi][ni] = __builtin_amdgcn_mfma_f32_16x16x32_bf16(af[mi], bf_[ni], acc[mi][ni], 0, 0, 0);
  };

  stage(0, 0);
  for (int k0 = 0; k0 < K; k0 += 64) {   // K is a multiple of 64 (1024/4096)
    __syncthreads();                     // drains stage(0,k0); protects buf1 from prev iter
    if (k0 + 32 < K) stage(1, k0 + 32);
    compute(0);
    __syncthreads();                     // drains stage(1); protects buf0
    if (k0 + 64 < K) stage(0, k0 + 64);
    compute(1);
  }

  float bv4[4];
#pragma unroll
  for (int ni = 0; ni < 4; ni++) bv4[ni] = bf2f(bias[bn + wn + ni * 16 + m16]);

#pragma unroll
  for (int mi = 0; mi < 4; mi++) {
#pragma unroll
    for (int ni = 0; ni < 4; ni++) {
      long col = bn + wn + ni * 16 + m16;
      long rowb = bm + wm + mi * 16 + quad * 4;
#pragma unroll
      for (int r = 0; r < 4; r++) {
        float v = acc[mi][ni][r] + bv4[ni];
        if (act) v = fmaxf(v, 0.f);
        C[(rowb + r) * (long)ldc + col] = f2bf(v);
      }
    }
  }
}

// ---------------- GEMM 256x256, BK=64, 8-wave, 4-phase counted-vmcnt schedule ----
// Used for FF1 only (N=4096: grid 512 = exactly 2 occupancy rounds).
#define MF16 __builtin_amdgcn_mfma_f32_16x16x32_bf16

#define TILE256(BUF, NBUF, DOA, DOB, KA, KB, VMS)                              \
  {                                                                            \
    /* p0: read A mi0-3 + B ni0-1, stage A-half0 of next tile */               \
    _Pragma("unroll") for (int mi = 0; mi < 4; mi++)                           \
      _Pragma("unroll") for (int kk = 0; kk < 2; kk++)                         \
        afr[mi][kk] = *(const bf16x8*)&sA[BUF][offA + mi * 1024 + kof[kk]];    \
    _Pragma("unroll") for (int ni = 0; ni < 2; ni++)                           \
      _Pragma("unroll") for (int kk = 0; kk < 2; kk++)                         \
        bfr[ni][kk] = *(const bf16x8*)&sB[BUF][offB + ni * 1024 + kof[kk]];    \
    if (DOA) stA(NBUF, 0, KA);                                                 \
    __builtin_amdgcn_s_barrier();                                              \
    asm volatile("s_waitcnt lgkmcnt(0)");                                      \
    __builtin_amdgcn_s_setprio(1);                                             \
    _Pragma("unroll") for (int kk = 0; kk < 2; kk++)                           \
      _Pragma("unroll") for (int mi = 0; mi < 4; mi++)                         \
        _Pragma("unroll") for (int ni = 0; ni < 2; ni++)                       \
          acc[mi][ni] = MF16(afr[mi][kk], bfr[ni][kk], acc[mi][ni], 0, 0, 0);  \
    __builtin_amdgcn_s_setprio(0);                                             \
    __builtin_amdgcn_s_barrier();                                              \
    /* p1: read B ni2-3 (A held), stage A-half1 */                             \
    _Pragma("unroll") for (int ni = 0; ni < 2; ni++)                           \
      _Pragma("unroll") for (int kk = 0; kk < 2; kk++)                         \
        bfr[2 + ni][kk] = *(const bf16x8*)&sB[BUF][offB + (2 + ni) * 1024 + kof[kk]]; \
    if (DOA) stA(NBUF, 1, KA);                                                 \
    __builtin_amdgcn_s_barrier();                                              \
    asm volatile("s_waitcnt lgkmcnt(0)");                                      \
    __builtin_amdgcn_s_setprio(1);                                             \
    _Pragma("unroll") for (int kk = 0; kk < 2; kk++)                           \
      _Pragma("unroll") for (int mi = 0; mi < 4; mi++)                         \
        _Pragma("unroll") for (int ni = 0; ni < 2; ni++)                       \
          acc[mi][2 + ni] = MF16(afr[mi][kk], bfr[2 + ni][kk], acc[mi][2 + ni], 0, 0, 0); \
    __builtin_amdgcn_s_setprio(0);                                             \
    __builtin_amdgcn_s_barrier();                                              \
    /* p2: read A mi4-7 (B held), stage B-half0 of tile T+2 (B of T read-done @p1) */ \
    _Pragma("unroll") for (int mi = 0; mi < 4; mi++)                           \
      _Pragma("unroll") for (int kk = 0; kk < 2; kk++)                         \
        afr[mi][kk] = *(const bf16x8*)&sA[BUF][offA + (4 + mi) * 1024 + kof[kk]]; \
    if (DOB) stB(BUF, 0, KB);                                                  \
    __builtin_amdgcn_s_barrier();                                              \
    asm volatile("s_waitcnt lgkmcnt(0)");                                      \
    __builtin_amdgcn_s_setprio(1);                                             \
    _Pragma("unroll") for (int kk = 0; kk < 2; kk++)                           \
      _Pragma("unroll") for (int mi = 0; mi < 4; mi++)                         \
        _Pragma("unroll") for (int ni = 0; ni < 2; ni++)                       \
          acc[4 + mi][2 + ni] = MF16(afr[mi][kk], bfr[2 + ni][kk], acc[4 + mi][2 + ni], 0, 0, 0); \
    __builtin_amdgcn_s_setprio(0);                                             \
    __builtin_amdgcn_s_barrier();                                              \
    /* p3: no reads, stage B-half1, counted vmcnt fence for next tile */       \
    if (DOB) stB(BUF, 1, KB);                                                  \
    asm volatile("s_waitcnt vmcnt(" VMS ")" ::: "memory");                     \
    __builtin_amdgcn_s_barrier();                                              \
    asm volatile("s_waitcnt lgkmcnt(0)");                                      \
    __builtin_amdgcn_s_setprio(1);                                             \
    _Pragma("unroll") for (int kk = 0; kk < 2; kk++)                           \
      _Pragma("unroll") for (int mi = 0; mi < 4; mi++)                         \
        _Pragma("unroll") for (int ni = 0; ni < 2; ni++)                       \
          acc[4 + mi][ni] = MF16(afr[mi][kk], bfr[ni][kk], acc[4 + mi][ni], 0, 0, 0); \
    __builtin_amdgcn_s_setprio(0);                                             \
    __builtin_amdgcn_s_barrier();                                              \
  }

__global__ __launch_bounds__(512, 2) void gemm256(const u16* __restrict__ A,
                                                  const u16* __restrict__ Bt,
                                                  const u16* __restrict__ bias,
                                                  u16* __restrict__ C,
                                                  int M, int N, int K, int act,
                                                  int ldc) {
  __shared__ alignas(16) u16 sA[2][16384];   // 2 x [2 halves][128 rows][64 cols]
  __shared__ alignas(16) u16 sB[2][16384];
  const int tid = threadIdx.x;
  const int wv = tid >> 6, lane = tid & 63;
  const int m16 = lane & 15, quad = lane >> 4;
  const int wr = wv >> 2, wc = wv & 3;

  // T1: bijective XCD-aware remap of the linear block id (tn fastest)
  const int NT = N >> 8;
  int bid = blockIdx.x;
  {
    const int nwg = gridDim.x;
    const int q = nwg >> 3, r = nwg & 7;
    const int xcd = bid & 7, lp = bid >> 3;
    bid = (xcd < r ? xcd * (q + 1) : r * (q + 1) + (xcd - r) * q) + lp;
  }
  const long bm = (long)(bid / NT) * 256;
  const long bn = (long)(bid % NT) * 256;

  // staging: linear LDS dest, inverse-swizzled global source (rule: both-sides)
  const int r0 = wv * 16 + (lane >> 3);             // row within 128-row half
  const int cstg = ((lane & 7) ^ (lane >> 3)) * 8;  // swizzled col (elements)
  const u16* gA0 = A  + (bm + r0) * (long)K + cstg;
  const u16* gA1 = A  + (bm + 128 + r0) * (long)K + cstg;
  const u16* gB0 = Bt + (bn + r0) * (long)K + cstg;
  const u16* gB1 = Bt + (bn + 128 + r0) * (long)K + cstg;
  const long k8 = 8 * (long)K;

  auto stA = [&](int nb, int h, int k0) {
    const u16* s = (h ? gA1 : gA0) + k0;
    u16* d = &sA[nb][h * 8192 + wv * 1024];
    async16(s, d);
    async16(s + k8, d + 512);
  };
  auto stB = [&](int nb, int h, int k0) {
    const u16* s = (h ? gB1 : gB0) + k0;
    u16* d = &sB[nb][h * 8192 + wv * 1024];
    async16(s, d);
    async16(s + k8, d + 512);
  };

  // fragment-read addressing (swizzled): granule(kk) = (kk*4+quad)^(m16&7)
  const int qs = quad ^ (m16 & 3);
  const int hb = (m16 >> 2) & 1;
  const int kof[2] = {hb * 32, 32 - hb * 32};
  const int offA = wr * 8192 + m16 * 64 + qs * 8;                    // + mi*1024
  const int offB = (wc >> 1) * 8192 + (wc & 1) * 4096 + m16 * 64 + qs * 8; // + ni*1024

  f32x4 acc[8][4];
#pragma unroll
  for (int i = 0; i < 8; i++)
#pragma unroll
    for (int j = 0; j < 4; j++) acc[i][j] = (f32x4){0.f, 0.f, 0.f, 0.f};
  bf16x8 afr[4][2], bfr[4][2];

  const int KT = K >> 6;   // K-tiles of 64; K multiple of 128, KT even >= 2

  // prologue: tile0 (A0,A1,B0,B1) -> buf0; B halves of tile1 -> buf1
  stA(0, 0, 0); stA(0, 1, 0); stB(0, 0, 0); stB(0, 1, 0);
  stB(1, 0, 64); stB(1, 1, 64);
  asm volatile("s_waitcnt vmcnt(4)" ::: "memory");   // tile0 landed; B(tile1) in flight
  __builtin_amdgcn_s_barrier();

  int T = 0;
  for (; T + 2 < KT; T += 2) {
    const int kA1 = (T + 1) << 6, kB2 = (T + 2) << 6, kB3 = (T + 3) << 6;
    TILE256(0, 1, true, true, kA1, kB2, "4");
    TILE256(1, 0, true, true, kB2, kB3, "4");
  }
  {  // tail pair (T = KT-2): no B stages remain -> must drain fully
    const int kA1 = (T + 1) << 6;
    TILE256(0, 1, true, false, kA1, 0, "0");
    TILE256(1, 0, false, false, 0, 0, "0");
  }

  float bv4[4];
#pragma unroll
  for (int ni = 0; ni < 4; ni++) bv4[ni] = bf2f(bias[bn + wc * 64 + ni * 16 + m16]);

#pragma unroll
  for (int mi = 0; mi < 8; mi++) {
#pragma unroll
    for (int ni = 0; ni < 4; ni++) {
      long col = bn + wc * 64 + ni * 16 + m16;
      long rowb = bm + wr * 128 + mi * 16 + quad * 4;
#pragma unroll
      for (int r = 0; r < 4; r++) {
        float v = acc[mi][ni][r] + bv4[ni];
        if (act) v = fmaxf(v, 0.f);
        C[(rowb + r) * (long)ldc + col] = f2bf(v);
      }
    }
  }
}

// ---------------- GEMM 256x128, BK=64, 8-wave, counted-vmcnt schedule ----------
// grid = (M/256)*(N/128), 96KB LDS -> 1 block/CU. Round-exact grids:
//   QKV N=3072: 768 = 3.0 rounds (vs gemm256's 384 = 1.5 -> 33% tail waste)
//   Wo  N=1024: 256 = 1.0;  FF2 N=1024: 256 = 1.0
// mode 1 (QKV): col<2048 -> C (ldc=2048, Q|K); col>=2048 -> Vt[b*16+h][dk][s].
#define TILE128(BUF, NBUF, DOA, DOB, KA, KB, VMS)                              \
  {                                                                            \
    /* p0: read A mi0-3 + B ni0-1; stage A-half0(T+1) */                       \
    _Pragma("unroll") for (int mi = 0; mi < 4; mi++)                           \
      _Pragma("unroll") for (int kk = 0; kk < 2; kk++)                         \
        afr[mi][kk] = *(const bf16x8*)&sA[BUF][offA + mi * 1024 + kof[kk]];    \
    _Pragma("unroll") for (int ni = 0; ni < 2; ni++)                           \
      _Pragma("unroll") for (int kk = 0; kk < 2; kk++)                         \
        bfr[ni][kk] = *(const bf16x8*)&sB[BUF][offB + ni * 1024 + kof[kk]];    \
    if (DOA) stA(NBUF, 0, KA);                                                 \
    __builtin_amdgcn_s_barrier();                                              \
    asm volatile("s_waitcnt lgkmcnt(0)");                                      \
    __builtin_amdgcn_s_setprio(1);                                             \
    _Pragma("unroll") for (int kk = 0; kk < 2; kk++)                           \
      _Pragma("unroll") for (int mi = 0; mi < 4; mi++)                         \
        _Pragma("unroll") for (int ni = 0; ni < 2; ni++)                       \
          acc[mi][ni] = MF16(afr[mi][kk], bfr[ni][kk], acc[mi][ni], 0, 0, 0);  \
    __builtin_amdgcn_s_setprio(0);                                             \
    __builtin_amdgcn_s_barrier();                                              \
    /* p1: read B ni2-3 (A held); stage A-half1(T+1) */                        \
    _Pragma("unroll") for (int ni = 0; ni < 2; ni++)                           \
      _Pragma("unroll") for (int kk = 0; kk < 2; kk++)                         \
        bfr[2 + ni][kk] = *(const bf16x8*)&sB[BUF][offB + (2 + ni) * 1024 + kof[kk]]; \
    if (DOA) stA(NBUF, 1, KA);                                                 \
    __builtin_amdgcn_s_barrier();                                              \
    asm volatile("s_waitcnt lgkmcnt(0)");                                      \
    __builtin_amdgcn_s_setprio(1);                                             \
    _Pragma("unroll") for (int kk = 0; kk < 2; kk++)                           \
      _Pragma("unroll") for (int mi = 0; mi < 4; mi++)                         \
        _Pragma("unroll") for (int ni = 0; ni < 2; ni++)                       \
          acc[mi][2 + ni] = MF16(afr[mi][kk], bfr[2 + ni][kk], acc[mi][2 + ni], 0, 0, 0); \
    __builtin_amdgcn_s_setprio(0);                                             \
    __builtin_amdgcn_s_barrier();                                              \
    /* p2: stage B(T+2) into BUF (same parity); counted fence */               \
    if (DOB) stB(BUF, KB);                                                     \
    asm volatile("s_waitcnt vmcnt(" VMS ")" ::: "memory");                     \
    __builtin_amdgcn_s_barrier();                                              \
  }

__global__ __launch_bounds__(512, 2) void gemm256x128(const u16* __restrict__ A,
                                                      const u16* __restrict__ Bt,
                                                      const u16* __restrict__ bias,
                                                      u16* __restrict__ C,
                                                      int M, int N, int K, int act,
                                                      int ldc, u16* __restrict__ Vt,
                                                      int mode) {
  __shared__ alignas(16) u16 sA[2][16384];   // [2 halves][128 rows][64 cols] swz
  __shared__ alignas(16) u16 sB[2][8192];    // [128 rows][64 cols] swz
  const int tid = threadIdx.x;
  const int wv = tid >> 6, lane = tid & 63;
  const int m16 = lane & 15, quad = lane >> 4;
  const int wr = wv >> 1, wc = wv & 1;       // 4M x 2N waves, 64x64 each

  const int NT = N >> 7;
  int bid = blockIdx.x;
  {
    const int nwg = gridDim.x;
    const int q = nwg >> 3, r = nwg & 7;
    const int xcd = bid & 7, lp = bid >> 3;
    bid = (xcd < r ? xcd * (q + 1) : r * (q + 1) + (xcd - r) * q) + lp;
  }
  const long bm = (long)(bid / NT) * 256;
  const long bn = (long)(bid % NT) * 128;

  const int r0 = wv * 16 + (lane >> 3);
  const int cstg = ((lane & 7) ^ (lane >> 3)) * 8;
  const u16* gA0 = A + (bm + r0) * (long)K + cstg;
  const u16* gA1 = A + (bm + 128 + r0) * (long)K + cstg;
  const u16* gB0 = Bt + (bn + r0) * (long)K + cstg;
  const long k8 = 8 * (long)K;

  auto stA = [&](int nb, int h, int k0) {
    const u16* s = (h ? gA1 : gA0) + k0;
    u16* d = &sA[nb][h * 8192 + wv * 1024];
    async16(s, d);
    async16(s + k8, d + 512);
  };
  auto stB = [&](int nb, int k0) {
    const u16* s = gB0 + k0;
    u16* d = &sB[nb][wv * 1024];
    async16(s, d);
    async16(s + k8, d + 512);
  };

  const int qs = quad ^ (m16 & 3);
  const int hb = (m16 >> 2) & 1;
  const int kof[2] = {hb * 32, 32 - hb * 32};
  const int offA = (wr >> 1) * 8192 + (wr & 1) * 4096 + m16 * 64 + qs * 8; // +mi*1024
  const int offB = wc * 4096 + m16 * 64 + qs * 8;                          // +ni*1024

  f32x4 acc[4][4];
#pragma unroll
  for (int i = 0; i < 4; i++)
#pragma unroll
    for (int j = 0; j < 4; j++) acc[i][j] = (f32x4){0.f, 0.f, 0.f, 0.f};
  bf16x8 afr[4][2], bfr[4][2];

  const int KT = K >> 6;   // even (K multiple of 128)

  // prologue: tile0 (A0,A1,B) -> buf0; B(tile1) -> buf1
  stA(0, 0, 0); stA(0, 1, 0); stB(0, 0);
  stB(1, 64);
  asm volatile("s_waitcnt vmcnt(2)" ::: "memory");   // tile0 landed; B(1) in flight
  __builtin_amdgcn_s_barrier();

  int T = 0;
  for (; T + 2 < KT; T += 2) {
    TILE128(0, 1, true, true, (T + 1) << 6, (T + 2) << 6, "2");
    TILE128(1, 0, true, true, (T + 2) << 6, (T + 3) << 6, "2");
  }
  // tail pair: tile KT-2 stages only A(KT-1); must drain fully
  TILE128(0, 1, true, false, (T + 1) << 6, 0, "0");
  TILE128(1, 0, false, false, 0, 0, "0");

  float bv4[4];
#pragma unroll
  for (int ni = 0; ni < 4; ni++) bv4[ni] = bf2f(bias[bn + wc * 64 + ni * 16 + m16]);

#pragma unroll
  for (int mi = 0; mi < 4; mi++) {
#pragma unroll
    for (int ni = 0; ni < 4; ni++) {
      long col = bn + wc * 64 + ni * 16 + m16;
      long rowb = bm + wr * 64 + mi * 16 + quad * 4;
      if (mode == 1 && col >= 2048) {
        // V -> Vt[(b*16+h)][dk][s], 4 acc rows = consecutive s
        int hh = ((int)col >> 6) & 15, dk = (int)col & 63;
        int bb = (int)(rowb >> 10), ss = (int)(rowb & 1023);
        u16 t4[4];
#pragma unroll
        for (int r = 0; r < 4; r++) t4[r] = f2bf(acc[mi][ni][r] + bv4[ni]);
        *(uint2*)&Vt[(((long)bb * 16 + hh) * 64 + dk) * 1024 + ss] = *(const uint2*)t4;
      } else {
#pragma unroll
        for (int r = 0; r < 4; r++) {
          float v = acc[mi][ni][r] + bv4[ni];
          if (act) v = fmaxf(v, 0.f);
          C[(rowb + r) * (long)ldc + col] = f2bf(v);
        }
      }
    }
  }
}

// ---------------- flash attention v3: exp2-domain softmax + defer-max ----------
// qk: [8192][2048] (Q|K per token), Vt: [b*16+h][64 dk][1024 s] (from QKV GEMM).
__global__ __launch_bounds__(256, 4) void attn_fwd(const u16* __restrict__ qk,
                                                   const u16* __restrict__ Vt,
                                                   u16* __restrict__ attnO) {
  __shared__ alignas(16) u16 sQP[8192];  // Q [128][64] swz; later per-wave P[32][64] @ wv*4096B
  __shared__ alignas(16) u16 sK[4096];   // [64 key][64 dk] swz
  __shared__ alignas(16) u16 sVt[4096];  // [64 dk][64 key] swz
  const int tid = threadIdx.x;
  const int bh = blockIdx.x;
  const int qt = blockIdx.y;
  const int b = bh >> 4, h = bh & 15;
  const int wv = tid >> 6, lane = tid & 63;
  const int m16 = lane & 15, quad = lane >> 4;
  const int kk = tid >> 3;               // staging row 0..31
  const int t7 = tid & 7;

  char* cQP = (char*)sQP;
  char* cK = (char*)sK;
  char* cV = (char*)sVt;

  // ---- stage Q [128 q][64 dk], scaled by log2(e)/sqrt(DK), swizzled ----
  {
    int row = tid >> 1, half = tid & 1;
    const u16* g = qk + (long)(b * Sq + qt * 128 + row) * 2048 + h * 64 + half * 32;
#pragma unroll
    for (int j = 0; j < 4; j++) {
      uint4 raw = *(const uint4*)(g + j * 8);
      const u16* pv = (const u16*)&raw;
      u16 t[8];
#pragma unroll
      for (int e = 0; e < 8; e++) t[e] = f2bf(bf2f(pv[e]) * 0.1803368801f);
      *(uint4*)(cQP + swzb(row, half * 64 + j * 16)) = *(const uint4*)t;
    }
  }
  __syncthreads();
  // Q frags: qf[qt2][s] = Q[wv*32 + qt2*16 + m16][s*32 + quad*8 ..]
  bf16x8 qf[2][2];
#pragma unroll
  for (int qt2 = 0; qt2 < 2; qt2++)
#pragma unroll
    for (int s = 0; s < 2; s++)
      qf[qt2][s] = *(const bf16x8*)(cQP + swzb(wv * 32 + qt2 * 16 + m16, s * 64 + quad * 16));

  f32x4 o[4][2];
#pragma unroll
  for (int dt = 0; dt < 4; dt++)
#pragma unroll
    for (int qt2 = 0; qt2 < 2; qt2++) o[dt][qt2] = (f32x4){0.f, 0.f, 0.f, 0.f};
  float mrun[2] = {-1e30f, -1e30f}, lrun[2] = {0.f, 0.f};

  const u16* gK = qk + (long)(b * Sq + kk) * 2048 + 1024 + h * 64 + t7 * 8;
  const u16* gV = Vt + ((long)bh * 64 + kk) * 1024 + t7 * 8;
  const long stepK = (long)64 * 2048;
  const int off0 = swzb(kk, t7 * 16);        // (kk+32)&7 == kk&7 -> +4096 bytes
  const int off1 = off0 + 4096;

  uint4 rk0 = *(const uint4*)gK;
  uint4 rk1 = *(const uint4*)(gK + 32 * 2048);
  uint4 rv0 = *(const uint4*)gV;
  uint4 rv1 = *(const uint4*)(gV + 32 * 1024);

  for (int kt = 0; kt < 16; kt++) {
    __syncthreads();   // previous iteration's K/V frag reads done
    *(uint4*)(cK + off0) = rk0;
    *(uint4*)(cK + off1) = rk1;
    *(uint4*)(cV + off0) = rv0;
    *(uint4*)(cV + off1) = rv1;
    __syncthreads();   // tiles published

    // S^T[key][q]: st[kt2][qt2], col=q=qt2*16+m16, row=key=kt2*16+quad*4+r
    f32x4 st[4][2];
#pragma unroll
    for (int kt2 = 0; kt2 < 4; kt2++)
#pragma unroll
      for (int qt2 = 0; qt2 < 2; qt2++) st[kt2][qt2] = (f32x4){0.f, 0.f, 0.f, 0.f};
    __builtin_amdgcn_s_setprio(1);
#pragma unroll
    for (int s = 0; s < 2; s++) {
      bf16x8 kf[4];
#pragma unroll
      for (int kt2 = 0; kt2 < 4; kt2++)
        kf[kt2] = *(const bf16x8*)(cK + swzb(kt2 * 16 + m16, s * 64 + quad * 16));
#pragma unroll
      for (int kt2 = 0; kt2 < 4; kt2++)
#pragma unroll
        for (int qt2 = 0; qt2 < 2; qt2++)
          st[kt2][qt2] = MF16(kf[kt2], qf[qt2][s], st[kt2][qt2], 0, 0, 0);
    }
    __builtin_amdgcn_s_setprio(0);

    if (kt < 15) {     // prefetch next K/V (hidden under softmax+PV)
      rk0 = *(const uint4*)(gK + (long)(kt + 1) * stepK);
      rk1 = *(const uint4*)(gK + (long)(kt + 1) * stepK + 32 * 2048);
      rv0 = *(const uint4*)(gV + (kt + 1) * 64);
      rv1 = *(const uint4*)(gV + (kt + 1) * 64 + 32 * 1024);
    }

    // online softmax per qt2 (lane owns q = qt2*16+m16; keys split across quad)
    // exp2 domain; T13 defer-max (wave-uniform skip via __all)
    char* cP = cQP + wv * 4096;
#pragma unroll
    for (int qt2 = 0; qt2 < 2; qt2++) {
      float pm = st[0][qt2][0];
#pragma unroll
      for (int kt2 = 0; kt2 < 4; kt2++)
#pragma unroll
        for (int r = 0; r < 4; r++) pm = fmaxf(pm, st[kt2][qt2][r]);
      pm = fmaxf(pm, __shfl_xor(pm, 16));
      pm = fmaxf(pm, __shfl_xor(pm, 32));
      if (!__all(pm - mrun[qt2] <= 11.5f)) {
        float mnew = fmaxf(mrun[qt2], pm);
        float al = exp2f(mrun[qt2] - mnew);
        mrun[qt2] = mnew;
        lrun[qt2] *= al;
#pragma unroll
        for (int dt = 0; dt < 4; dt++)
#pragma unroll
          for (int r = 0; r < 4; r++) o[dt][qt2][r] *= al;
      }
      float rs = 0.f;
#pragma unroll
      for (int kt2 = 0; kt2 < 4; kt2++) {
        u16 t4[4];
#pragma unroll
        for (int r = 0; r < 4; r++) {
          float p = exp2f(st[kt2][qt2][r] - mrun[qt2]);
          rs += p;
          t4[r] = f2bf(p);
        }
        *(uint2*)(cP + swzb(qt2 * 16 + m16, kt2 * 32 + quad * 8)) = *(const uint2*)t4;
      }
      rs += __shfl_xor(rs, 16);
      rs += __shfl_xor(rs, 32);
      lrun[qt2] += rs;
    }

    // O^T[dk][q] += V^T[dk][key] * P^T : A = V^T frags, B = P frags
    bf16x8 pb[2][2];
#pragma unroll
    for (int qt2 = 0; qt2 < 2; qt2++)
#pragma unroll
      for (int ks = 0; ks < 2; ks++)
        pb[qt2][ks] = *(const bf16x8*)(cP + swzb(qt2 * 16 + m16, ks * 64 + quad * 16));
    __builtin_amdgcn_s_setprio(1);
#pragma unroll
    for (int dt = 0; dt < 4; dt++) {
      bf16x8 v0 = *(const bf16x8*)(cV + swzb(dt * 16 + m16, quad * 16));
      bf16x8 v1 = *(const bf16x8*)(cV + swzb(dt * 16 + m16, 64 + quad * 16));
#pragma unroll
      for (int qt2 = 0; qt2 < 2; qt2++) {
        o[dt][qt2] = MF16(v0, pb[qt2][0], o[dt][qt2], 0, 0, 0);
        o[dt][qt2] = MF16(v1, pb[qt2][1], o[dt][qt2], 0, 0, 0);
      }
    }
    __builtin_amdgcn_s_setprio(0);
  }

#pragma unroll
  for (int qt2 = 0; qt2 < 2; qt2++) {
    float rl = 1.f / lrun[qt2];
    long tok = (long)(b * Sq + qt * 128 + wv * 32 + qt2 * 16 + m16);
#pragma unroll
    for (int dt = 0; dt < 4; dt++) {
      u16 t4[4];
#pragma unroll
      for (int r = 0; r < 4; r++) t4[r] = f2bf(o[dt][qt2][r] * rl);
      *(uint2*)&attnO[tok * 1024 + h * 64 + dt * 16 + quad * 4] = *(const uint2*)t4;
    }
  }
}

// ---------------- add + LayerNorm (bf16 out, internal), uint2-vectorized -------
__global__ __launch_bounds__(256) void add_ln(const u16* __restrict__ X,
                                              const u16* __restrict__ Y,
                                              const u16* __restrict__ g,
                                              const u16* __restrict__ be,
                                              u16* __restrict__ out) {
  const int row = blockIdx.x;
  const int t = threadIdx.x;
  const long base = (long)row * Dq;
  const int i4 = t * 4;
  uint2 xr = *(const uint2*)&X[base + i4];
  uint2 yr = *(const uint2*)&Y[base + i4];
  const u16* xp = (const u16*)&xr;
  const u16* yp = (const u16*)&yr;
  float v[4]; float s = 0.f, ss = 0.f;
#pragma unroll
  for (int i = 0; i < 4; i++) {
    float x = bf2f(xp[i]) + bf2f(yp[i]);
    v[i] = x; s += x; ss += x * x;
  }
#pragma unroll
  for (int off = 32; off > 0; off >>= 1) { s += __shfl_down(s, off); ss += __shfl_down(ss, off); }
  __shared__ float red[8];
  int wv = t >> 6, ln = t & 63;
  if (ln == 0) { red[wv] = s; red[4 + wv] = ss; }
  __syncthreads();
  s = red[0] + red[1] + red[2] + red[3];
  ss = red[4] + red[5] + red[6] + red[7];
  float mean = s * (1.f / Dq);
  float var = ss * (1.f / Dq) - mean * mean;
  float rstd = rsqrtf(var + 1e-5f);
  uint2 gr = *(const uint2*)&g[i4];
  uint2 br = *(const uint2*)&be[i4];
  const u16* gp = (const u16*)&gr;
  const u16* bp = (const u16*)&br;
  u16 o4[4];
#pragma unroll
  for (int i = 0; i < 4; i++)
    o4[i] = f2bf((v[i] - mean) * rstd * bf2f(gp[i]) + bf2f(bp[i]));
  *(uint2*)&out[base + i4] = *(const uint2*)o4;
}

// ---------------- final add + LayerNorm, dual-dtype store + fused diag ---------
__global__ __launch_bounds__(256) void add_ln_out(const u16* __restrict__ X,
                                                  const u16* __restrict__ Y,
                                                  const u16* __restrict__ g,
                                                  const u16* __restrict__ be,
                                                  void* __restrict__ out,
                                                  const u32* __restrict__ flags) {
  const u32 fp32 = flags[0];
  const int row = blockIdx.x;
  const int t = threadIdx.x;
  const long base = (long)row * Dq;
  const int i4 = t * 4;
  uint2 xr = *(const uint2*)&X[base + i4];
  uint2 yr = *(const uint2*)&Y[base + i4];
  const u16* xp = (const u16*)&xr;
  const u16* yp = (const u16*)&yr;
  float v[4]; float s = 0.f, ss = 0.f;
#pragma unroll
  for (int i = 0; i < 4; i++) {
    float x = bf2f(xp[i]) + bf2f(yp[i]);
    v[i] = x; s += x; ss += x * x;
  }
#pragma unroll
  for (int off = 32; off > 0; off >>= 1) { s += __shfl_down(s, off); ss += __shfl_down(ss, off); }
  __shared__ float red[8];
  int wv = t >> 6, ln = t & 63;
  if (ln == 0) { red[wv] = s; red[4 + wv] = ss; }
  __syncthreads();
  s = red[0] + red[1] + red[2] + red[3];
  ss = red[4] + red[5] + red[6] + red[7];
  float mean = s * (1.f / Dq);
  float var = ss * (1.f / Dq) - mean * mean;
  float rstd = rsqrtf(var + 1e-5f);
  uint2 gr = *(const uint2*)&g[i4];
  uint2 br = *(const uint2*)&be[i4];
  const u16* gp = (const u16*)&gr;
  const u16* bp = (const u16*)&br;
  if (fp32) {
    float4 o4;
    o4.x = (v[0] - mean) * rstd * bf2f(gp[0]) + bf2f(bp[0]);
    o4.y = (v[1] - mean) * rstd * bf2f(gp[1]) + bf2f(bp[1]);
    o4.z = (v[2] - mean) * rstd * bf2f(gp[2]) + bf2f(bp[2]);
    o4.w = (v[3] - mean) * rstd * bf2f(gp[3]) + bf2f(bp[3]);
    *(float4*)((float*)out + base + i4) = o4;
  } else {
    u16 o4[4];
#pragma unroll
    for (int i = 0; i < 4; i++)
      o4[i] = f2bf((v[i] - mean) * rstd * bf2f(gp[i]) + bf2f(bp[i]));
    *(uint2*)((u16*)out + base + i4) = *(const uint2*)o4;
  }
  // fused diag_mixed (was its own 1,1 launch): same thread wrote out[0..3]
  // above, so this overwrite is program-ordered.
  if (row == 0 && t == 0) {
    u32 a = flags[0];
    if (flags[1] != a || flags[7] != a || flags[11] != a || flags[13] != a) {
      if (a) ((float*)out)[0] = 3000.0f;
      else ((u16*)out)[0] = f2bf(3000.0f);
    }
  }
}

extern "C" void kernel_launch(void* const* d_in, const int* in_sizes, int n_in,
                              void* d_out, int out_size, void* d_ws, size_t ws_size,
                              hipStream_t stream) {
  char* ws = (char*)d_ws;
  size_t off = 0;
  auto alloc = [&](size_t bytes) {
    void* p = ws + off;
    off += (bytes + 255) & ~(size_t)255;
    return p;
  };
  u32* flags  = (u32*)alloc(32 * 4);
  u16* Wqkv_t = (u16*)alloc((size_t)3072 * 1024 * 2);   // 6 MB
  u16* Wo_t   = (u16*)alloc((size_t)1024 * 1024 * 2);   // 2 MB
  u16* W1_t   = (u16*)alloc((size_t)4096 * 1024 * 2);   // 8 MB
  u16* W2_t   = (u16*)alloc((size_t)1024 * 4096 * 2);   // 8 MB
  u16* svec   = (u16*)alloc((size_t)13312 * 2);         // all small vectors
  u16* src_bf = (u16*)alloc((size_t)TOK * 1024 * 2);    // 16 MB
  u16* regA   = (u16*)alloc((size_t)TOK * 4096 * 2);    // 64 MB
  size_t need_chunk2 = off;                              // h1(32MB) fits inside regA
  size_t need_full   = off + (size_t)TOK * 4096 * 2 / 2; // +32MB so h1(64MB) spans past regA

  u16* outw = (u16*)d_out;
  int CH;  // rows per FF chunk
  if (ws_size >= need_full) { CH = 8192; (void)alloc((size_t)32 << 20); }
  else if (ws_size >= need_chunk2) CH = 4096;
  else if (ws_size >= need_chunk2 - ((size_t)16 << 20)) CH = 2048;
  else {
    diag_ws_too_small<<<1, 1, 0, stream>>>(outw, 8000.0f + (float)(ws_size >> 20));
    return;
  }

  u16* qk    = regA;                          // [0,32)  Q|K per token [8192][2048]
  u16* Vt    = regA + (size_t)TOK * 2048;     // [32,48) V transposed [128][64][1024]
  u16* attnb = regA + (size_t)TOK * 3072;     // [48,64)
  u16* proj  = regA;                          // [0,16)  after qk/Vt dead
  u16* x     = regA + (size_t)TOK * 1024;     // [16,32)
  u16* h1    = regA + (size_t)TOK * 2048;     // [32,..) CH*4096*2 bytes (Vt dead by then)
  u16* f2    = src_bf;                        // src_bf dead after x computed

  u16* bqkv = svec + 0;      // 3072
  u16* bo_c = svec + 3072;
  u16* g1_c = svec + 4096;
  u16* be1_c = svec + 5120;
  u16* b1_c = svec + 6144;   // 4096
  u16* b2_c = svec + 10240;
  u16* g2_c = svec + 11264;
  u16* be2_c = svec + 12288;

  // ---- dtype detection ----
  InTab itab;
  for (int i = 0; i < 17; i++) { itab.p[i] = d_in[i]; itab.n[i] = in_sizes[i]; }
  detect_all<<<dim3(17), 256, 0, stream>>>(itab, flags);

  // ---- fused preprocessing: weight transposes + small vectors + src cvt ----
  CvtTab ct;
  const int srcs[10] = {2, 4, 6, 8, 9, 10, 12, 14, 15, 16};
  const int offs[10] = {0, 1024, 2048, 3072, 4096, 5120, 6144, 10240, 11264, 12288};
  const int lens[10] = {1024, 1024, 1024, 1024, 1024, 1024, 4096, 1024, 1024, 1024};
  for (int e = 0; e < 10; e++) { ct.p[e] = d_in[srcs[e]]; ct.flagidx[e] = srcs[e]; ct.dstoff[e] = offs[e]; ct.n[e] = lens[e]; }
  prep_all<<<dim3(3072 + 10 + TOK * 1024 / (256 * 8)), 256, 0, stream>>>(
      d_in[1], d_in[3], d_in[5], d_in[7], d_in[11], d_in[13],
      Wqkv_t, Wo_t, W1_t, W2_t, ct, svec, d_in[0], src_bf, flags);

  // qkv = src @ Wqkv + b: Q|K -> qk [8192][2048], V -> Vt transposed (mode 1)
  // 256x128 tile: 32x24 = 768 blocks = exactly 3 occupancy rounds
  // (gemm256's 384 blocks = 1.5 rounds wasted 33% in the tail)
  gemm256x128<<<dim3(32 * 24), 512, 0, stream>>>(src_bf, Wqkv_t, bqkv, qk, TOK, 3072, 1024, 0,
                                                 2048, Vt, 1);
  // attention [8192,1024]; grid: bh-major keeps one (b,h)'s K/V on one XCD's L2
  attn_fwd<<<dim3(128, 8), 256, 0, stream>>>(qk, Vt, attnb);
  // proj = attn @ Wo + bo  (256x128 tile: 32x8 = 256 blocks = 1 full round)
  gemm256x128<<<dim3(256), 512, 0, stream>>>(attnb, Wo_t, bo_c, proj, TOK, 1024, 1024, 0,
                                             1024, nullptr, 0);
  // x = LN(src + proj)
  add_ln<<<dim3(TOK), 256, 0, stream>>>(src_bf, proj, g1_c, be1_c, x);
  // FF chunked by CH rows
  for (int c = 0; c < TOK / CH; c++) {
    const u16* xc = x + (size_t)c * CH * 1024;
    u16* f2c = f2 + (size_t)c * CH * 1024;
    if (CH >= 4096) {
      gemm256<<<dim3((CH / 256) * 16), 512, 0, stream>>>(xc, W1_t, b1_c, h1, CH, 4096, 1024, 1,
                                                         4096);
    } else {
      gemm_bt<<<dim3(CH / 128, 32), 256, 0, stream>>>(xc, W1_t, b1_c, h1, CH, 4096, 1024, 1, 4096);
    }
    if (CH == 8192) {
      gemm256x128<<<dim3((CH / 256) * 8), 512, 0, stream>>>(h1, W2_t, b2_c, f2c, CH, 1024, 4096, 0,
                                                            1024, nullptr, 0);
    } else {
      gemm_bt<<<dim3(CH / 128, 8), 256, 0, stream>>>(h1, W2_t, b2_c, f2c, CH, 1024, 4096, 0, 1024);
    }
  }
  // out = LN(x + f2) + fused dtype-mismatch diag, stored in src's container dtype
  add_ln_out<<<dim3(TOK), 256, 0, stream>>>(x, f2, g2_c, be2_c, d_out, flags);
}